// Round 1
// baseline (890.989 us; speedup 1.0000x reference)
//
#include <hip/hip_runtime.h>

#define B4 4
#define NPIX 4096
#define CCH 320

__device__ __forceinline__ float delu_f(float v){
  return v > 0.f ? __fmaf_rn(10.f, v, 1.f) : __expf(10.f*v);
}

// ---------------- generic 64x64x16 f32 tile GEMM ----------------
// Out[b][m][n] = sum_k W[m][k]*X[b][k][n] (+bias[m]); N per launch = gridDim.x*64.
// EP: 0 = store (+bias), 1 = delu(store+bias), 2 = delu then atomic column-sum into qsum (no store)
template<int EP>
__global__ __launch_bounds__(256) void gemm_f32(
    const float* __restrict__ W, const float* __restrict__ bias,
    const float* __restrict__ X, long xStride, int ldX,
    float* __restrict__ Out, long outStride, int ldOut,
    int M, int K, float* __restrict__ qsum)
{
  __shared__ float Wt[16][64];
  __shared__ float Xt[16][64];
  const int b  = blockIdx.z;
  const int m0 = blockIdx.y * 64;
  const int n0 = blockIdx.x * 64;
  const int tid = threadIdx.x;
  const int tc = tid & 15, tr = tid >> 4;
  const int wm = tid >> 2, wk = (tid & 3) << 2;
  const int xk = tid >> 4, xn = (tid & 15) << 2;
  const float* Xb = X + (long)b * xStride;
  float acc[4][4] = {};

  for (int k0 = 0; k0 < K; k0 += 16) {
    float4 wv4;
    if (m0 + wm < M) wv4 = *reinterpret_cast<const float4*>(W + (long)(m0+wm)*K + k0 + wk);
    else wv4 = make_float4(0.f,0.f,0.f,0.f);
    Wt[wk+0][wm] = wv4.x; Wt[wk+1][wm] = wv4.y; Wt[wk+2][wm] = wv4.z; Wt[wk+3][wm] = wv4.w;
    *reinterpret_cast<float4*>(&Xt[xk][xn]) =
        *reinterpret_cast<const float4*>(Xb + (long)(k0+xk)*ldX + n0 + xn);
    __syncthreads();
    #pragma unroll
    for (int kk = 0; kk < 16; ++kk) {
      float4 a4 = *reinterpret_cast<const float4*>(&Wt[kk][tr<<2]);
      float4 b4 = *reinterpret_cast<const float4*>(&Xt[kk][tc<<2]);
      float av[4] = {a4.x,a4.y,a4.z,a4.w};
      float bv[4] = {b4.x,b4.y,b4.z,b4.w};
      #pragma unroll
      for (int i=0;i<4;i++)
        #pragma unroll
        for (int j=0;j<4;j++) acc[i][j] = __fmaf_rn(av[i], bv[j], acc[i][j]);
    }
    __syncthreads();
  }

  if (EP == 2) {
    #pragma unroll
    for (int j=0;j<4;j++){
      float s = 0.f;
      #pragma unroll
      for (int i=0;i<4;i++){
        int m = m0 + (tr<<2) + i;
        s += delu_f(acc[i][j] + bias[m]);
      }
      atomicAdd(&qsum[(long)b*NPIX + n0 + (tc<<2) + j], s);
    }
  } else {
    #pragma unroll
    for (int i=0;i<4;i++){
      int m = m0 + (tr<<2) + i;
      if (m < M) {
        float bv = bias ? bias[m] : 0.f;
        float r[4];
        #pragma unroll
        for (int j=0;j<4;j++){
          float v = acc[i][j] + bv;
          if (EP == 1) v = delu_f(v);
          r[j] = v;
        }
        *reinterpret_cast<float4*>(Out + (long)b*outStride + (long)m*ldOut + n0 + (tc<<2)) =
            make_float4(r[0],r[1],r[2],r[3]);
      }
    }
  }
}

// ---------------- weight composition kernels ----------------
__global__ void compose1_kernel(const float* __restrict__ av_w, const float* __restrict__ ad1_w,
    const float* __restrict__ ld1_w, const float* __restrict__ wc_w,
    const float* __restrict__ ag, const float* __restrict__ lg, float* __restrict__ Wbig1)
{
  int idx = blockIdx.x*256 + threadIdx.x;
  if (idx >= 320*320) return;
  int r = idx / 320, c = idx % 320;
  float cD = 1.4f*ag[0], cL = 0.3f*lg[0];
  if (r < 160) {               // vp weight: wc @ av_w
    float s = 0.f;
    for (int j=0;j<320;j++) s += wc_w[r*320+j]*av_w[j*320+c];
    Wbig1[idx] = s;
  } else {                     // Weff = 2*wc + cD*wc@ad1 + cL*wc@ld1
    int o = r - 160;
    float s1 = 0.f, s2 = 0.f;
    for (int j=0;j<320;j++){
      float w = wc_w[o*320+j];
      s1 += w*ad1_w[j*320+c];
      s2 += w*ld1_w[j*320+c];
    }
    Wbig1[idx] = 2.f*wc_w[o*320+c] + cD*s1 + cL*s2;
  }
}

__global__ void bias1_kernel(const float* __restrict__ av_b, const float* __restrict__ ad1_b,
    const float* __restrict__ ad3_b, const float* __restrict__ ld1_b, const float* __restrict__ ld3_b,
    const float* __restrict__ wc_w, const float* __restrict__ wc_b,
    const float* __restrict__ ag, const float* __restrict__ lg, float* __restrict__ bias1)
{
  int r = blockIdx.x*64 + threadIdx.x;
  if (r >= 320) return;
  float cD = 1.4f*ag[0], cL = 0.3f*lg[0];
  if (r < 160){
    float s = 0.f;
    for (int j=0;j<320;j++) s += wc_w[r*320+j]*av_b[j];
    bias1[r] = s;
  } else {
    int o = r - 160;
    float s = wc_b[o];
    for (int j=0;j<320;j++){
      float w = wc_w[o*320+j];
      s += cD*w*(ad1_b[j]+ad3_b[j]) + cL*w*(ld1_b[j]+ld3_b[j]);
    }
    bias1[r] = s;
  }
}

// fp64 composed q/k weights: q8 = (aq[:, :192]@w_swin)@swin + (aq[:,192:]@w_res)@res + b
__global__ void composeqk_kernel(const float* __restrict__ aq_w, const float* __restrict__ aq_b,
    const float* __restrict__ ak_w, const float* __restrict__ ak_b,
    const float* __restrict__ w_swin, const float* __restrict__ b_swin,
    const float* __restrict__ w_res, const float* __restrict__ b_res,
    double* __restrict__ Wsw, double* __restrict__ Wres, double* __restrict__ bqk)
{
  int idx = blockIdx.x*256 + threadIdx.x;
  if (idx < 80*192){
    int m = idx/192, j = idx%192;
    const float* aw = (m < 40) ? aq_w + m*320 : ak_w + (m-40)*320;
    double s = 0.0;
    for (int i=0;i<192;i++) s += (double)aw[i]*(double)w_swin[i*192+j];
    Wsw[idx] = s;
  }
  int idx2 = idx - 80*192;
  if (idx2 >= 0 && idx2 < 80*128){
    int m = idx2/128, j = idx2%128;
    const float* aw = (m < 40) ? aq_w + m*320 + 192 : ak_w + (m-40)*320 + 192;
    double s = 0.0;
    for (int i=0;i<128;i++) s += (double)aw[i]*(double)w_res[i*128+j];
    Wres[idx2] = s;
  }
  int idx3 = idx - 80*192 - 80*128;
  if (idx3 >= 0 && idx3 < 80){
    int m = idx3;
    const float* aw = (m < 40) ? aq_w + m*320 : ak_w + (m-40)*320;
    double s = (double)((m < 40) ? aq_b[m] : ak_b[m-40]);
    for (int i=0;i<192;i++) s += (double)aw[i]*(double)b_swin[i];
    for (int i=0;i<128;i++) s += (double)aw[192+i]*(double)b_res[i];
    bqk[m] = s;
  }
}

// Wmix[t*320+j][c] = cD*ad3[j][c][t] + cL*ld3[j][c][t]
__global__ void t1_kernel(const float* __restrict__ ad3_w, const float* __restrict__ ld3_w,
    const float* __restrict__ ag, const float* __restrict__ lg, float* __restrict__ Wmix)
{
  long idx = (long)blockIdx.x*256 + threadIdx.x;
  if (idx >= 2880L*320) return;
  int k = (int)(idx / 320), c = (int)(idx % 320);
  int t = k / 320, j = k % 320;
  float cD = 1.4f*ag[0], cL = 0.3f*lg[0];
  long src = (long)(j*320 + c)*9 + t;
  Wmix[idx] = cD*ad3_w[src] + cL*ld3_w[src];
}

// ---------------- fp64 q8/k8 (direct from swin/resnet) ----------------
__global__ __launch_bounds__(256) void qk8_kernel(const double* __restrict__ Wsw,
    const double* __restrict__ Wres, const double* __restrict__ bqk,
    const float* __restrict__ swin, const float* __restrict__ resnet, double* __restrict__ q8d)
{
  int b = blockIdx.z, mb = blockIdx.y*16;
  int n = blockIdx.x*256 + threadIdx.x;
  __shared__ double Ws[16][192];
  __shared__ double Wr[16][128];
  for (int i=threadIdx.x; i<16*192; i+=256) Ws[i/192][i%192] = Wsw[(mb + i/192)*192 + i%192];
  for (int i=threadIdx.x; i<16*128; i+=256) Wr[i/128][i%128] = Wres[(mb + i/128)*128 + i%128];
  __syncthreads();
  double acc[16];
  #pragma unroll
  for (int i=0;i<16;i++) acc[i] = bqk[mb+i];
  const float* sw = swin + (long)b*192*NPIX;
  for (int j=0;j<192;j++){
    double xv = (double)sw[(long)j*NPIX + n];
    #pragma unroll
    for (int i=0;i<16;i++) acc[i] += Ws[i][j]*xv;
  }
  const float* rs = resnet + (long)b*128*NPIX;
  for (int j=0;j<128;j++){
    double xv = (double)rs[(long)j*NPIX + n];
    #pragma unroll
    for (int i=0;i<16;i++) acc[i] += Wr[i][j]*xv;
  }
  #pragma unroll
  for (int i=0;i<16;i++) q8d[((long)b*80 + mb + i)*NPIX + n] = acc[i];
}

// ---------------- reductions ----------------
__global__ void sumk_kernel(const double* __restrict__ q8d, double* __restrict__ sumkd)
{
  int b = blockIdx.y, m = blockIdx.x;             // m in 0..39, k8 rows are 40..79
  const double* row = q8d + ((long)b*80 + 40 + m)*NPIX;
  double s = 0.0;
  for (int n=threadIdx.x; n<NPIX; n+=256) s += row[n];
  __shared__ double sd[256];
  sd[threadIdx.x] = s; __syncthreads();
  for (int o=128; o; o>>=1){ if (threadIdx.x < o) sd[threadIdx.x] += sd[threadIdx.x+o]; __syncthreads(); }
  if (threadIdx.x == 0) sumkd[b*40+m] = sd[0];
}

__global__ void colsum_kernel(const float* __restrict__ projL, const float* __restrict__ qsum,
    float* __restrict__ colsum)
{
  int b = blockIdx.y, c = blockIdx.x;
  const float* kl = projL + (long)b*640*NPIX + (long)c*NPIX;
  const float* qs = qsum + (long)b*NPIX;
  double s = 0.0;
  for (int n=threadIdx.x; n<NPIX; n+=256) s += (double)kl[n]*(double)qs[n];
  __shared__ double sd[256];
  sd[threadIdx.x] = s; __syncthreads();
  for (int o=128; o; o>>=1){ if (threadIdx.x < o) sd[threadIdx.x] += sd[threadIdx.x+o]; __syncthreads(); }
  if (threadIdx.x == 0) colsum[b*320+c] = (float)sd[0];
}

// kvp[b][m][o] = sum_n k8[m,n]*vp[o,n]   (m<40, o<160)
__global__ __launch_bounds__(256) void kvp_kernel(const float* __restrict__ proj1,
    const double* __restrict__ q8d, float* __restrict__ kvp)
{
  int b = blockIdx.z, m0 = blockIdx.x*8, o0 = blockIdx.y*32;
  const float* vp = proj1 + (long)b*(320L*NPIX);  // rows 0..159
  const double* k8 = q8d + ((long)b*80 + 40 + m0)*NPIX;
  __shared__ float ks[8][256];
  __shared__ float vs[32][257];
  int tid = threadIdx.x;
  int mi = tid >> 5, oi = tid & 31;
  float acc = 0.f;
  for (int n0 = 0; n0 < NPIX; n0 += 256){
    for (int r=0;r<8;r++)  ks[r][tid] = (float)k8[(long)r*NPIX + n0 + tid];
    for (int r=0;r<32;r++) vs[r][tid] = vp[(long)(o0+r)*NPIX + n0 + tid];
    __syncthreads();
    #pragma unroll 4
    for (int nn=0;nn<256;nn++) acc = __fmaf_rn(ks[mi][nn], vs[oi][nn], acc);
    __syncthreads();
  }
  kvp[((long)b*40 + m0 + mi)*160 + o0 + oi] = acc;
}

__global__ __launch_bounds__(256) void norm_kernel(const double* __restrict__ q8d,
    const float* __restrict__ projL, const double* __restrict__ sumkd,
    const float* __restrict__ colsum, float* __restrict__ norm_a, float* __restrict__ norm_l)
{
  int b = blockIdx.y;
  int lane = threadIdx.x & 63;
  int g = threadIdx.x >> 6;
  int px = blockIdx.x*64 + lane;
  __shared__ double sk[40];
  __shared__ float cs[320];
  if (threadIdx.x < 40) sk[threadIdx.x] = sumkd[b*40+threadIdx.x] + 1e-10;
  for (int i=threadIdx.x; i<320; i+=256) cs[i] = colsum[b*320+i];
  __syncthreads();
  const double* q8 = q8d + (long)b*80*NPIX;
  const float* kl = projL + (long)b*640*NPIX;
  double da = 0.0, dl = 0.0;
  for (int m=g; m<40;  m+=4) da += q8[(long)m*NPIX + px]*sk[m];
  for (int c=g; c<320; c+=4) dl += (double)kl[(long)c*NPIX + px]*(double)cs[c];
  __shared__ double redA[4][64], redL[4][64];
  redA[g][lane] = da; redL[g][lane] = dl;
  __syncthreads();
  if (g == 0){
    double a = redA[0][lane]+redA[1][lane]+redA[2][lane]+redA[3][lane];
    double l = redL[0][lane]+redL[1][lane]+redL[2][lane]+redL[3][lane];
    norm_a[(long)b*NPIX+px] = (float)(1.0/a);
    norm_l[(long)b*NPIX+px] = (float)(1.0/(l + 1e-10));
  }
}

// ---------------- final fused kernel: out = outacc + cL*norm_l*(W2@kvl) + cA*norm_a*(kvpT@q8) ----------------
__global__ __launch_bounds__(256) void final_kernel(
    const float* __restrict__ proj1, const float* __restrict__ projL,
    const float* __restrict__ wc_w, const float* __restrict__ colsum,
    const float* __restrict__ kvp, const double* __restrict__ q8d,
    const float* __restrict__ norm_a, const float* __restrict__ norm_l,
    const float* __restrict__ ag, const float* __restrict__ lg,
    float* __restrict__ Out)
{
  __shared__ float Wt[16][64];
  __shared__ float Xt[16][64];
  const int b  = blockIdx.z;
  const int m0 = blockIdx.y * 64;
  const int n0 = blockIdx.x * 64;
  const int tid = threadIdx.x;
  const int tc = tid & 15, tr = tid >> 4;
  const int wm = tid >> 2, wk = (tid & 3) << 2;
  const int xk = tid >> 4, xn = (tid & 15) << 2;
  const float* kl = projL + (long)b*(640L*NPIX);
  const float* vl = kl + 320L*NPIX;
  float acc1[4][4] = {};
  float acc2[4][4] = {};

  // phase 1: K=320: W2[o][c] = wc[o][c]*colsum[c], X = kl*vl
  for (int k0 = 0; k0 < 320; k0 += 16) {
    float4 wv4;
    if (m0 + wm < 160) {
      wv4 = *reinterpret_cast<const float4*>(wc_w + (long)(m0+wm)*320 + k0 + wk);
      wv4.x *= colsum[b*320 + k0+wk+0];
      wv4.y *= colsum[b*320 + k0+wk+1];
      wv4.z *= colsum[b*320 + k0+wk+2];
      wv4.w *= colsum[b*320 + k0+wk+3];
    } else wv4 = make_float4(0.f,0.f,0.f,0.f);
    Wt[wk+0][wm] = wv4.x; Wt[wk+1][wm] = wv4.y; Wt[wk+2][wm] = wv4.z; Wt[wk+3][wm] = wv4.w;
    float4 k4 = *reinterpret_cast<const float4*>(kl + (long)(k0+xk)*NPIX + n0 + xn);
    float4 v4 = *reinterpret_cast<const float4*>(vl + (long)(k0+xk)*NPIX + n0 + xn);
    *reinterpret_cast<float4*>(&Xt[xk][xn]) =
        make_float4(k4.x*v4.x, k4.y*v4.y, k4.z*v4.z, k4.w*v4.w);
    __syncthreads();
    #pragma unroll
    for (int kk = 0; kk < 16; ++kk) {
      float4 a4 = *reinterpret_cast<const float4*>(&Wt[kk][tr<<2]);
      float4 b4 = *reinterpret_cast<const float4*>(&Xt[kk][tc<<2]);
      float av[4] = {a4.x,a4.y,a4.z,a4.w};
      float bv[4] = {b4.x,b4.y,b4.z,b4.w};
      #pragma unroll
      for (int i=0;i<4;i++)
        #pragma unroll
        for (int j=0;j<4;j++) acc1[i][j] = __fmaf_rn(av[i], bv[j], acc1[i][j]);
    }
    __syncthreads();
  }

  // phase 2: K=40 (padded to 48): W = kvp^T, X = q8 (fp64->f32)
  for (int k0 = 0; k0 < 48; k0 += 16) {
    {
      int mm = tid & 63, kks = tid >> 6;
      #pragma unroll
      for (int p=0;p<4;p++){
        int kk = kks + p*4; int kg = k0 + kk; int m = m0 + mm;
        float v = 0.f;
        if (kg < 40 && m < 160) v = kvp[((long)b*40 + kg)*160 + m];
        Wt[kk][mm] = v;
      }
    }
    {
      int kg = k0 + xk;
      float4 q4 = make_float4(0.f,0.f,0.f,0.f);
      if (kg < 40) {
        const double* qr = q8d + ((long)b*80 + kg)*NPIX + n0 + xn;
        q4 = make_float4((float)qr[0],(float)qr[1],(float)qr[2],(float)qr[3]);
      }
      *reinterpret_cast<float4*>(&Xt[xk][xn]) = q4;
    }
    __syncthreads();
    #pragma unroll
    for (int kk = 0; kk < 16; ++kk) {
      float4 a4 = *reinterpret_cast<const float4*>(&Wt[kk][tr<<2]);
      float4 b4 = *reinterpret_cast<const float4*>(&Xt[kk][tc<<2]);
      float av[4] = {a4.x,a4.y,a4.z,a4.w};
      float bv[4] = {b4.x,b4.y,b4.z,b4.w};
      #pragma unroll
      for (int i=0;i<4;i++)
        #pragma unroll
        for (int j=0;j<4;j++) acc2[i][j] = __fmaf_rn(av[i], bv[j], acc2[i][j]);
    }
    __syncthreads();
  }

  const float cA = 0.7f*ag[0], cL = 0.3f*lg[0];
  #pragma unroll
  for (int i=0;i<4;i++){
    int m = m0 + (tr<<2) + i;
    if (m < 160){
      const float* oa = proj1 + (long)b*(320L*NPIX) + (long)(160+m)*NPIX + n0 + (tc<<2);
      float* op = Out + ((long)b*160 + m)*NPIX + n0 + (tc<<2);
      #pragma unroll
      for (int j=0;j<4;j++){
        int n = n0 + (tc<<2) + j;
        op[j] = oa[j] + cL*norm_l[(long)b*NPIX+n]*acc1[i][j]
                      + cA*norm_a[(long)b*NPIX+n]*acc2[i][j];
      }
    }
  }
}

// ---------------- composed 3x3 conv (implicit GEMM, K=2880), accumulates into Out ----------------
__global__ __launch_bounds__(256) void conv_kernel(const float* __restrict__ Wd3,
    const float* __restrict__ x, float* __restrict__ Out)
{
  __shared__ float Wt[16][64];
  __shared__ float Xt[16][64];
  const int b  = blockIdx.z;
  const int m0 = blockIdx.y * 64;
  const int n0 = blockIdx.x * 64;
  const int h  = n0 >> 6;                 // BN=64 == W, tile is one image row
  const int tid = threadIdx.x;
  const int tc = tid & 15, tr = tid >> 4;
  const int wm = tid >> 2, wk = (tid & 3) << 2;
  const int lw = tid & 63, lk0 = tid >> 6;
  const float* xb = x + (long)b*(320L*NPIX);
  float acc[4][4] = {};

  for (int k0 = 0; k0 < 2880; k0 += 16) {
    const int t = k0 / 320;               // 320 % 16 == 0 -> t uniform within chunk
    const int dh = t/3 - 1, dw = t%3 - 1;
    const int cbase = k0 - t*320;
    const int hp = h + dh;
    float4 wv4;
    if (m0 + wm < 160) wv4 = *reinterpret_cast<const float4*>(Wd3 + (long)(m0+wm)*2880 + k0 + wk);
    else wv4 = make_float4(0.f,0.f,0.f,0.f);
    Wt[wk+0][wm] = wv4.x; Wt[wk+1][wm] = wv4.y; Wt[wk+2][wm] = wv4.z; Wt[wk+3][wm] = wv4.w;
    const int wp = lw + dw;
    const bool ok = (hp >= 0) && (hp < 64) && (wp >= 0) && (wp < 64);
    #pragma unroll
    for (int p=0;p<4;p++){
      int kk = lk0 + p*4;
      float v = 0.f;
      if (ok) v = xb[(long)(cbase+kk)*NPIX + hp*64 + wp];
      Xt[kk][lw] = v;
    }
    __syncthreads();
    #pragma unroll
    for (int kk = 0; kk < 16; ++kk) {
      float4 a4 = *reinterpret_cast<const float4*>(&Wt[kk][tr<<2]);
      float4 b4 = *reinterpret_cast<const float4*>(&Xt[kk][tc<<2]);
      float av[4] = {a4.x,a4.y,a4.z,a4.w};
      float bv[4] = {b4.x,b4.y,b4.z,b4.w};
      #pragma unroll
      for (int i=0;i<4;i++)
        #pragma unroll
        for (int j=0;j<4;j++) acc[i][j] = __fmaf_rn(av[i], bv[j], acc[i][j]);
    }
    __syncthreads();
  }
  #pragma unroll
  for (int i=0;i<4;i++){
    int m = m0 + (tr<<2) + i;
    if (m < 160){
      float* op = Out + ((long)b*160 + m)*NPIX + n0 + (tc<<2);
      #pragma unroll
      for (int j=0;j<4;j++) op[j] += acc[i][j];
    }
  }
}

extern "C" void kernel_launch(void* const* d_in, const int* in_sizes, int n_in,
                              void* d_out, int out_size, void* d_ws, size_t ws_size,
                              hipStream_t stream)
{
  const float* swin   = (const float*)d_in[0];
  const float* resnet = (const float*)d_in[1];
  const float* w_swin = (const float*)d_in[2];
  const float* b_swin = (const float*)d_in[3];
  const float* w_res  = (const float*)d_in[4];
  const float* b_res  = (const float*)d_in[5];
  const float* aq_w = (const float*)d_in[6];
  const float* aq_b = (const float*)d_in[7];
  const float* ak_w = (const float*)d_in[8];
  const float* ak_b = (const float*)d_in[9];
  const float* av_w = (const float*)d_in[10];
  const float* av_b = (const float*)d_in[11];
  const float* ad1_w = (const float*)d_in[12];
  const float* ad1_b = (const float*)d_in[13];
  const float* ad3_w = (const float*)d_in[14];
  const float* ad3_b = (const float*)d_in[15];
  const float* ag    = (const float*)d_in[16];
  const float* lq_w = (const float*)d_in[17];
  const float* lq_b = (const float*)d_in[18];
  const float* lk_w = (const float*)d_in[19];
  const float* lk_b = (const float*)d_in[20];
  const float* lv_w = (const float*)d_in[21];
  const float* lv_b = (const float*)d_in[22];
  const float* ld1_w = (const float*)d_in[23];
  const float* ld1_b = (const float*)d_in[24];
  const float* ld3_w = (const float*)d_in[25];
  const float* ld3_b = (const float*)d_in[26];
  const float* lg    = (const float*)d_in[27];
  const float* wc_w = (const float*)d_in[28];
  const float* wc_b = (const float*)d_in[29];
  float* out = (float*)d_out;

  // ---- workspace carve (doubles first for alignment) ----
  char* p = (char*)d_ws;
  double* q8d   = (double*)p; p += (size_t)B4*80*NPIX*8;
  double* Wsw   = (double*)p; p += (size_t)80*192*8;
  double* Wres  = (double*)p; p += (size_t)80*128*8;
  double* bqk   = (double*)p; p += (size_t)80*8;
  double* sumkd = (double*)p; p += (size_t)160*8;
  float* x      = (float*)p;  p += (size_t)B4*CCH*NPIX*4;
  float* proj1  = (float*)p;  p += (size_t)B4*CCH*NPIX*4;  // rows 0..159 vp, 160..319 outacc
  float* projL  = (float*)p;  p += (size_t)B4*640*NPIX*4;  // rows 0..319 kl, 320..639 vl
  float* qsum   = (float*)p;  p += (size_t)B4*NPIX*4;
  float* norm_a = (float*)p;  p += (size_t)B4*NPIX*4;
  float* norm_l = (float*)p;  p += (size_t)B4*NPIX*4;
  float* colsum = (float*)p;  p += (size_t)B4*320*4;
  float* kvp    = (float*)p;  p += (size_t)B4*40*160*4;
  float* Wbig1  = (float*)p;  p += (size_t)320*320*4;
  float* bias1  = (float*)p;  p += (size_t)320*4;
  float* Wmix   = (float*)p;  p += (size_t)2880*320*4;
  float* Wd3eff = (float*)p;  p += (size_t)160*2880*4;
  if ((size_t)(p - (char*)d_ws) > ws_size) return;  // insufficient scratch -> clean no-op

  hipMemsetAsync(qsum, 0, (size_t)B4*NPIX*4, stream);

  // ---- weight composition ----
  composeqk_kernel<<<(80*192 + 80*128 + 80 + 255)/256, 256, 0, stream>>>(
      aq_w, aq_b, ak_w, ak_b, w_swin, b_swin, w_res, b_res, Wsw, Wres, bqk);
  compose1_kernel<<<(320*320 + 255)/256, 256, 0, stream>>>(av_w, ad1_w, ld1_w, wc_w, ag, lg, Wbig1);
  bias1_kernel<<<5, 64, 0, stream>>>(av_b, ad1_b, ad3_b, ld1_b, ld3_b, wc_w, wc_b, ag, lg, bias1);
  t1_kernel<<<(2880*320 + 255)/256, 256, 0, stream>>>(ad3_w, ld3_w, ag, lg, Wmix);
  // Wd3eff[o][t*320+c] = wc @ Wmix_t   (9 "batches" of 160x320x320)
  gemm_f32<0><<<dim3(5,3,9), 256, 0, stream>>>(wc_w, nullptr, Wmix, 320L*320, 320,
                                               Wd3eff, 320, 2880, 160, 320, nullptr);

  // ---- x = concat(w_swin@swin+b, w_res@res+b) ----
  gemm_f32<0><<<dim3(64,3,4), 256, 0, stream>>>(w_swin, b_swin, swin, 192L*NPIX, NPIX,
                                                x, 320L*NPIX, NPIX, 192, 192, nullptr);
  gemm_f32<0><<<dim3(64,2,4), 256, 0, stream>>>(w_res, b_res, resnet, 128L*NPIX, NPIX,
                                                x + 192L*NPIX, 320L*NPIX, NPIX, 128, 128, nullptr);

  // ---- fp64 q8/k8 path ----
  qk8_kernel<<<dim3(16,5,4), 256, 0, stream>>>(Wsw, Wres, bqk, swin, resnet, q8d);

  // ---- projections from x ----
  gemm_f32<0><<<dim3(64,5,4), 256, 0, stream>>>(Wbig1, bias1, x, 320L*NPIX, NPIX,
                                                proj1, 320L*NPIX, NPIX, 320, 320, nullptr);
  gemm_f32<2><<<dim3(64,5,4), 256, 0, stream>>>(lq_w, lq_b, x, 320L*NPIX, NPIX,
                                                nullptr, 0, 0, 320, 320, qsum);
  gemm_f32<1><<<dim3(64,5,4), 256, 0, stream>>>(lk_w, lk_b, x, 320L*NPIX, NPIX,
                                                projL, 640L*NPIX, NPIX, 320, 320, nullptr);
  gemm_f32<0><<<dim3(64,5,4), 256, 0, stream>>>(lv_w, lv_b, x, 320L*NPIX, NPIX,
                                                projL + 320L*NPIX, 640L*NPIX, NPIX, 320, 320, nullptr);

  // ---- reductions ----
  sumk_kernel<<<dim3(40,4), 256, 0, stream>>>(q8d, sumkd);
  kvp_kernel<<<dim3(5,5,4), 256, 0, stream>>>(proj1, q8d, kvp);
  colsum_kernel<<<dim3(320,4), 256, 0, stream>>>(projL, qsum, colsum);
  norm_kernel<<<dim3(64,4), 256, 0, stream>>>(q8d, projL, sumkd, colsum, norm_a, norm_l);

  // ---- fused epilogue + composed conv ----
  final_kernel<<<dim3(64,3,4), 256, 0, stream>>>(proj1, projL, wc_w, colsum, kvp, q8d,
                                                 norm_a, norm_l, ag, lg, out);
  conv_kernel<<<dim3(64,3,4), 256, 0, stream>>>(Wd3eff, x, out);
}

// Round 2
// 545.469 us; speedup vs baseline: 1.6334x; 1.6334x over previous
//
#include <hip/hip_runtime.h>
#include <stdint.h>

#define B4 4
#define NPIX 4096

typedef short sh8 __attribute__((ext_vector_type(8)));
typedef float f4 __attribute__((ext_vector_type(4)));

__device__ __forceinline__ float delu_f(float v){
  return v > 0.f ? __fmaf_rn(10.f, v, 1.f) : __expf(10.f*v);
}
__device__ __forceinline__ unsigned short f2bf(float f){
  unsigned u = __float_as_uint(f);
  u += 0x7fffu + ((u>>16)&1u);
  return (unsigned short)(u>>16);
}
__device__ __forceinline__ float bf2f(unsigned short h){
  return __uint_as_float(((unsigned)h)<<16);
}

// ---------------- generic 64x64x16 f32 tile GEMM ----------------
// EP: 0 = store(+bias); 3 = write transposed bf16 hi/lo into xT[b][n][320] at channel tOff+m
template<int EP>
__global__ __launch_bounds__(256) void gemm_f32(
    const float* __restrict__ W, const float* __restrict__ bias,
    const float* __restrict__ X, long xStride, int ldX,
    float* __restrict__ Out, long outStride, int ldOut,
    int M, int K,
    unsigned short* __restrict__ tHi, unsigned short* __restrict__ tLo, int tOff)
{
  __shared__ float Wt[16][64];
  __shared__ float Xt[16][64];
  const int b  = blockIdx.z;
  const int m0 = blockIdx.y * 64;
  const int n0 = blockIdx.x * 64;
  const int tid = threadIdx.x;
  const int tc = tid & 15, tr = tid >> 4;
  const int wm = tid >> 2, wk = (tid & 3) << 2;
  const int xk = tid >> 4, xn = (tid & 15) << 2;
  const float* Xb = X + (long)b * xStride;
  float acc[4][4] = {};

  for (int k0 = 0; k0 < K; k0 += 16) {
    float4 wv4;
    if (m0 + wm < M) wv4 = *reinterpret_cast<const float4*>(W + (long)(m0+wm)*K + k0 + wk);
    else wv4 = make_float4(0.f,0.f,0.f,0.f);
    Wt[wk+0][wm] = wv4.x; Wt[wk+1][wm] = wv4.y; Wt[wk+2][wm] = wv4.z; Wt[wk+3][wm] = wv4.w;
    *reinterpret_cast<float4*>(&Xt[xk][xn]) =
        *reinterpret_cast<const float4*>(Xb + (long)(k0+xk)*ldX + n0 + xn);
    __syncthreads();
    #pragma unroll
    for (int kk = 0; kk < 16; ++kk) {
      float4 a4 = *reinterpret_cast<const float4*>(&Wt[kk][tr<<2]);
      float4 b4 = *reinterpret_cast<const float4*>(&Xt[kk][tc<<2]);
      float av[4] = {a4.x,a4.y,a4.z,a4.w};
      float bv[4] = {b4.x,b4.y,b4.z,b4.w};
      #pragma unroll
      for (int i=0;i<4;i++)
        #pragma unroll
        for (int j=0;j<4;j++) acc[i][j] = __fmaf_rn(av[i], bv[j], acc[i][j]);
    }
    __syncthreads();
  }

  #pragma unroll
  for (int i=0;i<4;i++){
    int m = m0 + (tr<<2) + i;
    if (m < M) {
      float bv = bias ? bias[m] : 0.f;
      if (EP == 3) {
        #pragma unroll
        for (int j=0;j<4;j++){
          int n = n0 + (tc<<2) + j;
          float v = acc[i][j] + bv;
          unsigned short h = f2bf(v);
          float lo = v - bf2f(h);
          long o = ((long)b*NPIX + n)*320 + tOff + m;
          tHi[o] = h; tLo[o] = f2bf(lo);
        }
      } else {
        float r[4];
        #pragma unroll
        for (int j=0;j<4;j++) r[j] = acc[i][j] + bv;
        *reinterpret_cast<float4*>(Out + (long)b*outStride + (long)m*ldOut + n0 + (tc<<2)) =
            make_float4(r[0],r[1],r[2],r[3]);
      }
    }
  }
}

// ---------------- bf16 MFMA GEMM: C[m][n] = sum_k W[m][k] * xT[n][k] ----------------
// tile 64(m) x 128(n) x 32(k), 4 waves (2x2). xT layout: [B][4096][320] bf16.
// EP: 0 = store acc+bias (fp32); 1 = store delu(acc+bias); 2 = delu, column-sum -> atomicAdd qsum
// SPLIT: 1 = 3-pass hi/lo (near-fp32), 0 = single pass (hi only)
template<int EP, int SPLIT>
__global__ __launch_bounds__(256) void gemm_mfma(
    const unsigned short* __restrict__ Whi, const unsigned short* __restrict__ Wlo,
    const float* __restrict__ bias,
    const unsigned short* __restrict__ Xhi, const unsigned short* __restrict__ Xlo,
    float* __restrict__ Out, long outStride, float* __restrict__ qsum)
{
  __shared__ unsigned short Ah[64][40];
  __shared__ unsigned short Bh[128][40];
  __shared__ unsigned short Al[SPLIT?64:8][40];
  __shared__ unsigned short Bl[SPLIT?128:8][40];
  const int b  = blockIdx.z;
  const int m0 = blockIdx.y * 64;
  const int n0 = blockIdx.x * 128;
  const int tid = threadIdx.x;
  const int sRow = tid >> 2, sK = (tid & 3) << 3;
  const int lane = tid & 63, w = tid >> 6;
  const int wr = w >> 1, wc = w & 1;
  const int fr = lane & 15, fko = (lane >> 4) << 3;

  f4 z4 = {0.f,0.f,0.f,0.f};
  f4 acc[2][4];
  #pragma unroll
  for (int mf=0; mf<2; mf++)
    #pragma unroll
    for (int nf=0; nf<4; nf++) acc[mf][nf] = z4;

  for (int k0 = 0; k0 < 320; k0 += 32) {
    *reinterpret_cast<sh8*>(&Ah[sRow][sK]) =
        *reinterpret_cast<const sh8*>(Whi + (long)(m0+sRow)*320 + k0 + sK);
    if (SPLIT)
      *reinterpret_cast<sh8*>(&Al[sRow][sK]) =
          *reinterpret_cast<const sh8*>(Wlo + (long)(m0+sRow)*320 + k0 + sK);
    #pragma unroll
    for (int r=0; r<2; r++){
      int row = r*64 + sRow;
      long src = ((long)b*NPIX + n0 + row)*320 + k0 + sK;
      *reinterpret_cast<sh8*>(&Bh[row][sK]) = *reinterpret_cast<const sh8*>(Xhi + src);
      if (SPLIT)
        *reinterpret_cast<sh8*>(&Bl[row][sK]) = *reinterpret_cast<const sh8*>(Xlo + src);
    }
    __syncthreads();
    sh8 aH[2], bH[4];
    #pragma unroll
    for (int mf=0; mf<2; mf++)
      aH[mf] = *reinterpret_cast<const sh8*>(&Ah[wr*32 + mf*16 + fr][fko]);
    #pragma unroll
    for (int nf=0; nf<4; nf++)
      bH[nf] = *reinterpret_cast<const sh8*>(&Bh[wc*64 + nf*16 + fr][fko]);
    #pragma unroll
    for (int mf=0; mf<2; mf++)
      #pragma unroll
      for (int nf=0; nf<4; nf++)
        acc[mf][nf] = __builtin_amdgcn_mfma_f32_16x16x32_bf16(aH[mf], bH[nf], acc[mf][nf], 0,0,0);
    if (SPLIT){
      sh8 aL[2], bL[4];
      #pragma unroll
      for (int mf=0; mf<2; mf++)
        aL[mf] = *reinterpret_cast<const sh8*>(&Al[wr*32 + mf*16 + fr][fko]);
      #pragma unroll
      for (int nf=0; nf<4; nf++)
        bL[nf] = *reinterpret_cast<const sh8*>(&Bl[wc*64 + nf*16 + fr][fko]);
      #pragma unroll
      for (int mf=0; mf<2; mf++)
        #pragma unroll
        for (int nf=0; nf<4; nf++){
          acc[mf][nf] = __builtin_amdgcn_mfma_f32_16x16x32_bf16(aL[mf], bH[nf], acc[mf][nf], 0,0,0);
          acc[mf][nf] = __builtin_amdgcn_mfma_f32_16x16x32_bf16(aH[mf], bL[nf], acc[mf][nf], 0,0,0);
        }
    }
    __syncthreads();
  }

  const int orow0 = m0 + wr*32;
  const int ocol  = n0 + wc*64;
  if (EP == 2){
    #pragma unroll
    for (int nf=0; nf<4; nf++){
      float s = 0.f;
      #pragma unroll
      for (int mf=0; mf<2; mf++)
        #pragma unroll
        for (int r=0; r<4; r++)
          s += delu_f(acc[mf][nf][r] + bias[orow0 + mf*16 + ((lane>>4)<<2) + r]);
      s += __shfl_xor(s, 16, 64);
      s += __shfl_xor(s, 32, 64);
      if (lane < 16) atomicAdd(&qsum[(long)b*NPIX + ocol + nf*16 + fr], s);
    }
  } else {
    #pragma unroll
    for (int mf=0; mf<2; mf++)
      #pragma unroll
      for (int r=0; r<4; r++){
        int row = orow0 + mf*16 + ((lane>>4)<<2) + r;
        float bv = bias ? bias[row] : 0.f;
        #pragma unroll
        for (int nf=0; nf<4; nf++){
          float v = acc[mf][nf][r] + bv;
          if (EP == 1) v = delu_f(v);
          Out[(long)b*outStride + (long)row*NPIX + ocol + nf*16 + fr] = v;
        }
      }
  }
}

// ---------------- composed 3x3 conv via MFMA (K = 9*320), accumulates into Out ----------------
__global__ __launch_bounds__(256) void conv_mfma(
    const unsigned short* __restrict__ Wd3,   // [192][2880] bf16 (rows 160.. zero)
    const unsigned short* __restrict__ Xhi,   // [B][4096][320] bf16
    float* __restrict__ Out)                  // [B][160][4096] +=
{
  __shared__ unsigned short Ah[64][40];
  __shared__ unsigned short Bh[128][40];
  const int b  = blockIdx.z;
  const int m0 = blockIdx.y * 64;
  const int n0 = blockIdx.x * 128;
  const int tid = threadIdx.x;
  const int sRow = tid >> 2, sK = (tid & 3) << 3;
  const int lane = tid & 63, w = tid >> 6;
  const int wr = w >> 1, wc = w & 1;
  const int fr = lane & 15, fko = (lane >> 4) << 3;

  f4 z4 = {0.f,0.f,0.f,0.f};
  f4 acc[2][4];
  #pragma unroll
  for (int mf=0; mf<2; mf++)
    #pragma unroll
    for (int nf=0; nf<4; nf++) acc[mf][nf] = z4;

  for (int t = 0; t < 9; t++){
    const int dh = t/3 - 1, dw = t%3 - 1;
    for (int c0 = 0; c0 < 320; c0 += 32){
      *reinterpret_cast<sh8*>(&Ah[sRow][sK]) =
          *reinterpret_cast<const sh8*>(Wd3 + (long)(m0+sRow)*2880 + t*320 + c0 + sK);
      #pragma unroll
      for (int r=0; r<2; r++){
        int row = r*64 + sRow;
        int p = n0 + row;
        int h = p >> 6, wq = p & 63;
        int hp = h + dh, wp = wq + dw;
        sh8 v = {0,0,0,0,0,0,0,0};
        if (hp >= 0 && hp < 64 && wp >= 0 && wp < 64)
          v = *reinterpret_cast<const sh8*>(Xhi + ((long)b*NPIX + hp*64 + wp)*320 + c0 + sK);
        *reinterpret_cast<sh8*>(&Bh[row][sK]) = v;
      }
      __syncthreads();
      sh8 aH[2], bH[4];
      #pragma unroll
      for (int mf=0; mf<2; mf++)
        aH[mf] = *reinterpret_cast<const sh8*>(&Ah[wr*32 + mf*16 + fr][fko]);
      #pragma unroll
      for (int nf=0; nf<4; nf++)
        bH[nf] = *reinterpret_cast<const sh8*>(&Bh[wc*64 + nf*16 + fr][fko]);
      #pragma unroll
      for (int mf=0; mf<2; mf++)
        #pragma unroll
        for (int nf=0; nf<4; nf++)
          acc[mf][nf] = __builtin_amdgcn_mfma_f32_16x16x32_bf16(aH[mf], bH[nf], acc[mf][nf], 0,0,0);
      __syncthreads();
    }
  }

  const int orow0 = m0 + wr*32;
  const int ocol  = n0 + wc*64;
  #pragma unroll
  for (int mf=0; mf<2; mf++)
    #pragma unroll
    for (int r=0; r<4; r++){
      int row = orow0 + mf*16 + ((lane>>4)<<2) + r;
      if (row < 160){
        #pragma unroll
        for (int nf=0; nf<4; nf++){
          long o = ((long)b*160 + row)*NPIX + ocol + nf*16 + fr;
          Out[o] += acc[mf][nf][r];
        }
      }
    }
}

// ---------------- weight composition kernels ----------------
__global__ void compose1_kernel(const float* __restrict__ av_w, const float* __restrict__ ad1_w,
    const float* __restrict__ ld1_w, const float* __restrict__ wc_w,
    const float* __restrict__ ag, const float* __restrict__ lg, float* __restrict__ Wbig1)
{
  int idx = blockIdx.x*256 + threadIdx.x;
  if (idx >= 320*320) return;
  int r = idx / 320, c = idx % 320;
  float cD = 1.4f*ag[0], cL = 0.3f*lg[0];
  if (r < 160) {
    float s = 0.f;
    for (int j=0;j<320;j++) s += wc_w[r*320+j]*av_w[j*320+c];
    Wbig1[idx] = s;
  } else {
    int o = r - 160;
    float s1 = 0.f, s2 = 0.f;
    for (int j=0;j<320;j++){
      float w = wc_w[o*320+j];
      s1 += w*ad1_w[j*320+c];
      s2 += w*ld1_w[j*320+c];
    }
    Wbig1[idx] = 2.f*wc_w[o*320+c] + cD*s1 + cL*s2;
  }
}

__global__ void bias1_kernel(const float* __restrict__ av_b, const float* __restrict__ ad1_b,
    const float* __restrict__ ad3_b, const float* __restrict__ ld1_b, const float* __restrict__ ld3_b,
    const float* __restrict__ wc_w, const float* __restrict__ wc_b,
    const float* __restrict__ ag, const float* __restrict__ lg, float* __restrict__ bias1)
{
  int r = blockIdx.x*64 + threadIdx.x;
  if (r >= 320) return;
  float cD = 1.4f*ag[0], cL = 0.3f*lg[0];
  if (r < 160){
    float s = 0.f;
    for (int j=0;j<320;j++) s += wc_w[r*320+j]*av_b[j];
    bias1[r] = s;
  } else {
    int o = r - 160;
    float s = wc_b[o];
    for (int j=0;j<320;j++){
      float w = wc_w[o*320+j];
      s += cD*w*(ad1_b[j]+ad3_b[j]) + cL*w*(ld1_b[j]+ld3_b[j]);
    }
    bias1[r] = s;
  }
}

__global__ void composeqk_kernel(const float* __restrict__ aq_w, const float* __restrict__ aq_b,
    const float* __restrict__ ak_w, const float* __restrict__ ak_b,
    const float* __restrict__ w_swin, const float* __restrict__ b_swin,
    const float* __restrict__ w_res, const float* __restrict__ b_res,
    double* __restrict__ Wsw, double* __restrict__ Wres, double* __restrict__ bqk)
{
  int idx = blockIdx.x*256 + threadIdx.x;
  if (idx < 80*192){
    int m = idx/192, j = idx%192;
    const float* aw = (m < 40) ? aq_w + m*320 : ak_w + (m-40)*320;
    double s = 0.0;
    for (int i=0;i<192;i++) s += (double)aw[i]*(double)w_swin[i*192+j];
    Wsw[idx] = s;
  }
  int idx2 = idx - 80*192;
  if (idx2 >= 0 && idx2 < 80*128){
    int m = idx2/128, j = idx2%128;
    const float* aw = (m < 40) ? aq_w + m*320 + 192 : ak_w + (m-40)*320 + 192;
    double s = 0.0;
    for (int i=0;i<128;i++) s += (double)aw[i]*(double)w_res[i*128+j];
    Wres[idx2] = s;
  }
  int idx3 = idx - 80*192 - 80*128;
  if (idx3 >= 0 && idx3 < 80){
    int m = idx3;
    const float* aw = (m < 40) ? aq_w + m*320 : ak_w + (m-40)*320;
    double s = (double)((m < 40) ? aq_b[m] : ak_b[m-40]);
    for (int i=0;i<192;i++) s += (double)aw[i]*(double)b_swin[i];
    for (int i=0;i<128;i++) s += (double)aw[192+i]*(double)b_res[i];
    bqk[m] = s;
  }
}

__global__ void t1_kernel(const float* __restrict__ ad3_w, const float* __restrict__ ld3_w,
    const float* __restrict__ ag, const float* __restrict__ lg, float* __restrict__ Wmix)
{
  long idx = (long)blockIdx.x*256 + threadIdx.x;
  if (idx >= 2880L*320) return;
  int k = (int)(idx / 320), c = (int)(idx % 320);
  int t = k / 320, j = k % 320;
  float cD = 1.4f*ag[0], cL = 0.3f*lg[0];
  long src = (long)(j*320 + c)*9 + t;
  Wmix[idx] = cD*ad3_w[src] + cL*ld3_w[src];
}

// ---------------- conversions ----------------
__global__ void cvt_bf16_kernel(const float* __restrict__ src, unsigned short* __restrict__ dst, int n){
  int i = blockIdx.x*256 + threadIdx.x;
  if (i < n) dst[i] = f2bf(src[i]);
}
__global__ void cvt_split_kernel(const float* __restrict__ src,
    unsigned short* __restrict__ hi, unsigned short* __restrict__ lo, int n){
  int i = blockIdx.x*256 + threadIdx.x;
  if (i < n){
    float v = src[i];
    unsigned short h = f2bf(v);
    hi[i] = h;
    lo[i] = f2bf(v - bf2f(h));
  }
}
__global__ void cvt_pad_kernel(const float* __restrict__ src, unsigned short* __restrict__ dst){
  int i = blockIdx.x*256 + threadIdx.x;
  if (i >= 192*2880) return;
  int row = i / 2880;
  dst[i] = (row < 160) ? f2bf(src[i]) : (unsigned short)0;
}

// ---------------- fp64 q8/k8 ----------------
__global__ __launch_bounds__(256) void qk8_kernel(const double* __restrict__ Wsw,
    const double* __restrict__ Wres, const double* __restrict__ bqk,
    const float* __restrict__ swin, const float* __restrict__ resnet, double* __restrict__ q8d)
{
  int b = blockIdx.z, mb = blockIdx.y*16;
  int n = blockIdx.x*256 + threadIdx.x;
  __shared__ double Ws[16][192];
  __shared__ double Wr[16][128];
  for (int i=threadIdx.x; i<16*192; i+=256) Ws[i/192][i%192] = Wsw[(mb + i/192)*192 + i%192];
  for (int i=threadIdx.x; i<16*128; i+=256) Wr[i/128][i%128] = Wres[(mb + i/128)*128 + i%128];
  __syncthreads();
  double acc[16];
  #pragma unroll
  for (int i=0;i<16;i++) acc[i] = bqk[mb+i];
  const float* sw = swin + (long)b*192*NPIX;
  for (int j=0;j<192;j++){
    double xv = (double)sw[(long)j*NPIX + n];
    #pragma unroll
    for (int i=0;i<16;i++) acc[i] += Ws[i][j]*xv;
  }
  const float* rs = resnet + (long)b*128*NPIX;
  for (int j=0;j<128;j++){
    double xv = (double)rs[(long)j*NPIX + n];
    #pragma unroll
    for (int i=0;i<16;i++) acc[i] += Wr[i][j]*xv;
  }
  #pragma unroll
  for (int i=0;i<16;i++) q8d[((long)b*80 + mb + i)*NPIX + n] = acc[i];
}

// ---------------- reductions ----------------
__global__ void sumk_kernel(const double* __restrict__ q8d, double* __restrict__ sumkd)
{
  int b = blockIdx.y, m = blockIdx.x;
  const double* row = q8d + ((long)b*80 + 40 + m)*NPIX;
  double s = 0.0;
  for (int n=threadIdx.x; n<NPIX; n+=256) s += row[n];
  __shared__ double sd[256];
  sd[threadIdx.x] = s; __syncthreads();
  for (int o=128; o; o>>=1){ if (threadIdx.x < o) sd[threadIdx.x] += sd[threadIdx.x+o]; __syncthreads(); }
  if (threadIdx.x == 0) sumkd[b*40+m] = sd[0];
}

__global__ void colsum_kernel(const float* __restrict__ projL, const float* __restrict__ qsum,
    float* __restrict__ colsum)
{
  int b = blockIdx.y, c = blockIdx.x;
  const float* kl = projL + (long)b*640*NPIX + (long)c*NPIX;
  const float* qs = qsum + (long)b*NPIX;
  double s = 0.0;
  for (int n=threadIdx.x; n<NPIX; n+=256) s += (double)kl[n]*(double)qs[n];
  __shared__ double sd[256];
  sd[threadIdx.x] = s; __syncthreads();
  for (int o=128; o; o>>=1){ if (threadIdx.x < o) sd[threadIdx.x] += sd[threadIdx.x+o]; __syncthreads(); }
  if (threadIdx.x == 0) colsum[b*320+c] = (float)sd[0];
}

__global__ __launch_bounds__(256) void kvp_kernel(const float* __restrict__ proj1,
    const double* __restrict__ q8d, float* __restrict__ kvp)
{
  int b = blockIdx.z, m0 = blockIdx.x*8, o0 = blockIdx.y*32;
  const float* vp = proj1 + (long)b*(320L*NPIX);
  const double* k8 = q8d + ((long)b*80 + 40 + m0)*NPIX;
  __shared__ float ks[8][256];
  __shared__ float vs[32][257];
  int tid = threadIdx.x;
  int mi = tid >> 5, oi = tid & 31;
  float acc = 0.f;
  for (int n0 = 0; n0 < NPIX; n0 += 256){
    for (int r=0;r<8;r++)  ks[r][tid] = (float)k8[(long)r*NPIX + n0 + tid];
    for (int r=0;r<32;r++) vs[r][tid] = vp[(long)(o0+r)*NPIX + n0 + tid];
    __syncthreads();
    #pragma unroll 4
    for (int nn=0;nn<256;nn++) acc = __fmaf_rn(ks[mi][nn], vs[oi][nn], acc);
    __syncthreads();
  }
  kvp[((long)b*40 + m0 + mi)*160 + o0 + oi] = acc;
}

__global__ __launch_bounds__(256) void norm_kernel(const double* __restrict__ q8d,
    const float* __restrict__ projL, const double* __restrict__ sumkd,
    const float* __restrict__ colsum, float* __restrict__ norm_a, float* __restrict__ norm_l)
{
  int b = blockIdx.y;
  int lane = threadIdx.x & 63;
  int g = threadIdx.x >> 6;
  int px = blockIdx.x*64 + lane;
  __shared__ double sk[40];
  __shared__ float cs[320];
  if (threadIdx.x < 40) sk[threadIdx.x] = sumkd[b*40+threadIdx.x] + 1e-10;
  for (int i=threadIdx.x; i<320; i+=256) cs[i] = colsum[b*320+i];
  __syncthreads();
  const double* q8 = q8d + (long)b*80*NPIX;
  const float* kl = projL + (long)b*640*NPIX;
  double da = 0.0, dl = 0.0;
  for (int m=g; m<40;  m+=4) da += q8[(long)m*NPIX + px]*sk[m];
  for (int c=g; c<320; c+=4) dl += (double)kl[(long)c*NPIX + px]*(double)cs[c];
  __shared__ double redA[4][64], redL[4][64];
  redA[g][lane] = da; redL[g][lane] = dl;
  __syncthreads();
  if (g == 0){
    double a = redA[0][lane]+redA[1][lane]+redA[2][lane]+redA[3][lane];
    double l = redL[0][lane]+redL[1][lane]+redL[2][lane]+redL[3][lane];
    norm_a[(long)b*NPIX+px] = (float)(1.0/a);
    norm_l[(long)b*NPIX+px] = (float)(1.0/(l + 1e-10));
  }
}

// ---------------- final fused kernel ----------------
__global__ __launch_bounds__(256) void final_kernel(
    const float* __restrict__ proj1, const float* __restrict__ projL,
    const float* __restrict__ wc_w, const float* __restrict__ colsum,
    const float* __restrict__ kvp, const double* __restrict__ q8d,
    const float* __restrict__ norm_a, const float* __restrict__ norm_l,
    const float* __restrict__ ag, const float* __restrict__ lg,
    float* __restrict__ Out)
{
  __shared__ float Wt[16][64];
  __shared__ float Xt[16][64];
  const int b  = blockIdx.z;
  const int m0 = blockIdx.y * 64;
  const int n0 = blockIdx.x * 64;
  const int tid = threadIdx.x;
  const int tc = tid & 15, tr = tid >> 4;
  const int wm = tid >> 2, wk = (tid & 3) << 2;
  const int xk = tid >> 4, xn = (tid & 15) << 2;
  const float* kl = projL + (long)b*(640L*NPIX);
  const float* vl = kl + 320L*NPIX;
  float acc1[4][4] = {};
  float acc2[4][4] = {};

  for (int k0 = 0; k0 < 320; k0 += 16) {
    float4 wv4;
    if (m0 + wm < 160) {
      wv4 = *reinterpret_cast<const float4*>(wc_w + (long)(m0+wm)*320 + k0 + wk);
      wv4.x *= colsum[b*320 + k0+wk+0];
      wv4.y *= colsum[b*320 + k0+wk+1];
      wv4.z *= colsum[b*320 + k0+wk+2];
      wv4.w *= colsum[b*320 + k0+wk+3];
    } else wv4 = make_float4(0.f,0.f,0.f,0.f);
    Wt[wk+0][wm] = wv4.x; Wt[wk+1][wm] = wv4.y; Wt[wk+2][wm] = wv4.z; Wt[wk+3][wm] = wv4.w;
    float4 k4 = *reinterpret_cast<const float4*>(kl + (long)(k0+xk)*NPIX + n0 + xn);
    float4 v4 = *reinterpret_cast<const float4*>(vl + (long)(k0+xk)*NPIX + n0 + xn);
    *reinterpret_cast<float4*>(&Xt[xk][xn]) =
        make_float4(k4.x*v4.x, k4.y*v4.y, k4.z*v4.z, k4.w*v4.w);
    __syncthreads();
    #pragma unroll
    for (int kk = 0; kk < 16; ++kk) {
      float4 a4 = *reinterpret_cast<const float4*>(&Wt[kk][tr<<2]);
      float4 b4 = *reinterpret_cast<const float4*>(&Xt[kk][tc<<2]);
      float av[4] = {a4.x,a4.y,a4.z,a4.w};
      float bv[4] = {b4.x,b4.y,b4.z,b4.w};
      #pragma unroll
      for (int i=0;i<4;i++)
        #pragma unroll
        for (int j=0;j<4;j++) acc1[i][j] = __fmaf_rn(av[i], bv[j], acc1[i][j]);
    }
    __syncthreads();
  }

  for (int k0 = 0; k0 < 48; k0 += 16) {
    {
      int mm = tid & 63, kks = tid >> 6;
      #pragma unroll
      for (int p=0;p<4;p++){
        int kk = kks + p*4; int kg = k0 + kk; int m = m0 + mm;
        float v = 0.f;
        if (kg < 40 && m < 160) v = kvp[((long)b*40 + kg)*160 + m];
        Wt[kk][mm] = v;
      }
    }
    {
      int kg = k0 + xk;
      float4 q4 = make_float4(0.f,0.f,0.f,0.f);
      if (kg < 40) {
        const double* qr = q8d + ((long)b*80 + kg)*NPIX + n0 + xn;
        q4 = make_float4((float)qr[0],(float)qr[1],(float)qr[2],(float)qr[3]);
      }
      *reinterpret_cast<float4*>(&Xt[xk][xn]) = q4;
    }
    __syncthreads();
    #pragma unroll
    for (int kk = 0; kk < 16; ++kk) {
      float4 a4 = *reinterpret_cast<const float4*>(&Wt[kk][tr<<2]);
      float4 b4 = *reinterpret_cast<const float4*>(&Xt[kk][tc<<2]);
      float av[4] = {a4.x,a4.y,a4.z,a4.w};
      float bv[4] = {b4.x,b4.y,b4.z,b4.w};
      #pragma unroll
      for (int i=0;i<4;i++)
        #pragma unroll
        for (int j=0;j<4;j++) acc2[i][j] = __fmaf_rn(av[i], bv[j], acc2[i][j]);
    }
    __syncthreads();
  }

  const float cA = 0.7f*ag[0], cL = 0.3f*lg[0];
  #pragma unroll
  for (int i=0;i<4;i++){
    int m = m0 + (tr<<2) + i;
    if (m < 160){
      const float* oa = proj1 + (long)b*(320L*NPIX) + (long)(160+m)*NPIX + n0 + (tc<<2);
      float* op = Out + ((long)b*160 + m)*NPIX + n0 + (tc<<2);
      #pragma unroll
      for (int j=0;j<4;j++){
        int n = n0 + (tc<<2) + j;
        op[j] = oa[j] + cL*norm_l[(long)b*NPIX+n]*acc1[i][j]
                      + cA*norm_a[(long)b*NPIX+n]*acc2[i][j];
      }
    }
  }
}

extern "C" void kernel_launch(void* const* d_in, const int* in_sizes, int n_in,
                              void* d_out, int out_size, void* d_ws, size_t ws_size,
                              hipStream_t stream)
{
  const float* swin   = (const float*)d_in[0];
  const float* resnet = (const float*)d_in[1];
  const float* w_swin = (const float*)d_in[2];
  const float* b_swin = (const float*)d_in[3];
  const float* w_res  = (const float*)d_in[4];
  const float* b_res  = (const float*)d_in[5];
  const float* aq_w = (const float*)d_in[6];
  const float* aq_b = (const float*)d_in[7];
  const float* ak_w = (const float*)d_in[8];
  const float* ak_b = (const float*)d_in[9];
  const float* av_w = (const float*)d_in[10];
  const float* av_b = (const float*)d_in[11];
  const float* ad1_w = (const float*)d_in[12];
  const float* ad1_b = (const float*)d_in[13];
  const float* ad3_w = (const float*)d_in[14];
  const float* ad3_b = (const float*)d_in[15];
  const float* ag    = (const float*)d_in[16];
  const float* lq_w = (const float*)d_in[17];
  const float* lq_b = (const float*)d_in[18];
  const float* lk_w = (const float*)d_in[19];
  const float* lk_b = (const float*)d_in[20];
  const float* lv_w = (const float*)d_in[21];
  const float* lv_b = (const float*)d_in[22];
  const float* ld1_w = (const float*)d_in[23];
  const float* ld1_b = (const float*)d_in[24];
  const float* ld3_w = (const float*)d_in[25];
  const float* ld3_b = (const float*)d_in[26];
  const float* lg    = (const float*)d_in[27];
  const float* wc_w = (const float*)d_in[28];
  const float* wc_b = (const float*)d_in[29];
  float* out = (float*)d_out;

  // ---- workspace carve ----
  char* p = (char*)d_ws;
  double* q8d   = (double*)p; p += (size_t)B4*80*NPIX*8;
  double* Wsw   = (double*)p; p += (size_t)80*192*8;
  double* Wres  = (double*)p; p += (size_t)80*128*8;
  double* bqk   = (double*)p; p += (size_t)80*8;
  double* sumkd = (double*)p; p += (size_t)160*8;
  float* proj1  = (float*)p;  p += (size_t)B4*320*NPIX*4;  // rows 0..159 vp, 160..319 outacc
  float* projL  = (float*)p;  p += (size_t)B4*640*NPIX*4;  // rows 0..319 kl, 320..639 vl
  float* qsum   = (float*)p;  p += (size_t)B4*NPIX*4;
  float* norm_a = (float*)p;  p += (size_t)B4*NPIX*4;
  float* norm_l = (float*)p;  p += (size_t)B4*NPIX*4;
  float* colsum = (float*)p;  p += (size_t)B4*320*4;
  float* kvp    = (float*)p;  p += (size_t)B4*40*160*4;
  float* Wbig1  = (float*)p;  p += (size_t)320*320*4;
  float* bias1  = (float*)p;  p += (size_t)320*4;
  float* Wmix   = (float*)p;  p += (size_t)2880*320*4;
  float* Wd3eff = (float*)p;  p += (size_t)160*2880*4;
  p = (char*)(((uintptr_t)p + 255) & ~(uintptr_t)255);
  unsigned short* xTh  = (unsigned short*)p; p += (size_t)B4*NPIX*320*2;
  unsigned short* xTl  = (unsigned short*)p; p += (size_t)B4*NPIX*320*2;
  unsigned short* Wb1h = (unsigned short*)p; p += (size_t)320*320*2;
  unsigned short* Wb1l = (unsigned short*)p; p += (size_t)320*320*2;
  unsigned short* lqh  = (unsigned short*)p; p += (size_t)320*320*2;
  unsigned short* lkh  = (unsigned short*)p; p += (size_t)320*320*2;
  unsigned short* lvh  = (unsigned short*)p; p += (size_t)320*320*2;
  unsigned short* Wd3b = (unsigned short*)p; p += (size_t)192*2880*2;
  if ((size_t)(p - (char*)d_ws) > ws_size) return;

  hipMemsetAsync(qsum, 0, (size_t)B4*NPIX*4, stream);

  // ---- weight composition (fp32 / fp64) ----
  composeqk_kernel<<<(80*192 + 80*128 + 80 + 255)/256, 256, 0, stream>>>(
      aq_w, aq_b, ak_w, ak_b, w_swin, b_swin, w_res, b_res, Wsw, Wres, bqk);
  compose1_kernel<<<(320*320 + 255)/256, 256, 0, stream>>>(av_w, ad1_w, ld1_w, wc_w, ag, lg, Wbig1);
  bias1_kernel<<<5, 64, 0, stream>>>(av_b, ad1_b, ad3_b, ld1_b, ld3_b, wc_w, wc_b, ag, lg, bias1);
  t1_kernel<<<(2880*320 + 255)/256, 256, 0, stream>>>(ad3_w, ld3_w, ag, lg, Wmix);
  gemm_f32<0><<<dim3(5,3,9), 256, 0, stream>>>(wc_w, nullptr, Wmix, 320L*320, 320,
      Wd3eff, 320, 2880, 160, 320, nullptr, nullptr, 0);

  // ---- weight bf16 conversions ----
  cvt_split_kernel<<<(320*320 + 255)/256, 256, 0, stream>>>(Wbig1, Wb1h, Wb1l, 320*320);
  cvt_bf16_kernel<<<(320*320 + 255)/256, 256, 0, stream>>>(lq_w, lqh, 320*320);
  cvt_bf16_kernel<<<(320*320 + 255)/256, 256, 0, stream>>>(lk_w, lkh, 320*320);
  cvt_bf16_kernel<<<(320*320 + 255)/256, 256, 0, stream>>>(lv_w, lvh, 320*320);
  cvt_pad_kernel<<<(192*2880 + 255)/256, 256, 0, stream>>>(Wd3eff, Wd3b);

  // ---- x = concat(w_swin@swin+b, w_res@res+b), written directly as transposed bf16 hi/lo ----
  gemm_f32<3><<<dim3(64,3,4), 256, 0, stream>>>(w_swin, b_swin, swin, 192L*NPIX, NPIX,
      nullptr, 0, 0, 192, 192, xTh, xTl, 0);
  gemm_f32<3><<<dim3(64,2,4), 256, 0, stream>>>(w_res, b_res, resnet, 128L*NPIX, NPIX,
      nullptr, 0, 0, 128, 128, xTh, xTl, 192);

  // ---- fp64 q8/k8 path ----
  qk8_kernel<<<dim3(16,5,4), 256, 0, stream>>>(Wsw, Wres, bqk, swin, resnet, q8d);

  // ---- MFMA projections ----
  gemm_mfma<0,1><<<dim3(32,5,4), 256, 0, stream>>>(Wb1h, Wb1l, bias1, xTh, xTl,
      proj1, 320L*NPIX, nullptr);
  gemm_mfma<2,0><<<dim3(32,5,4), 256, 0, stream>>>(lqh, nullptr, lq_b, xTh, nullptr,
      nullptr, 0, qsum);
  gemm_mfma<1,0><<<dim3(32,5,4), 256, 0, stream>>>(lkh, nullptr, lk_b, xTh, nullptr,
      projL, 640L*NPIX, nullptr);
  gemm_mfma<0,0><<<dim3(32,5,4), 256, 0, stream>>>(lvh, nullptr, lv_b, xTh, nullptr,
      projL + 320L*NPIX, 640L*NPIX, nullptr);

  // ---- reductions ----
  sumk_kernel<<<dim3(40,4), 256, 0, stream>>>(q8d, sumkd);
  kvp_kernel<<<dim3(5,5,4), 256, 0, stream>>>(proj1, q8d, kvp);
  colsum_kernel<<<dim3(320,4), 256, 0, stream>>>(projL, qsum, colsum);
  norm_kernel<<<dim3(64,4), 256, 0, stream>>>(q8d, projL, sumkd, colsum, norm_a, norm_l);

  // ---- fused epilogue + composed conv ----
  final_kernel<<<dim3(64,3,4), 256, 0, stream>>>(proj1, projL, wc_w, colsum, kvp, q8d,
                                                 norm_a, norm_l, ag, lg, out);
  conv_mfma<<<dim3(32,3,4), 256, 0, stream>>>(Wd3b, xTh, out);
}

// Round 3
// 514.891 us; speedup vs baseline: 1.7304x; 1.0594x over previous
//
#include <hip/hip_runtime.h>
#include <stdint.h>

#define B4 4
#define NPIX 4096

typedef short sh8 __attribute__((ext_vector_type(8)));
typedef float f4 __attribute__((ext_vector_type(4)));

__device__ __forceinline__ float delu_f(float v){
  return v > 0.f ? __fmaf_rn(10.f, v, 1.f) : __expf(10.f*v);
}
__device__ __forceinline__ unsigned short f2bf(float f){
  unsigned u = __float_as_uint(f);
  u += 0x7fffu + ((u>>16)&1u);
  return (unsigned short)(u>>16);
}
__device__ __forceinline__ float bf2f(unsigned short h){
  return __uint_as_float(((unsigned)h)<<16);
}

// ---------------- generic 64x64x16 f32 tile GEMM (weight-compose only now) ----------------
__global__ __launch_bounds__(256) void gemm_f32(
    const float* __restrict__ W, const float* __restrict__ bias,
    const float* __restrict__ X, long xStride, int ldX,
    float* __restrict__ Out, long outStride, int ldOut,
    int M, int K)
{
  __shared__ float Wt[16][64];
  __shared__ float Xt[16][64];
  const int b  = blockIdx.z;
  const int m0 = blockIdx.y * 64;
  const int n0 = blockIdx.x * 64;
  const int tid = threadIdx.x;
  const int tc = tid & 15, tr = tid >> 4;
  const int wm = tid >> 2, wk = (tid & 3) << 2;
  const int xk = tid >> 4, xn = (tid & 15) << 2;
  const float* Xb = X + (long)b * xStride;
  float acc[4][4] = {};

  for (int k0 = 0; k0 < K; k0 += 16) {
    float4 wv4;
    if (m0 + wm < M) wv4 = *reinterpret_cast<const float4*>(W + (long)(m0+wm)*K + k0 + wk);
    else wv4 = make_float4(0.f,0.f,0.f,0.f);
    Wt[wk+0][wm] = wv4.x; Wt[wk+1][wm] = wv4.y; Wt[wk+2][wm] = wv4.z; Wt[wk+3][wm] = wv4.w;
    *reinterpret_cast<float4*>(&Xt[xk][xn]) =
        *reinterpret_cast<const float4*>(Xb + (long)(k0+xk)*ldX + n0 + xn);
    __syncthreads();
    #pragma unroll
    for (int kk = 0; kk < 16; ++kk) {
      float4 a4 = *reinterpret_cast<const float4*>(&Wt[kk][tr<<2]);
      float4 b4 = *reinterpret_cast<const float4*>(&Xt[kk][tc<<2]);
      float av[4] = {a4.x,a4.y,a4.z,a4.w};
      float bv[4] = {b4.x,b4.y,b4.z,b4.w};
      #pragma unroll
      for (int i=0;i<4;i++)
        #pragma unroll
        for (int j=0;j<4;j++) acc[i][j] = __fmaf_rn(av[i], bv[j], acc[i][j]);
    }
    __syncthreads();
  }

  #pragma unroll
  for (int i=0;i<4;i++){
    int m = m0 + (tr<<2) + i;
    if (m < M) {
      float bv = bias ? bias[m] : 0.f;
      float r[4];
      #pragma unroll
      for (int j=0;j<4;j++) r[j] = acc[i][j] + bv;
      *reinterpret_cast<float4*>(Out + (long)b*outStride + (long)m*ldOut + n0 + (tc<<2)) =
          make_float4(r[0],r[1],r[2],r[3]);
    }
  }
}

// ---------------- bf16 MFMA GEMM: C[m][n] = sum_k W[m][k] * xT[n][k] ----------------
// tile 64(m) x 128(n) x 32(k), 4 waves (2x2). xT layout: [B][4096][320] bf16.
// EP: 0 = store acc+bias (fp32); 1 = store delu(acc+bias); 2 = delu, column-sum -> atomicAdd qsum
// SPLIT: 1 = 3-pass hi/lo (near-fp32), 0 = single pass (hi only)
template<int EP, int SPLIT>
__global__ __launch_bounds__(256) void gemm_mfma(
    const unsigned short* __restrict__ Whi, const unsigned short* __restrict__ Wlo,
    const float* __restrict__ bias,
    const unsigned short* __restrict__ Xhi, const unsigned short* __restrict__ Xlo,
    float* __restrict__ Out, long outStride, float* __restrict__ qsum)
{
  __shared__ unsigned short Ah[64][40];
  __shared__ unsigned short Bh[128][40];
  __shared__ unsigned short Al[SPLIT?64:8][40];
  __shared__ unsigned short Bl[SPLIT?128:8][40];
  const int b  = blockIdx.z;
  const int m0 = blockIdx.y * 64;
  const int n0 = blockIdx.x * 128;
  const int tid = threadIdx.x;
  const int sRow = tid >> 2, sK = (tid & 3) << 3;
  const int lane = tid & 63, w = tid >> 6;
  const int wr = w >> 1, wc = w & 1;
  const int fr = lane & 15, fko = (lane >> 4) << 3;

  f4 z4 = {0.f,0.f,0.f,0.f};
  f4 acc[2][4];
  #pragma unroll
  for (int mf=0; mf<2; mf++)
    #pragma unroll
    for (int nf=0; nf<4; nf++) acc[mf][nf] = z4;

  for (int k0 = 0; k0 < 320; k0 += 32) {
    *reinterpret_cast<sh8*>(&Ah[sRow][sK]) =
        *reinterpret_cast<const sh8*>(Whi + (long)(m0+sRow)*320 + k0 + sK);
    if (SPLIT)
      *reinterpret_cast<sh8*>(&Al[sRow][sK]) =
          *reinterpret_cast<const sh8*>(Wlo + (long)(m0+sRow)*320 + k0 + sK);
    #pragma unroll
    for (int r=0; r<2; r++){
      int row = r*64 + sRow;
      long src = ((long)b*NPIX + n0 + row)*320 + k0 + sK;
      *reinterpret_cast<sh8*>(&Bh[row][sK]) = *reinterpret_cast<const sh8*>(Xhi + src);
      if (SPLIT)
        *reinterpret_cast<sh8*>(&Bl[row][sK]) = *reinterpret_cast<const sh8*>(Xlo + src);
    }
    __syncthreads();
    sh8 aH[2], bH[4];
    #pragma unroll
    for (int mf=0; mf<2; mf++)
      aH[mf] = *reinterpret_cast<const sh8*>(&Ah[wr*32 + mf*16 + fr][fko]);
    #pragma unroll
    for (int nf=0; nf<4; nf++)
      bH[nf] = *reinterpret_cast<const sh8*>(&Bh[wc*64 + nf*16 + fr][fko]);
    #pragma unroll
    for (int mf=0; mf<2; mf++)
      #pragma unroll
      for (int nf=0; nf<4; nf++)
        acc[mf][nf] = __builtin_amdgcn_mfma_f32_16x16x32_bf16(aH[mf], bH[nf], acc[mf][nf], 0,0,0);
    if (SPLIT){
      sh8 aL[2], bL[4];
      #pragma unroll
      for (int mf=0; mf<2; mf++)
        aL[mf] = *reinterpret_cast<const sh8*>(&Al[wr*32 + mf*16 + fr][fko]);
      #pragma unroll
      for (int nf=0; nf<4; nf++)
        bL[nf] = *reinterpret_cast<const sh8*>(&Bl[wc*64 + nf*16 + fr][fko]);
      #pragma unroll
      for (int mf=0; mf<2; mf++)
        #pragma unroll
        for (int nf=0; nf<4; nf++){
          acc[mf][nf] = __builtin_amdgcn_mfma_f32_16x16x32_bf16(aL[mf], bH[nf], acc[mf][nf], 0,0,0);
          acc[mf][nf] = __builtin_amdgcn_mfma_f32_16x16x32_bf16(aH[mf], bL[nf], acc[mf][nf], 0,0,0);
        }
    }
    __syncthreads();
  }

  const int orow0 = m0 + wr*32;
  const int ocol  = n0 + wc*64;
  if (EP == 2){
    #pragma unroll
    for (int nf=0; nf<4; nf++){
      float s = 0.f;
      #pragma unroll
      for (int mf=0; mf<2; mf++)
        #pragma unroll
        for (int r=0; r<4; r++)
          s += delu_f(acc[mf][nf][r] + bias[orow0 + mf*16 + ((lane>>4)<<2) + r]);
      s += __shfl_xor(s, 16, 64);
      s += __shfl_xor(s, 32, 64);
      if (lane < 16) atomicAdd(&qsum[(long)b*NPIX + ocol + nf*16 + fr], s);
    }
  } else {
    #pragma unroll
    for (int mf=0; mf<2; mf++)
      #pragma unroll
      for (int r=0; r<4; r++){
        int row = orow0 + mf*16 + ((lane>>4)<<2) + r;
        float bv = bias ? bias[row] : 0.f;
        #pragma unroll
        for (int nf=0; nf<4; nf++){
          float v = acc[mf][nf][r] + bv;
          if (EP == 1) v = delu_f(v);
          Out[(long)b*outStride + (long)row*NPIX + ocol + nf*16 + fr] = v;
        }
      }
  }
}

// ---------------- x-build MFMA: role-flipped (A = pixels, B = weight rows), 3-pass split ----------------
// xT[pixel][tOff+o] = sum_k inT[pixel][cOff+k] * W[o][k] + bias[o], written as bf16 hi/lo.
__global__ __launch_bounds__(256) void xbuild_mfma(
    const unsigned short* __restrict__ inThi, const unsigned short* __restrict__ inTlo,
    int cOff, int K,
    const unsigned short* __restrict__ Wh, const unsigned short* __restrict__ Wl,
    const float* __restrict__ bias, int outC, int tOff,
    unsigned short* __restrict__ xTh, unsigned short* __restrict__ xTl)
{
  __shared__ unsigned short Ah[64][40];
  __shared__ unsigned short Bh[128][40];
  __shared__ unsigned short Al[64][40];
  __shared__ unsigned short Bl[128][40];
  const int b  = blockIdx.z;
  const int m0 = blockIdx.y * 64;     // pixel tile
  const int n0 = blockIdx.x * 128;    // out-channel tile
  const int tid = threadIdx.x;
  const int sRow = tid >> 2, sK = (tid & 3) << 3;
  const int lane = tid & 63, w = tid >> 6;
  const int wr = w >> 1, wc = w & 1;
  const int fr = lane & 15, fko = (lane >> 4) << 3;

  f4 z4 = {0.f,0.f,0.f,0.f};
  f4 acc[2][4];
  #pragma unroll
  for (int mf=0; mf<2; mf++)
    #pragma unroll
    for (int nf=0; nf<4; nf++) acc[mf][nf] = z4;

  for (int k0 = 0; k0 < K; k0 += 32) {
    long asrc = ((long)b*NPIX + m0 + sRow)*320 + cOff + k0 + sK;
    *reinterpret_cast<sh8*>(&Ah[sRow][sK]) = *reinterpret_cast<const sh8*>(inThi + asrc);
    *reinterpret_cast<sh8*>(&Al[sRow][sK]) = *reinterpret_cast<const sh8*>(inTlo + asrc);
    #pragma unroll
    for (int r=0; r<2; r++){
      int row = r*64 + sRow;
      sh8 vh = {0,0,0,0,0,0,0,0}, vl = {0,0,0,0,0,0,0,0};
      if (n0 + row < outC){
        vh = *reinterpret_cast<const sh8*>(Wh + (long)(n0+row)*K + k0 + sK);
        vl = *reinterpret_cast<const sh8*>(Wl + (long)(n0+row)*K + k0 + sK);
      }
      *reinterpret_cast<sh8*>(&Bh[row][sK]) = vh;
      *reinterpret_cast<sh8*>(&Bl[row][sK]) = vl;
    }
    __syncthreads();
    sh8 aH[2], aL[2], bH[4], bL[4];
    #pragma unroll
    for (int mf=0; mf<2; mf++){
      aH[mf] = *reinterpret_cast<const sh8*>(&Ah[wr*32 + mf*16 + fr][fko]);
      aL[mf] = *reinterpret_cast<const sh8*>(&Al[wr*32 + mf*16 + fr][fko]);
    }
    #pragma unroll
    for (int nf=0; nf<4; nf++){
      bH[nf] = *reinterpret_cast<const sh8*>(&Bh[wc*64 + nf*16 + fr][fko]);
      bL[nf] = *reinterpret_cast<const sh8*>(&Bl[wc*64 + nf*16 + fr][fko]);
    }
    #pragma unroll
    for (int mf=0; mf<2; mf++)
      #pragma unroll
      for (int nf=0; nf<4; nf++){
        acc[mf][nf] = __builtin_amdgcn_mfma_f32_16x16x32_bf16(aH[mf], bH[nf], acc[mf][nf], 0,0,0);
        acc[mf][nf] = __builtin_amdgcn_mfma_f32_16x16x32_bf16(aH[mf], bL[nf], acc[mf][nf], 0,0,0);
        acc[mf][nf] = __builtin_amdgcn_mfma_f32_16x16x32_bf16(aL[mf], bH[nf], acc[mf][nf], 0,0,0);
      }
    __syncthreads();
  }

  const int opix0 = m0 + wr*32;
  const int ocol  = n0 + wc*64;
  #pragma unroll
  for (int mf=0; mf<2; mf++)
    #pragma unroll
    for (int r=0; r<4; r++){
      int pix = opix0 + mf*16 + ((lane>>4)<<2) + r;
      #pragma unroll
      for (int nf=0; nf<4; nf++){
        int col = ocol + nf*16 + fr;
        if (col < outC){
          float v = acc[mf][nf][r] + bias[col];
          unsigned short h = f2bf(v);
          long o = ((long)b*NPIX + pix)*320 + tOff + col;
          xTh[o] = h;
          xTl[o] = f2bf(v - bf2f(h));
        }
      }
    }
}

// ---------------- final MFMA: out = outacc + cL*norm_l*(W2@pT) + cA*norm_a*(kvpT@q8) ----------------
__global__ __launch_bounds__(256) void final_mfma(
    const unsigned short* __restrict__ W2h,   // [B][160][320] bf16 (wc*colsum)
    const unsigned short* __restrict__ pT,    // [B][4096][320] bf16 (kl*vl)^T
    const float* __restrict__ kvp,            // [B][40][160]
    const double* __restrict__ q8d,           // [B][80][4096]
    const float* __restrict__ proj1,
    const float* __restrict__ norm_a, const float* __restrict__ norm_l,
    const float* __restrict__ ag, const float* __restrict__ lg,
    float* __restrict__ Out)
{
  __shared__ unsigned short Ah[64][40];
  __shared__ unsigned short Bh[128][40];
  __shared__ unsigned short Al[64][40];
  __shared__ unsigned short Bl[128][40];
  const int b  = blockIdx.z;
  const int m0 = blockIdx.y * 64;
  const int n0 = blockIdx.x * 128;
  const int tid = threadIdx.x;
  const int sRow = tid >> 2, sK = (tid & 3) << 3;
  const int lane = tid & 63, w = tid >> 6;
  const int wr = w >> 1, wc = w & 1;
  const int fr = lane & 15, fko = (lane >> 4) << 3;

  f4 z4 = {0.f,0.f,0.f,0.f};
  f4 acc1[2][4], acc2[2][4];
  #pragma unroll
  for (int mf=0; mf<2; mf++)
    #pragma unroll
    for (int nf=0; nf<4; nf++){ acc1[mf][nf] = z4; acc2[mf][nf] = z4; }

  // phase 1: K=320, single-pass bf16
  for (int k0 = 0; k0 < 320; k0 += 32) {
    sh8 av = {0,0,0,0,0,0,0,0};
    if (m0 + sRow < 160)
      av = *reinterpret_cast<const sh8*>(W2h + ((long)b*160 + m0 + sRow)*320 + k0 + sK);
    *reinterpret_cast<sh8*>(&Ah[sRow][sK]) = av;
    #pragma unroll
    for (int r=0; r<2; r++){
      int row = r*64 + sRow;
      *reinterpret_cast<sh8*>(&Bh[row][sK]) =
          *reinterpret_cast<const sh8*>(pT + ((long)b*NPIX + n0 + row)*320 + k0 + sK);
    }
    __syncthreads();
    sh8 aH[2], bH[4];
    #pragma unroll
    for (int mf=0; mf<2; mf++)
      aH[mf] = *reinterpret_cast<const sh8*>(&Ah[wr*32 + mf*16 + fr][fko]);
    #pragma unroll
    for (int nf=0; nf<4; nf++)
      bH[nf] = *reinterpret_cast<const sh8*>(&Bh[wc*64 + nf*16 + fr][fko]);
    #pragma unroll
    for (int mf=0; mf<2; mf++)
      #pragma unroll
      for (int nf=0; nf<4; nf++)
        acc1[mf][nf] = __builtin_amdgcn_mfma_f32_16x16x32_bf16(aH[mf], bH[nf], acc1[mf][nf], 0,0,0);
    __syncthreads();
  }

  // phase 2: K=64 (40 valid), 3-pass hi/lo split, operands converted in staging
  for (int k0 = 0; k0 < 64; k0 += 32) {
    {
      int m = m0 + sRow;
      #pragma unroll
      for (int i=0;i<8;i++){
        int kk = k0 + sK + i;
        float v = (kk < 40 && m < 160) ? kvp[((long)b*40 + kk)*160 + m] : 0.f;
        unsigned short h = f2bf(v);
        Ah[sRow][sK+i] = h;
        Al[sRow][sK+i] = f2bf(v - bf2f(h));
      }
    }
    #pragma unroll
    for (int r=0; r<2; r++){
      int row = r*64 + sRow;
      int pix = n0 + row;
      #pragma unroll
      for (int i=0;i<8;i++){
        int kk = k0 + sK + i;
        float v = (kk < 40) ? (float)q8d[((long)b*80 + kk)*NPIX + pix] : 0.f;
        unsigned short h = f2bf(v);
        Bh[row][sK+i] = h;
        Bl[row][sK+i] = f2bf(v - bf2f(h));
      }
    }
    __syncthreads();
    sh8 aH[2], aL[2], bH[4], bL[4];
    #pragma unroll
    for (int mf=0; mf<2; mf++){
      aH[mf] = *reinterpret_cast<const sh8*>(&Ah[wr*32 + mf*16 + fr][fko]);
      aL[mf] = *reinterpret_cast<const sh8*>(&Al[wr*32 + mf*16 + fr][fko]);
    }
    #pragma unroll
    for (int nf=0; nf<4; nf++){
      bH[nf] = *reinterpret_cast<const sh8*>(&Bh[wc*64 + nf*16 + fr][fko]);
      bL[nf] = *reinterpret_cast<const sh8*>(&Bl[wc*64 + nf*16 + fr][fko]);
    }
    #pragma unroll
    for (int mf=0; mf<2; mf++)
      #pragma unroll
      for (int nf=0; nf<4; nf++){
        acc2[mf][nf] = __builtin_amdgcn_mfma_f32_16x16x32_bf16(aH[mf], bH[nf], acc2[mf][nf], 0,0,0);
        acc2[mf][nf] = __builtin_amdgcn_mfma_f32_16x16x32_bf16(aH[mf], bL[nf], acc2[mf][nf], 0,0,0);
        acc2[mf][nf] = __builtin_amdgcn_mfma_f32_16x16x32_bf16(aL[mf], bH[nf], acc2[mf][nf], 0,0,0);
      }
    __syncthreads();
  }

  const float cA = 0.7f*ag[0], cL = 0.3f*lg[0];
  const int orow0 = m0 + wr*32;
  const int ocol  = n0 + wc*64;
  #pragma unroll
  for (int mf=0; mf<2; mf++)
    #pragma unroll
    for (int r=0; r<4; r++){
      int row = orow0 + mf*16 + ((lane>>4)<<2) + r;
      if (row < 160){
        const float* oa = proj1 + (long)b*(320L*NPIX) + (long)(160+row)*NPIX;
        #pragma unroll
        for (int nf=0; nf<4; nf++){
          int col = ocol + nf*16 + fr;
          Out[((long)b*160 + row)*NPIX + col] =
              oa[col] + cL*norm_l[(long)b*NPIX+col]*acc1[mf][nf][r]
                      + cA*norm_a[(long)b*NPIX+col]*acc2[mf][nf][r];
        }
      }
    }
}

// ---------------- composed 3x3 conv via MFMA (K = 9*320), accumulates into Out ----------------
__global__ __launch_bounds__(256) void conv_mfma(
    const unsigned short* __restrict__ Wd3,   // [192][2880] bf16 (rows 160.. zero)
    const unsigned short* __restrict__ Xhi,   // [B][4096][320] bf16
    float* __restrict__ Out)                  // [B][160][4096] +=
{
  __shared__ unsigned short Ah[64][40];
  __shared__ unsigned short Bh[128][40];
  const int b  = blockIdx.z;
  const int m0 = blockIdx.y * 64;
  const int n0 = blockIdx.x * 128;
  const int tid = threadIdx.x;
  const int sRow = tid >> 2, sK = (tid & 3) << 3;
  const int lane = tid & 63, w = tid >> 6;
  const int wr = w >> 1, wc = w & 1;
  const int fr = lane & 15, fko = (lane >> 4) << 3;

  f4 z4 = {0.f,0.f,0.f,0.f};
  f4 acc[2][4];
  #pragma unroll
  for (int mf=0; mf<2; mf++)
    #pragma unroll
    for (int nf=0; nf<4; nf++) acc[mf][nf] = z4;

  for (int t = 0; t < 9; t++){
    const int dh = t/3 - 1, dw = t%3 - 1;
    for (int c0 = 0; c0 < 320; c0 += 32){
      *reinterpret_cast<sh8*>(&Ah[sRow][sK]) =
          *reinterpret_cast<const sh8*>(Wd3 + (long)(m0+sRow)*2880 + t*320 + c0 + sK);
      #pragma unroll
      for (int r=0; r<2; r++){
        int row = r*64 + sRow;
        int p = n0 + row;
        int h = p >> 6, wq = p & 63;
        int hp = h + dh, wp = wq + dw;
        sh8 v = {0,0,0,0,0,0,0,0};
        if (hp >= 0 && hp < 64 && wp >= 0 && wp < 64)
          v = *reinterpret_cast<const sh8*>(Xhi + ((long)b*NPIX + hp*64 + wp)*320 + c0 + sK);
        *reinterpret_cast<sh8*>(&Bh[row][sK]) = v;
      }
      __syncthreads();
      sh8 aH[2], bH[4];
      #pragma unroll
      for (int mf=0; mf<2; mf++)
        aH[mf] = *reinterpret_cast<const sh8*>(&Ah[wr*32 + mf*16 + fr][fko]);
      #pragma unroll
      for (int nf=0; nf<4; nf++)
        bH[nf] = *reinterpret_cast<const sh8*>(&Bh[wc*64 + nf*16 + fr][fko]);
      #pragma unroll
      for (int mf=0; mf<2; mf++)
        #pragma unroll
        for (int nf=0; nf<4; nf++)
          acc[mf][nf] = __builtin_amdgcn_mfma_f32_16x16x32_bf16(aH[mf], bH[nf], acc[mf][nf], 0,0,0);
      __syncthreads();
    }
  }

  const int orow0 = m0 + wr*32;
  const int ocol  = n0 + wc*64;
  #pragma unroll
  for (int mf=0; mf<2; mf++)
    #pragma unroll
    for (int r=0; r<4; r++){
      int row = orow0 + mf*16 + ((lane>>4)<<2) + r;
      if (row < 160){
        #pragma unroll
        for (int nf=0; nf<4; nf++){
          long o = ((long)b*160 + row)*NPIX + ocol + nf*16 + fr;
          Out[o] += acc[mf][nf][r];
        }
      }
    }
}

// ---------------- weight composition kernels ----------------
__global__ void compose1_kernel(const float* __restrict__ av_w, const float* __restrict__ ad1_w,
    const float* __restrict__ ld1_w, const float* __restrict__ wc_w,
    const float* __restrict__ ag, const float* __restrict__ lg, float* __restrict__ Wbig1)
{
  int idx = blockIdx.x*256 + threadIdx.x;
  if (idx >= 320*320) return;
  int r = idx / 320, c = idx % 320;
  float cD = 1.4f*ag[0], cL = 0.3f*lg[0];
  if (r < 160) {
    float s = 0.f;
    for (int j=0;j<320;j++) s += wc_w[r*320+j]*av_w[j*320+c];
    Wbig1[idx] = s;
  } else {
    int o = r - 160;
    float s1 = 0.f, s2 = 0.f;
    for (int j=0;j<320;j++){
      float w = wc_w[o*320+j];
      s1 += w*ad1_w[j*320+c];
      s2 += w*ld1_w[j*320+c];
    }
    Wbig1[idx] = 2.f*wc_w[o*320+c] + cD*s1 + cL*s2;
  }
}

__global__ void bias1_kernel(const float* __restrict__ av_b, const float* __restrict__ ad1_b,
    const float* __restrict__ ad3_b, const float* __restrict__ ld1_b, const float* __restrict__ ld3_b,
    const float* __restrict__ wc_w, const float* __restrict__ wc_b,
    const float* __restrict__ ag, const float* __restrict__ lg, float* __restrict__ bias1)
{
  int r = blockIdx.x*64 + threadIdx.x;
  if (r >= 320) return;
  float cD = 1.4f*ag[0], cL = 0.3f*lg[0];
  if (r < 160){
    float s = 0.f;
    for (int j=0;j<320;j++) s += wc_w[r*320+j]*av_b[j];
    bias1[r] = s;
  } else {
    int o = r - 160;
    float s = wc_b[o];
    for (int j=0;j<320;j++){
      float w = wc_w[o*320+j];
      s += cD*w*(ad1_b[j]+ad3_b[j]) + cL*w*(ld1_b[j]+ld3_b[j]);
    }
    bias1[r] = s;
  }
}

__global__ void composeqk_kernel(const float* __restrict__ aq_w, const float* __restrict__ aq_b,
    const float* __restrict__ ak_w, const float* __restrict__ ak_b,
    const float* __restrict__ w_swin, const float* __restrict__ b_swin,
    const float* __restrict__ w_res, const float* __restrict__ b_res,
    double* __restrict__ Wsw, double* __restrict__ Wres, double* __restrict__ bqk)
{
  int idx = blockIdx.x*256 + threadIdx.x;
  if (idx < 80*192){
    int m = idx/192, j = idx%192;
    const float* aw = (m < 40) ? aq_w + m*320 : ak_w + (m-40)*320;
    double s = 0.0;
    for (int i=0;i<192;i++) s += (double)aw[i]*(double)w_swin[i*192+j];
    Wsw[idx] = s;
  }
  int idx2 = idx - 80*192;
  if (idx2 >= 0 && idx2 < 80*128){
    int m = idx2/128, j = idx2%128;
    const float* aw = (m < 40) ? aq_w + m*320 + 192 : ak_w + (m-40)*320 + 192;
    double s = 0.0;
    for (int i=0;i<128;i++) s += (double)aw[i]*(double)w_res[i*128+j];
    Wres[idx2] = s;
  }
  int idx3 = idx - 80*192 - 80*128;
  if (idx3 >= 0 && idx3 < 80){
    int m = idx3;
    const float* aw = (m < 40) ? aq_w + m*320 : ak_w + (m-40)*320;
    double s = (double)((m < 40) ? aq_b[m] : ak_b[m-40]);
    for (int i=0;i<192;i++) s += (double)aw[i]*(double)b_swin[i];
    for (int i=0;i<128;i++) s += (double)aw[192+i]*(double)b_res[i];
    bqk[m] = s;
  }
}

__global__ void t1_kernel(const float* __restrict__ ad3_w, const float* __restrict__ ld3_w,
    const float* __restrict__ ag, const float* __restrict__ lg, float* __restrict__ Wmix)
{
  long idx = (long)blockIdx.x*256 + threadIdx.x;
  if (idx >= 2880L*320) return;
  int k = (int)(idx / 320), c = (int)(idx % 320);
  int t = k / 320, j = k % 320;
  float cD = 1.4f*ag[0], cL = 0.3f*lg[0];
  long src = (long)(j*320 + c)*9 + t;
  Wmix[idx] = cD*ad3_w[src] + cL*ld3_w[src];
}

// ---------------- conversions ----------------
__global__ void cvt_bf16_kernel(const float* __restrict__ src, unsigned short* __restrict__ dst, int n){
  int i = blockIdx.x*256 + threadIdx.x;
  if (i < n) dst[i] = f2bf(src[i]);
}
__global__ void cvt_split_kernel(const float* __restrict__ src,
    unsigned short* __restrict__ hi, unsigned short* __restrict__ lo, int n){
  int i = blockIdx.x*256 + threadIdx.x;
  if (i < n){
    float v = src[i];
    unsigned short h = f2bf(v);
    hi[i] = h;
    lo[i] = f2bf(v - bf2f(h));
  }
}
__global__ void cvt_pad_kernel(const float* __restrict__ src, unsigned short* __restrict__ dst){
  int i = blockIdx.x*256 + threadIdx.x;
  if (i >= 192*2880) return;
  int row = i / 2880;
  dst[i] = (row < 160) ? f2bf(src[i]) : (unsigned short)0;
}

// inT: transpose raw inputs to [B][4096][320] bf16 hi/lo (cols 0..191 swin, 192..319 res)
__global__ __launch_bounds__(256) void inT_kernel(
    const float* __restrict__ swin, const float* __restrict__ resnet,
    unsigned short* __restrict__ inThi, unsigned short* __restrict__ inTlo)
{
  __shared__ float t[64][65];
  const int b = blockIdx.z, ct = blockIdx.y, n0 = blockIdx.x*64;
  const float* src; int C, cs0;
  if (ct < 3){ src = swin;   C = 192; cs0 = ct*64; }
  else       { src = resnet; C = 128; cs0 = (ct-3)*64; }
  const int dst0 = ct*64;
  const int tid = threadIdx.x;
  #pragma unroll
  for (int it=0; it<16; ++it){
    int idx = it*256 + tid;
    int c = idx >> 6, n = idx & 63;
    t[c][n] = src[((long)b*C + cs0 + c)*NPIX + n0 + n];
  }
  __syncthreads();
  #pragma unroll
  for (int it=0; it<16; ++it){
    int idx = it*256 + tid;
    int n = idx >> 6, c = idx & 63;
    float v = t[c][n];
    unsigned short h = f2bf(v);
    long o = ((long)b*NPIX + n0 + n)*320 + dst0 + c;
    inThi[o] = h;
    inTlo[o] = f2bf(v - bf2f(h));
  }
}

// pT[n][c] = bf16(kl[c][n]*vl[c][n])
__global__ __launch_bounds__(256) void pT_kernel(
    const float* __restrict__ projL, unsigned short* __restrict__ pT)
{
  __shared__ float t[64][65];
  const int b = blockIdx.z, c0 = blockIdx.y*64, n0 = blockIdx.x*64;
  const float* kl = projL + (long)b*(640L*NPIX);
  const float* vl = kl + 320L*NPIX;
  const int tid = threadIdx.x;
  #pragma unroll
  for (int it=0; it<16; ++it){
    int idx = it*256 + tid;
    int c = idx >> 6, n = idx & 63;
    long s = (long)(c0+c)*NPIX + n0 + n;
    t[c][n] = kl[s]*vl[s];
  }
  __syncthreads();
  #pragma unroll
  for (int it=0; it<16; ++it){
    int idx = it*256 + tid;
    int n = idx >> 6, c = idx & 63;
    pT[((long)b*NPIX + n0 + n)*320 + c0 + c] = f2bf(t[c][n]);
  }
}

// W2h[b][o][c] = bf16(wc[o][c]*colsum[b][c])
__global__ void w2_kernel(const float* __restrict__ wc_w, const float* __restrict__ colsum,
    unsigned short* __restrict__ W2h)
{
  int idx = blockIdx.x*256 + threadIdx.x;
  if (idx >= B4*160*320) return;
  int b = idx / (160*320);
  int rem = idx - b*160*320;
  int c = rem % 320;
  W2h[idx] = f2bf(wc_w[rem]*colsum[b*320+c]);
}

// ---------------- fp64 q8/k8 ----------------
__global__ __launch_bounds__(256) void qk8_kernel(const double* __restrict__ Wsw,
    const double* __restrict__ Wres, const double* __restrict__ bqk,
    const float* __restrict__ swin, const float* __restrict__ resnet, double* __restrict__ q8d)
{
  int b = blockIdx.z, mb = blockIdx.y*16;
  int n = blockIdx.x*256 + threadIdx.x;
  __shared__ double Ws[16][192];
  __shared__ double Wr[16][128];
  for (int i=threadIdx.x; i<16*192; i+=256) Ws[i/192][i%192] = Wsw[(mb + i/192)*192 + i%192];
  for (int i=threadIdx.x; i<16*128; i+=256) Wr[i/128][i%128] = Wres[(mb + i/128)*128 + i%128];
  __syncthreads();
  double acc[16];
  #pragma unroll
  for (int i=0;i<16;i++) acc[i] = bqk[mb+i];
  const float* sw = swin + (long)b*192*NPIX;
  for (int j=0;j<192;j++){
    double xv = (double)sw[(long)j*NPIX + n];
    #pragma unroll
    for (int i=0;i<16;i++) acc[i] += Ws[i][j]*xv;
  }
  const float* rs = resnet + (long)b*128*NPIX;
  for (int j=0;j<128;j++){
    double xv = (double)rs[(long)j*NPIX + n];
    #pragma unroll
    for (int i=0;i<16;i++) acc[i] += Wr[i][j]*xv;
  }
  #pragma unroll
  for (int i=0;i<16;i++) q8d[((long)b*80 + mb + i)*NPIX + n] = acc[i];
}

// ---------------- reductions ----------------
__global__ void sumk_kernel(const double* __restrict__ q8d, double* __restrict__ sumkd)
{
  int b = blockIdx.y, m = blockIdx.x;
  const double* row = q8d + ((long)b*80 + 40 + m)*NPIX;
  double s = 0.0;
  for (int n=threadIdx.x; n<NPIX; n+=256) s += row[n];
  __shared__ double sd[256];
  sd[threadIdx.x] = s; __syncthreads();
  for (int o=128; o; o>>=1){ if (threadIdx.x < o) sd[threadIdx.x] += sd[threadIdx.x+o]; __syncthreads(); }
  if (threadIdx.x == 0) sumkd[b*40+m] = sd[0];
}

__global__ void colsum_kernel(const float* __restrict__ projL, const float* __restrict__ qsum,
    float* __restrict__ colsum)
{
  int b = blockIdx.y, c = blockIdx.x;
  const float* kl = projL + (long)b*640*NPIX + (long)c*NPIX;
  const float* qs = qsum + (long)b*NPIX;
  double s = 0.0;
  for (int n=threadIdx.x; n<NPIX; n+=256) s += (double)kl[n]*(double)qs[n];
  __shared__ double sd[256];
  sd[threadIdx.x] = s; __syncthreads();
  for (int o=128; o; o>>=1){ if (threadIdx.x < o) sd[threadIdx.x] += sd[threadIdx.x+o]; __syncthreads(); }
  if (threadIdx.x == 0) colsum[b*320+c] = (float)sd[0];
}

// kvp[b][m][o] += over K-chunks; single pass over vp
__global__ __launch_bounds__(256) void kvp_kernel2(const float* __restrict__ proj1,
    const double* __restrict__ q8d, float* __restrict__ kvp)
{
  __shared__ float ks[40][128];
  __shared__ float vs[32][129];
  const int b = blockIdx.z, o0 = blockIdx.x*32, nbase = blockIdx.y*1024;
  const float* vp = proj1 + (long)b*(320L*NPIX);
  const double* k8 = q8d + ((long)b*80 + 40)*NPIX;
  const int tid = threadIdx.x;
  const int mg = tid >> 5, oi = tid & 31;
  float acc[5] = {0.f,0.f,0.f,0.f,0.f};
  for (int nc=0; nc<8; ++nc){
    int n0 = nbase + nc*128;
    for (int idx=tid; idx<40*128; idx+=256){
      int r = idx >> 7, n = idx & 127;
      ks[r][n] = (float)k8[(long)r*NPIX + n0 + n];
    }
    for (int idx=tid; idx<32*128; idx+=256){
      int r = idx >> 7, n = idx & 127;
      vs[r][n] = vp[(long)(o0+r)*NPIX + n0 + n];
    }
    __syncthreads();
    for (int nn=0; nn<128; ++nn){
      float vv = vs[oi][nn];
      #pragma unroll
      for (int i=0;i<5;i++) acc[i] = __fmaf_rn(ks[mg+8*i][nn], vv, acc[i]);
    }
    __syncthreads();
  }
  #pragma unroll
  for (int i=0;i<5;i++)
    atomicAdd(&kvp[((long)b*40 + mg + 8*i)*160 + o0 + oi], acc[i]);
}

__global__ __launch_bounds__(256) void norm_kernel(const double* __restrict__ q8d,
    const float* __restrict__ projL, const double* __restrict__ sumkd,
    const float* __restrict__ colsum, float* __restrict__ norm_a, float* __restrict__ norm_l)
{
  int b = blockIdx.y;
  int lane = threadIdx.x & 63;
  int g = threadIdx.x >> 6;
  int px = blockIdx.x*64 + lane;
  __shared__ double sk[40];
  __shared__ float cs[320];
  if (threadIdx.x < 40) sk[threadIdx.x] = sumkd[b*40+threadIdx.x] + 1e-10;
  for (int i=threadIdx.x; i<320; i+=256) cs[i] = colsum[b*320+i];
  __syncthreads();
  const double* q8 = q8d + (long)b*80*NPIX;
  const float* kl = projL + (long)b*640*NPIX;
  double da = 0.0, dl = 0.0;
  for (int m=g; m<40;  m+=4) da += q8[(long)m*NPIX + px]*sk[m];
  for (int c=g; c<320; c+=4) dl += (double)kl[(long)c*NPIX + px]*(double)cs[c];
  __shared__ double redA[4][64], redL[4][64];
  redA[g][lane] = da; redL[g][lane] = dl;
  __syncthreads();
  if (g == 0){
    double a = redA[0][lane]+redA[1][lane]+redA[2][lane]+redA[3][lane];
    double l = redL[0][lane]+redL[1][lane]+redL[2][lane]+redL[3][lane];
    norm_a[(long)b*NPIX+px] = (float)(1.0/a);
    norm_l[(long)b*NPIX+px] = (float)(1.0/(l + 1e-10));
  }
}

extern "C" void kernel_launch(void* const* d_in, const int* in_sizes, int n_in,
                              void* d_out, int out_size, void* d_ws, size_t ws_size,
                              hipStream_t stream)
{
  const float* swin   = (const float*)d_in[0];
  const float* resnet = (const float*)d_in[1];
  const float* w_swin = (const float*)d_in[2];
  const float* b_swin = (const float*)d_in[3];
  const float* w_res  = (const float*)d_in[4];
  const float* b_res  = (const float*)d_in[5];
  const float* aq_w = (const float*)d_in[6];
  const float* aq_b = (const float*)d_in[7];
  const float* ak_w = (const float*)d_in[8];
  const float* ak_b = (const float*)d_in[9];
  const float* av_w = (const float*)d_in[10];
  const float* av_b = (const float*)d_in[11];
  const float* ad1_w = (const float*)d_in[12];
  const float* ad1_b = (const float*)d_in[13];
  const float* ad3_w = (const float*)d_in[14];
  const float* ad3_b = (const float*)d_in[15];
  const float* ag    = (const float*)d_in[16];
  const float* lq_w = (const float*)d_in[17];
  const float* lq_b = (const float*)d_in[18];
  const float* lk_w = (const float*)d_in[19];
  const float* lk_b = (const float*)d_in[20];
  const float* lv_w = (const float*)d_in[21];
  const float* lv_b = (const float*)d_in[22];
  const float* ld1_w = (const float*)d_in[23];
  const float* ld1_b = (const float*)d_in[24];
  const float* ld3_w = (const float*)d_in[25];
  const float* ld3_b = (const float*)d_in[26];
  const float* lg    = (const float*)d_in[27];
  const float* wc_w = (const float*)d_in[28];
  const float* wc_b = (const float*)d_in[29];
  float* out = (float*)d_out;

  // ---- workspace carve ----
  char* p = (char*)d_ws;
  double* q8d   = (double*)p; p += (size_t)B4*80*NPIX*8;
  double* Wsw   = (double*)p; p += (size_t)80*192*8;
  double* Wres  = (double*)p; p += (size_t)80*128*8;
  double* bqk   = (double*)p; p += (size_t)80*8;
  double* sumkd = (double*)p; p += (size_t)160*8;
  float* proj1  = (float*)p;  p += (size_t)B4*320*NPIX*4;  // rows 0..159 vp, 160..319 outacc
  float* projL  = (float*)p;  p += (size_t)B4*640*NPIX*4;  // rows 0..319 kl, 320..639 vl
  float* qsum   = (float*)p;  p += (size_t)B4*NPIX*4;
  float* norm_a = (float*)p;  p += (size_t)B4*NPIX*4;
  float* norm_l = (float*)p;  p += (size_t)B4*NPIX*4;
  float* colsum = (float*)p;  p += (size_t)B4*320*4;
  float* kvp    = (float*)p;  p += (size_t)B4*40*160*4;
  float* Wbig1  = (float*)p;  p += (size_t)320*320*4;
  float* bias1  = (float*)p;  p += (size_t)320*4;
  float* Wmix   = (float*)p;  p += (size_t)2880*320*4;
  float* Wd3eff = (float*)p;  p += (size_t)160*2880*4;
  p = (char*)(((uintptr_t)p + 255) & ~(uintptr_t)255);
  unsigned short* xTh  = (unsigned short*)p; p += (size_t)B4*NPIX*320*2;
  unsigned short* xTl  = (unsigned short*)p; p += (size_t)B4*NPIX*320*2;
  unsigned short* Wb1h = (unsigned short*)p; p += (size_t)320*320*2;
  unsigned short* Wb1l = (unsigned short*)p; p += (size_t)320*320*2;
  unsigned short* lqh  = (unsigned short*)p; p += (size_t)320*320*2;
  unsigned short* lkh  = (unsigned short*)p; p += (size_t)320*320*2;
  unsigned short* lvh  = (unsigned short*)p; p += (size_t)320*320*2;
  unsigned short* Wd3b = (unsigned short*)p; p += (size_t)192*2880*2;
  unsigned short* wswh = (unsigned short*)p; p += (size_t)192*192*2;
  unsigned short* wswl = (unsigned short*)p; p += (size_t)192*192*2;
  unsigned short* wrsh = (unsigned short*)p; p += (size_t)128*128*2;
  unsigned short* wrsl = (unsigned short*)p; p += (size_t)128*128*2;
  if ((size_t)(p - (char*)d_ws) > ws_size) return;

  // aliases over dead regions (stream-ordered safety):
  // inT (21 MB) lives in projL (42 MB): written before lk/lv produce projL.
  unsigned short* inThi = (unsigned short*)projL;
  unsigned short* inTlo = inThi + (size_t)B4*NPIX*320;
  // pT (10.5 MB) lives in xTl: written after the split proj1 GEMM (last reader of xTl).
  unsigned short* pT = xTl;
  // W2h (0.4 MB) lives in Wmix (3.7 MB): written after Wd3eff compose (last reader of Wmix).
  unsigned short* W2h = (unsigned short*)Wmix;

  hipMemsetAsync(qsum, 0, (size_t)B4*NPIX*4, stream);
  hipMemsetAsync(kvp,  0, (size_t)B4*40*160*4, stream);

  // ---- weight composition ----
  composeqk_kernel<<<(80*192 + 80*128 + 80 + 255)/256, 256, 0, stream>>>(
      aq_w, aq_b, ak_w, ak_b, w_swin, b_swin, w_res, b_res, Wsw, Wres, bqk);
  compose1_kernel<<<(320*320 + 255)/256, 256, 0, stream>>>(av_w, ad1_w, ld1_w, wc_w, ag, lg, Wbig1);
  bias1_kernel<<<5, 64, 0, stream>>>(av_b, ad1_b, ad3_b, ld1_b, ld3_b, wc_w, wc_b, ag, lg, bias1);
  t1_kernel<<<(2880*320 + 255)/256, 256, 0, stream>>>(ad3_w, ld3_w, ag, lg, Wmix);
  gemm_f32<<<dim3(5,3,9), 256, 0, stream>>>(wc_w, nullptr, Wmix, 320L*320, 320,
      Wd3eff, 320, 2880, 160, 320);

  // ---- weight bf16 conversions ----
  cvt_split_kernel<<<(320*320 + 255)/256, 256, 0, stream>>>(Wbig1, Wb1h, Wb1l, 320*320);
  cvt_bf16_kernel<<<(320*320 + 255)/256, 256, 0, stream>>>(lq_w, lqh, 320*320);
  cvt_bf16_kernel<<<(320*320 + 255)/256, 256, 0, stream>>>(lk_w, lkh, 320*320);
  cvt_bf16_kernel<<<(320*320 + 255)/256, 256, 0, stream>>>(lv_w, lvh, 320*320);
  cvt_pad_kernel<<<(192*2880 + 255)/256, 256, 0, stream>>>(Wd3eff, Wd3b);
  cvt_split_kernel<<<(192*192 + 255)/256, 256, 0, stream>>>(w_swin, wswh, wswl, 192*192);
  cvt_split_kernel<<<(128*128 + 255)/256, 256, 0, stream>>>(w_res, wrsh, wrsl, 128*128);

  // ---- input transpose + x-build via MFMA (writes xTh/xTl) ----
  inT_kernel<<<dim3(64,5,4), 256, 0, stream>>>(swin, resnet, inThi, inTlo);
  xbuild_mfma<<<dim3(2,64,4), 256, 0, stream>>>(inThi, inTlo, 0, 192,
      wswh, wswl, b_swin, 192, 0, xTh, xTl);
  xbuild_mfma<<<dim3(1,64,4), 256, 0, stream>>>(inThi, inTlo, 192, 128,
      wrsh, wrsl, b_res, 128, 192, xTh, xTl);

  // ---- fp64 q8/k8 path ----
  qk8_kernel<<<dim3(16,5,4), 256, 0, stream>>>(Wsw, Wres, bqk, swin, resnet, q8d);

  // ---- MFMA projections (proj1 last: frees xTl for pT alias) ----
  gemm_mfma<2,0><<<dim3(32,5,4), 256, 0, stream>>>(lqh, nullptr, lq_b, xTh, nullptr,
      nullptr, 0, qsum);
  gemm_mfma<1,0><<<dim3(32,5,4), 256, 0, stream>>>(lkh, nullptr, lk_b, xTh, nullptr,
      projL, 640L*NPIX, nullptr);
  gemm_mfma<0,0><<<dim3(32,5,4), 256, 0, stream>>>(lvh, nullptr, lv_b, xTh, nullptr,
      projL + 320L*NPIX, 640L*NPIX, nullptr);
  gemm_mfma<0,1><<<dim3(32,5,4), 256, 0, stream>>>(Wb1h, Wb1l, bias1, xTh, xTl,
      proj1, 320L*NPIX, nullptr);

  // ---- reductions ----
  sumk_kernel<<<dim3(40,4), 256, 0, stream>>>(q8d, sumkd);
  kvp_kernel2<<<dim3(5,4,4), 256, 0, stream>>>(proj1, q8d, kvp);
  colsum_kernel<<<dim3(320,4), 256, 0, stream>>>(projL, qsum, colsum);
  norm_kernel<<<dim3(64,4), 256, 0, stream>>>(q8d, projL, sumkd, colsum, norm_a, norm_l);

  // ---- prep for final ----
  pT_kernel<<<dim3(64,5,4), 256, 0, stream>>>(projL, pT);
  w2_kernel<<<(B4*160*320 + 255)/256, 256, 0, stream>>>(wc_w, colsum, W2h);

  // ---- fused epilogue + composed conv ----
  final_mfma<<<dim3(32,3,4), 256, 0, stream>>>(W2h, pT, kvp, q8d, proj1,
                                               norm_a, norm_l, ag, lg, out);
  conv_mfma<<<dim3(32,3,4), 256, 0, stream>>>(Wd3b, xTh, out);
}

// Round 4
// 439.654 us; speedup vs baseline: 2.0266x; 1.1711x over previous
//
#include <hip/hip_runtime.h>
#include <stdint.h>

#define B4 4
#define NPIX 4096

typedef short sh8 __attribute__((ext_vector_type(8)));
typedef float f4 __attribute__((ext_vector_type(4)));

__device__ __forceinline__ float delu_f(float v){
  return v > 0.f ? __fmaf_rn(10.f, v, 1.f) : __expf(10.f*v);
}
__device__ __forceinline__ unsigned short f2bf(float f){
  unsigned u = __float_as_uint(f);
  u += 0x7fffu + ((u>>16)&1u);
  return (unsigned short)(u>>16);
}
__device__ __forceinline__ float bf2f(unsigned short h){
  return __uint_as_float(((unsigned)h)<<16);
}

// ---------------- generic 64x64x16 f32 tile GEMM (weight-compose only now) ----------------
__global__ __launch_bounds__(256) void gemm_f32(
    const float* __restrict__ W, const float* __restrict__ bias,
    const float* __restrict__ X, long xStride, int ldX,
    float* __restrict__ Out, long outStride, int ldOut,
    int M, int K)
{
  __shared__ float Wt[16][64];
  __shared__ float Xt[16][64];
  const int b  = blockIdx.z;
  const int m0 = blockIdx.y * 64;
  const int n0 = blockIdx.x * 64;
  const int tid = threadIdx.x;
  const int tc = tid & 15, tr = tid >> 4;
  const int wm = tid >> 2, wk = (tid & 3) << 2;
  const int xk = tid >> 4, xn = (tid & 15) << 2;
  const float* Xb = X + (long)b * xStride;
  float acc[4][4] = {};

  for (int k0 = 0; k0 < K; k0 += 16) {
    float4 wv4;
    if (m0 + wm < M) wv4 = *reinterpret_cast<const float4*>(W + (long)(m0+wm)*K + k0 + wk);
    else wv4 = make_float4(0.f,0.f,0.f,0.f);
    Wt[wk+0][wm] = wv4.x; Wt[wk+1][wm] = wv4.y; Wt[wk+2][wm] = wv4.z; Wt[wk+3][wm] = wv4.w;
    *reinterpret_cast<float4*>(&Xt[xk][xn]) =
        *reinterpret_cast<const float4*>(Xb + (long)(k0+xk)*ldX + n0 + xn);
    __syncthreads();
    #pragma unroll
    for (int kk = 0; kk < 16; ++kk) {
      float4 a4 = *reinterpret_cast<const float4*>(&Wt[kk][tr<<2]);
      float4 b4 = *reinterpret_cast<const float4*>(&Xt[kk][tc<<2]);
      float av[4] = {a4.x,a4.y,a4.z,a4.w};
      float bv[4] = {b4.x,b4.y,b4.z,b4.w};
      #pragma unroll
      for (int i=0;i<4;i++)
        #pragma unroll
        for (int j=0;j<4;j++) acc[i][j] = __fmaf_rn(av[i], bv[j], acc[i][j]);
    }
    __syncthreads();
  }

  #pragma unroll
  for (int i=0;i<4;i++){
    int m = m0 + (tr<<2) + i;
    if (m < M) {
      float bv = bias ? bias[m] : 0.f;
      float r[4];
      #pragma unroll
      for (int j=0;j<4;j++) r[j] = acc[i][j] + bv;
      *reinterpret_cast<float4*>(Out + (long)b*outStride + (long)m*ldOut + n0 + (tc<<2)) =
          make_float4(r[0],r[1],r[2],r[3]);
    }
  }
}

// ---------------- bf16 MFMA GEMM: C[m][n] = sum_k W[m][k] * xT[n][k] ----------------
template<int EP, int SPLIT>
__global__ __launch_bounds__(256) void gemm_mfma(
    const unsigned short* __restrict__ Whi, const unsigned short* __restrict__ Wlo,
    const float* __restrict__ bias,
    const unsigned short* __restrict__ Xhi, const unsigned short* __restrict__ Xlo,
    float* __restrict__ Out, long outStride, float* __restrict__ qsum)
{
  __shared__ unsigned short Ah[64][40];
  __shared__ unsigned short Bh[128][40];
  __shared__ unsigned short Al[SPLIT?64:8][40];
  __shared__ unsigned short Bl[SPLIT?128:8][40];
  const int b  = blockIdx.z;
  const int m0 = blockIdx.y * 64;
  const int n0 = blockIdx.x * 128;
  const int tid = threadIdx.x;
  const int sRow = tid >> 2, sK = (tid & 3) << 3;
  const int lane = tid & 63, w = tid >> 6;
  const int wr = w >> 1, wc = w & 1;
  const int fr = lane & 15, fko = (lane >> 4) << 3;

  f4 z4 = {0.f,0.f,0.f,0.f};
  f4 acc[2][4];
  #pragma unroll
  for (int mf=0; mf<2; mf++)
    #pragma unroll
    for (int nf=0; nf<4; nf++) acc[mf][nf] = z4;

  for (int k0 = 0; k0 < 320; k0 += 32) {
    *reinterpret_cast<sh8*>(&Ah[sRow][sK]) =
        *reinterpret_cast<const sh8*>(Whi + (long)(m0+sRow)*320 + k0 + sK);
    if (SPLIT)
      *reinterpret_cast<sh8*>(&Al[sRow][sK]) =
          *reinterpret_cast<const sh8*>(Wlo + (long)(m0+sRow)*320 + k0 + sK);
    #pragma unroll
    for (int r=0; r<2; r++){
      int row = r*64 + sRow;
      long src = ((long)b*NPIX + n0 + row)*320 + k0 + sK;
      *reinterpret_cast<sh8*>(&Bh[row][sK]) = *reinterpret_cast<const sh8*>(Xhi + src);
      if (SPLIT)
        *reinterpret_cast<sh8*>(&Bl[row][sK]) = *reinterpret_cast<const sh8*>(Xlo + src);
    }
    __syncthreads();
    sh8 aH[2], bH[4];
    #pragma unroll
    for (int mf=0; mf<2; mf++)
      aH[mf] = *reinterpret_cast<const sh8*>(&Ah[wr*32 + mf*16 + fr][fko]);
    #pragma unroll
    for (int nf=0; nf<4; nf++)
      bH[nf] = *reinterpret_cast<const sh8*>(&Bh[wc*64 + nf*16 + fr][fko]);
    #pragma unroll
    for (int mf=0; mf<2; mf++)
      #pragma unroll
      for (int nf=0; nf<4; nf++)
        acc[mf][nf] = __builtin_amdgcn_mfma_f32_16x16x32_bf16(aH[mf], bH[nf], acc[mf][nf], 0,0,0);
    if (SPLIT){
      sh8 aL[2], bL[4];
      #pragma unroll
      for (int mf=0; mf<2; mf++)
        aL[mf] = *reinterpret_cast<const sh8*>(&Al[wr*32 + mf*16 + fr][fko]);
      #pragma unroll
      for (int nf=0; nf<4; nf++)
        bL[nf] = *reinterpret_cast<const sh8*>(&Bl[wc*64 + nf*16 + fr][fko]);
      #pragma unroll
      for (int mf=0; mf<2; mf++)
        #pragma unroll
        for (int nf=0; nf<4; nf++){
          acc[mf][nf] = __builtin_amdgcn_mfma_f32_16x16x32_bf16(aL[mf], bH[nf], acc[mf][nf], 0,0,0);
          acc[mf][nf] = __builtin_amdgcn_mfma_f32_16x16x32_bf16(aH[mf], bL[nf], acc[mf][nf], 0,0,0);
        }
    }
    __syncthreads();
  }

  const int orow0 = m0 + wr*32;
  const int ocol  = n0 + wc*64;
  if (EP == 2){
    #pragma unroll
    for (int nf=0; nf<4; nf++){
      float s = 0.f;
      #pragma unroll
      for (int mf=0; mf<2; mf++)
        #pragma unroll
        for (int r=0; r<4; r++)
          s += delu_f(acc[mf][nf][r] + bias[orow0 + mf*16 + ((lane>>4)<<2) + r]);
      s += __shfl_xor(s, 16, 64);
      s += __shfl_xor(s, 32, 64);
      if (lane < 16) atomicAdd(&qsum[(long)b*NPIX + ocol + nf*16 + fr], s);
    }
  } else {
    #pragma unroll
    for (int mf=0; mf<2; mf++)
      #pragma unroll
      for (int r=0; r<4; r++){
        int row = orow0 + mf*16 + ((lane>>4)<<2) + r;
        float bv = bias ? bias[row] : 0.f;
        #pragma unroll
        for (int nf=0; nf<4; nf++){
          float v = acc[mf][nf][r] + bv;
          if (EP == 1) v = delu_f(v);
          Out[(long)b*outStride + (long)row*NPIX + ocol + nf*16 + fr] = v;
        }
      }
  }
}

// ---------------- x-build MFMA: role-flipped (A = pixels, B = weight rows), 3-pass split ----------------
__global__ __launch_bounds__(256) void xbuild_mfma(
    const unsigned short* __restrict__ inThi, const unsigned short* __restrict__ inTlo,
    int cOff, int K,
    const unsigned short* __restrict__ Wh, const unsigned short* __restrict__ Wl,
    const float* __restrict__ bias, int outC, int tOff,
    unsigned short* __restrict__ xTh, unsigned short* __restrict__ xTl)
{
  __shared__ unsigned short Ah[64][40];
  __shared__ unsigned short Bh[128][40];
  __shared__ unsigned short Al[64][40];
  __shared__ unsigned short Bl[128][40];
  const int b  = blockIdx.z;
  const int m0 = blockIdx.y * 64;     // pixel tile
  const int n0 = blockIdx.x * 128;    // out-channel tile
  const int tid = threadIdx.x;
  const int sRow = tid >> 2, sK = (tid & 3) << 3;
  const int lane = tid & 63, w = tid >> 6;
  const int wr = w >> 1, wc = w & 1;
  const int fr = lane & 15, fko = (lane >> 4) << 3;

  f4 z4 = {0.f,0.f,0.f,0.f};
  f4 acc[2][4];
  #pragma unroll
  for (int mf=0; mf<2; mf++)
    #pragma unroll
    for (int nf=0; nf<4; nf++) acc[mf][nf] = z4;

  for (int k0 = 0; k0 < K; k0 += 32) {
    long asrc = ((long)b*NPIX + m0 + sRow)*320 + cOff + k0 + sK;
    *reinterpret_cast<sh8*>(&Ah[sRow][sK]) = *reinterpret_cast<const sh8*>(inThi + asrc);
    *reinterpret_cast<sh8*>(&Al[sRow][sK]) = *reinterpret_cast<const sh8*>(inTlo + asrc);
    #pragma unroll
    for (int r=0; r<2; r++){
      int row = r*64 + sRow;
      sh8 vh = {0,0,0,0,0,0,0,0}, vl = {0,0,0,0,0,0,0,0};
      if (n0 + row < outC){
        vh = *reinterpret_cast<const sh8*>(Wh + (long)(n0+row)*K + k0 + sK);
        vl = *reinterpret_cast<const sh8*>(Wl + (long)(n0+row)*K + k0 + sK);
      }
      *reinterpret_cast<sh8*>(&Bh[row][sK]) = vh;
      *reinterpret_cast<sh8*>(&Bl[row][sK]) = vl;
    }
    __syncthreads();
    sh8 aH[2], aL[2], bH[4], bL[4];
    #pragma unroll
    for (int mf=0; mf<2; mf++){
      aH[mf] = *reinterpret_cast<const sh8*>(&Ah[wr*32 + mf*16 + fr][fko]);
      aL[mf] = *reinterpret_cast<const sh8*>(&Al[wr*32 + mf*16 + fr][fko]);
    }
    #pragma unroll
    for (int nf=0; nf<4; nf++){
      bH[nf] = *reinterpret_cast<const sh8*>(&Bh[wc*64 + nf*16 + fr][fko]);
      bL[nf] = *reinterpret_cast<const sh8*>(&Bl[wc*64 + nf*16 + fr][fko]);
    }
    #pragma unroll
    for (int mf=0; mf<2; mf++)
      #pragma unroll
      for (int nf=0; nf<4; nf++){
        acc[mf][nf] = __builtin_amdgcn_mfma_f32_16x16x32_bf16(aH[mf], bH[nf], acc[mf][nf], 0,0,0);
        acc[mf][nf] = __builtin_amdgcn_mfma_f32_16x16x32_bf16(aH[mf], bL[nf], acc[mf][nf], 0,0,0);
        acc[mf][nf] = __builtin_amdgcn_mfma_f32_16x16x32_bf16(aL[mf], bH[nf], acc[mf][nf], 0,0,0);
      }
    __syncthreads();
  }

  const int opix0 = m0 + wr*32;
  const int ocol  = n0 + wc*64;
  #pragma unroll
  for (int mf=0; mf<2; mf++)
    #pragma unroll
    for (int r=0; r<4; r++){
      int pix = opix0 + mf*16 + ((lane>>4)<<2) + r;
      #pragma unroll
      for (int nf=0; nf<4; nf++){
        int col = ocol + nf*16 + fr;
        if (col < outC){
          float v = acc[mf][nf][r] + bias[col];
          unsigned short h = f2bf(v);
          long o = ((long)b*NPIX + pix)*320 + tOff + col;
          xTh[o] = h;
          xTl[o] = f2bf(v - bf2f(h));
        }
      }
    }
}

// ---------------- kvp via MFMA, K-split: kvp[b][m][o] = sum_n k8[m][n]*vp[o][n] ----------------
// A = k8 (fp64 [40][4096]) hi/lo in staging; B = vp (fp32 [160][4096]) hi/lo in staging.
// grid (2 o-tiles, 32 pixel-chunks, B4); atomicAdd epilogue.
__global__ __launch_bounds__(256) void kvp_mfma(
    const float* __restrict__ proj1, const double* __restrict__ q8d,
    float* __restrict__ kvp)
{
  __shared__ unsigned short Ah[64][40];
  __shared__ unsigned short Bh[128][40];
  __shared__ unsigned short Al[64][40];
  __shared__ unsigned short Bl[128][40];
  const int b = blockIdx.z;
  const int o0 = blockIdx.x * 128;
  const int kbase = blockIdx.y * 128;
  const int tid = threadIdx.x;
  const int sRow = tid >> 2, sK = (tid & 3) << 3;
  const int lane = tid & 63, w = tid >> 6;
  const int wr = w >> 1, wc = w & 1;
  const int fr = lane & 15, fko = (lane >> 4) << 3;
  const double* k8 = q8d + ((long)b*80 + 40)*NPIX;
  const float* vp = proj1 + (long)b*(320L*NPIX);

  f4 z4 = {0.f,0.f,0.f,0.f};
  f4 acc[2][4];
  #pragma unroll
  for (int mf=0; mf<2; mf++)
    #pragma unroll
    for (int nf=0; nf<4; nf++) acc[mf][nf] = z4;

  for (int k0 = 0; k0 < 128; k0 += 32) {
    {
      #pragma unroll
      for (int i=0;i<8;i++){
        float v = (sRow < 40) ? (float)k8[(long)sRow*NPIX + kbase + k0 + sK + i] : 0.f;
        unsigned short h = f2bf(v);
        Ah[sRow][sK+i] = h;
        Al[sRow][sK+i] = f2bf(v - bf2f(h));
      }
    }
    #pragma unroll
    for (int r=0;r<2;r++){
      int row = r*64 + sRow;
      int o = o0 + row;
      float vv[8] = {0,0,0,0,0,0,0,0};
      if (o < 160){
        float4 v4a = *reinterpret_cast<const float4*>(vp + (long)o*NPIX + kbase + k0 + sK);
        float4 v4b = *reinterpret_cast<const float4*>(vp + (long)o*NPIX + kbase + k0 + sK + 4);
        vv[0]=v4a.x; vv[1]=v4a.y; vv[2]=v4a.z; vv[3]=v4a.w;
        vv[4]=v4b.x; vv[5]=v4b.y; vv[6]=v4b.z; vv[7]=v4b.w;
      }
      #pragma unroll
      for (int i=0;i<8;i++){
        unsigned short h = f2bf(vv[i]);
        Bh[row][sK+i] = h;
        Bl[row][sK+i] = f2bf(vv[i] - bf2f(h));
      }
    }
    __syncthreads();
    sh8 aH[2], aL[2], bH[4], bL[4];
    #pragma unroll
    for (int mf=0; mf<2; mf++){
      aH[mf] = *reinterpret_cast<const sh8*>(&Ah[wr*32 + mf*16 + fr][fko]);
      aL[mf] = *reinterpret_cast<const sh8*>(&Al[wr*32 + mf*16 + fr][fko]);
    }
    #pragma unroll
    for (int nf=0; nf<4; nf++){
      bH[nf] = *reinterpret_cast<const sh8*>(&Bh[wc*64 + nf*16 + fr][fko]);
      bL[nf] = *reinterpret_cast<const sh8*>(&Bl[wc*64 + nf*16 + fr][fko]);
    }
    #pragma unroll
    for (int mf=0; mf<2; mf++)
      #pragma unroll
      for (int nf=0; nf<4; nf++){
        acc[mf][nf] = __builtin_amdgcn_mfma_f32_16x16x32_bf16(aH[mf], bH[nf], acc[mf][nf], 0,0,0);
        acc[mf][nf] = __builtin_amdgcn_mfma_f32_16x16x32_bf16(aH[mf], bL[nf], acc[mf][nf], 0,0,0);
        acc[mf][nf] = __builtin_amdgcn_mfma_f32_16x16x32_bf16(aL[mf], bH[nf], acc[mf][nf], 0,0,0);
      }
    __syncthreads();
  }

  const int orow0 = wr*32;
  const int ocol  = o0 + wc*64;
  #pragma unroll
  for (int mf=0; mf<2; mf++)
    #pragma unroll
    for (int r=0; r<4; r++){
      int row = orow0 + mf*16 + ((lane>>4)<<2) + r;
      if (row < 40){
        #pragma unroll
        for (int nf=0; nf<4; nf++){
          int col = ocol + nf*16 + fr;
          if (col < 160)
            atomicAdd(&kvp[((long)b*40 + row)*160 + col], acc[mf][nf][r]);
        }
      }
    }
}

// ---------------- final MFMA: out = outacc + cL*norm_l*(W2@pT) + cA*norm_a*(kvpT@q8) ----------------
__global__ __launch_bounds__(256) void final_mfma(
    const unsigned short* __restrict__ W2h,
    const unsigned short* __restrict__ pT,
    const float* __restrict__ kvp,
    const double* __restrict__ q8d,
    const float* __restrict__ proj1,
    const float* __restrict__ norm_a, const float* __restrict__ norm_l,
    const float* __restrict__ ag, const float* __restrict__ lg,
    float* __restrict__ Out)
{
  __shared__ unsigned short Ah[64][40];
  __shared__ unsigned short Bh[128][40];
  __shared__ unsigned short Al[64][40];
  __shared__ unsigned short Bl[128][40];
  const int b  = blockIdx.z;
  const int m0 = blockIdx.y * 64;
  const int n0 = blockIdx.x * 128;
  const int tid = threadIdx.x;
  const int sRow = tid >> 2, sK = (tid & 3) << 3;
  const int lane = tid & 63, w = tid >> 6;
  const int wr = w >> 1, wc = w & 1;
  const int fr = lane & 15, fko = (lane >> 4) << 3;

  f4 z4 = {0.f,0.f,0.f,0.f};
  f4 acc1[2][4], acc2[2][4];
  #pragma unroll
  for (int mf=0; mf<2; mf++)
    #pragma unroll
    for (int nf=0; nf<4; nf++){ acc1[mf][nf] = z4; acc2[mf][nf] = z4; }

  for (int k0 = 0; k0 < 320; k0 += 32) {
    sh8 av = {0,0,0,0,0,0,0,0};
    if (m0 + sRow < 160)
      av = *reinterpret_cast<const sh8*>(W2h + ((long)b*160 + m0 + sRow)*320 + k0 + sK);
    *reinterpret_cast<sh8*>(&Ah[sRow][sK]) = av;
    #pragma unroll
    for (int r=0; r<2; r++){
      int row = r*64 + sRow;
      *reinterpret_cast<sh8*>(&Bh[row][sK]) =
          *reinterpret_cast<const sh8*>(pT + ((long)b*NPIX + n0 + row)*320 + k0 + sK);
    }
    __syncthreads();
    sh8 aH[2], bH[4];
    #pragma unroll
    for (int mf=0; mf<2; mf++)
      aH[mf] = *reinterpret_cast<const sh8*>(&Ah[wr*32 + mf*16 + fr][fko]);
    #pragma unroll
    for (int nf=0; nf<4; nf++)
      bH[nf] = *reinterpret_cast<const sh8*>(&Bh[wc*64 + nf*16 + fr][fko]);
    #pragma unroll
    for (int mf=0; mf<2; mf++)
      #pragma unroll
      for (int nf=0; nf<4; nf++)
        acc1[mf][nf] = __builtin_amdgcn_mfma_f32_16x16x32_bf16(aH[mf], bH[nf], acc1[mf][nf], 0,0,0);
    __syncthreads();
  }

  for (int k0 = 0; k0 < 64; k0 += 32) {
    {
      int m = m0 + sRow;
      #pragma unroll
      for (int i=0;i<8;i++){
        int kk = k0 + sK + i;
        float v = (kk < 40 && m < 160) ? kvp[((long)b*40 + kk)*160 + m] : 0.f;
        unsigned short h = f2bf(v);
        Ah[sRow][sK+i] = h;
        Al[sRow][sK+i] = f2bf(v - bf2f(h));
      }
    }
    #pragma unroll
    for (int r=0; r<2; r++){
      int row = r*64 + sRow;
      int pix = n0 + row;
      #pragma unroll
      for (int i=0;i<8;i++){
        int kk = k0 + sK + i;
        float v = (kk < 40) ? (float)q8d[((long)b*80 + kk)*NPIX + pix] : 0.f;
        unsigned short h = f2bf(v);
        Bh[row][sK+i] = h;
        Bl[row][sK+i] = f2bf(v - bf2f(h));
      }
    }
    __syncthreads();
    sh8 aH[2], aL[2], bH[4], bL[4];
    #pragma unroll
    for (int mf=0; mf<2; mf++){
      aH[mf] = *reinterpret_cast<const sh8*>(&Ah[wr*32 + mf*16 + fr][fko]);
      aL[mf] = *reinterpret_cast<const sh8*>(&Al[wr*32 + mf*16 + fr][fko]);
    }
    #pragma unroll
    for (int nf=0; nf<4; nf++){
      bH[nf] = *reinterpret_cast<const sh8*>(&Bh[wc*64 + nf*16 + fr][fko]);
      bL[nf] = *reinterpret_cast<const sh8*>(&Bl[wc*64 + nf*16 + fr][fko]);
    }
    #pragma unroll
    for (int mf=0; mf<2; mf++)
      #pragma unroll
      for (int nf=0; nf<4; nf++){
        acc2[mf][nf] = __builtin_amdgcn_mfma_f32_16x16x32_bf16(aH[mf], bH[nf], acc2[mf][nf], 0,0,0);
        acc2[mf][nf] = __builtin_amdgcn_mfma_f32_16x16x32_bf16(aH[mf], bL[nf], acc2[mf][nf], 0,0,0);
        acc2[mf][nf] = __builtin_amdgcn_mfma_f32_16x16x32_bf16(aL[mf], bH[nf], acc2[mf][nf], 0,0,0);
      }
    __syncthreads();
  }

  const float cA = 0.7f*ag[0], cL = 0.3f*lg[0];
  const int orow0 = m0 + wr*32;
  const int ocol  = n0 + wc*64;
  #pragma unroll
  for (int mf=0; mf<2; mf++)
    #pragma unroll
    for (int r=0; r<4; r++){
      int row = orow0 + mf*16 + ((lane>>4)<<2) + r;
      if (row < 160){
        const float* oa = proj1 + (long)b*(320L*NPIX) + (long)(160+row)*NPIX;
        #pragma unroll
        for (int nf=0; nf<4; nf++){
          int col = ocol + nf*16 + fr;
          Out[((long)b*160 + row)*NPIX + col] =
              oa[col] + cL*norm_l[(long)b*NPIX+col]*acc1[mf][nf][r]
                      + cA*norm_a[(long)b*NPIX+col]*acc2[mf][nf][r];
        }
      }
    }
}

// ---------------- composed 3x3 conv via MFMA (K = 9*320), accumulates into Out ----------------
__global__ __launch_bounds__(256) void conv_mfma(
    const unsigned short* __restrict__ Wd3,
    const unsigned short* __restrict__ Xhi,
    float* __restrict__ Out)
{
  __shared__ unsigned short Ah[64][40];
  __shared__ unsigned short Bh[128][40];
  const int b  = blockIdx.z;
  const int m0 = blockIdx.y * 64;
  const int n0 = blockIdx.x * 128;
  const int tid = threadIdx.x;
  const int sRow = tid >> 2, sK = (tid & 3) << 3;
  const int lane = tid & 63, w = tid >> 6;
  const int wr = w >> 1, wc = w & 1;
  const int fr = lane & 15, fko = (lane >> 4) << 3;

  f4 z4 = {0.f,0.f,0.f,0.f};
  f4 acc[2][4];
  #pragma unroll
  for (int mf=0; mf<2; mf++)
    #pragma unroll
    for (int nf=0; nf<4; nf++) acc[mf][nf] = z4;

  for (int t = 0; t < 9; t++){
    const int dh = t/3 - 1, dw = t%3 - 1;
    for (int c0 = 0; c0 < 320; c0 += 32){
      *reinterpret_cast<sh8*>(&Ah[sRow][sK]) =
          *reinterpret_cast<const sh8*>(Wd3 + (long)(m0+sRow)*2880 + t*320 + c0 + sK);
      #pragma unroll
      for (int r=0; r<2; r++){
        int row = r*64 + sRow;
        int p = n0 + row;
        int h = p >> 6, wq = p & 63;
        int hp = h + dh, wp = wq + dw;
        sh8 v = {0,0,0,0,0,0,0,0};
        if (hp >= 0 && hp < 64 && wp >= 0 && wp < 64)
          v = *reinterpret_cast<const sh8*>(Xhi + ((long)b*NPIX + hp*64 + wp)*320 + c0 + sK);
        *reinterpret_cast<sh8*>(&Bh[row][sK]) = v;
      }
      __syncthreads();
      sh8 aH[2], bH[4];
      #pragma unroll
      for (int mf=0; mf<2; mf++)
        aH[mf] = *reinterpret_cast<const sh8*>(&Ah[wr*32 + mf*16 + fr][fko]);
      #pragma unroll
      for (int nf=0; nf<4; nf++)
        bH[nf] = *reinterpret_cast<const sh8*>(&Bh[wc*64 + nf*16 + fr][fko]);
      #pragma unroll
      for (int mf=0; mf<2; mf++)
        #pragma unroll
        for (int nf=0; nf<4; nf++)
          acc[mf][nf] = __builtin_amdgcn_mfma_f32_16x16x32_bf16(aH[mf], bH[nf], acc[mf][nf], 0,0,0);
      __syncthreads();
    }
  }

  const int orow0 = m0 + wr*32;
  const int ocol  = n0 + wc*64;
  #pragma unroll
  for (int mf=0; mf<2; mf++)
    #pragma unroll
    for (int r=0; r<4; r++){
      int row = orow0 + mf*16 + ((lane>>4)<<2) + r;
      if (row < 160){
        #pragma unroll
        for (int nf=0; nf<4; nf++){
          long o = ((long)b*160 + row)*NPIX + ocol + nf*16 + fr;
          Out[o] += acc[mf][nf][r];
        }
      }
    }
}

// ---------------- weight composition kernels ----------------
__global__ void compose1_kernel(const float* __restrict__ av_w, const float* __restrict__ ad1_w,
    const float* __restrict__ ld1_w, const float* __restrict__ wc_w,
    const float* __restrict__ ag, const float* __restrict__ lg, float* __restrict__ Wbig1)
{
  int idx = blockIdx.x*256 + threadIdx.x;
  if (idx >= 320*320) return;
  int r = idx / 320, c = idx % 320;
  float cD = 1.4f*ag[0], cL = 0.3f*lg[0];
  if (r < 160) {
    float s = 0.f;
    for (int j=0;j<320;j++) s += wc_w[r*320+j]*av_w[j*320+c];
    Wbig1[idx] = s;
  } else {
    int o = r - 160;
    float s1 = 0.f, s2 = 0.f;
    for (int j=0;j<320;j++){
      float w = wc_w[o*320+j];
      s1 += w*ad1_w[j*320+c];
      s2 += w*ld1_w[j*320+c];
    }
    Wbig1[idx] = 2.f*wc_w[o*320+c] + cD*s1 + cL*s2;
  }
}

__global__ void bias1_kernel(const float* __restrict__ av_b, const float* __restrict__ ad1_b,
    const float* __restrict__ ad3_b, const float* __restrict__ ld1_b, const float* __restrict__ ld3_b,
    const float* __restrict__ wc_w, const float* __restrict__ wc_b,
    const float* __restrict__ ag, const float* __restrict__ lg, float* __restrict__ bias1)
{
  int r = blockIdx.x*64 + threadIdx.x;
  if (r >= 320) return;
  float cD = 1.4f*ag[0], cL = 0.3f*lg[0];
  if (r < 160){
    float s = 0.f;
    for (int j=0;j<320;j++) s += wc_w[r*320+j]*av_b[j];
    bias1[r] = s;
  } else {
    int o = r - 160;
    float s = wc_b[o];
    for (int j=0;j<320;j++){
      float w = wc_w[o*320+j];
      s += cD*w*(ad1_b[j]+ad3_b[j]) + cL*w*(ld1_b[j]+ld3_b[j]);
    }
    bias1[r] = s;
  }
}

__global__ void composeqk_kernel(const float* __restrict__ aq_w, const float* __restrict__ aq_b,
    const float* __restrict__ ak_w, const float* __restrict__ ak_b,
    const float* __restrict__ w_swin, const float* __restrict__ b_swin,
    const float* __restrict__ w_res, const float* __restrict__ b_res,
    double* __restrict__ Wsw, double* __restrict__ Wres, double* __restrict__ bqk)
{
  int idx = blockIdx.x*256 + threadIdx.x;
  if (idx < 80*192){
    int m = idx/192, j = idx%192;
    const float* aw = (m < 40) ? aq_w + m*320 : ak_w + (m-40)*320;
    double s = 0.0;
    for (int i=0;i<192;i++) s += (double)aw[i]*(double)w_swin[i*192+j];
    Wsw[idx] = s;
  }
  int idx2 = idx - 80*192;
  if (idx2 >= 0 && idx2 < 80*128){
    int m = idx2/128, j = idx2%128;
    const float* aw = (m < 40) ? aq_w + m*320 + 192 : ak_w + (m-40)*320 + 192;
    double s = 0.0;
    for (int i=0;i<128;i++) s += (double)aw[i]*(double)w_res[i*128+j];
    Wres[idx2] = s;
  }
  int idx3 = idx - 80*192 - 80*128;
  if (idx3 >= 0 && idx3 < 80){
    int m = idx3;
    const float* aw = (m < 40) ? aq_w + m*320 : ak_w + (m-40)*320;
    double s = (double)((m < 40) ? aq_b[m] : ak_b[m-40]);
    for (int i=0;i<192;i++) s += (double)aw[i]*(double)b_swin[i];
    for (int i=0;i<128;i++) s += (double)aw[192+i]*(double)b_res[i];
    bqk[m] = s;
  }
}

__global__ void t1_kernel(const float* __restrict__ ad3_w, const float* __restrict__ ld3_w,
    const float* __restrict__ ag, const float* __restrict__ lg, float* __restrict__ Wmix)
{
  long idx = (long)blockIdx.x*256 + threadIdx.x;
  if (idx >= 2880L*320) return;
  int k = (int)(idx / 320), c = (int)(idx % 320);
  int t = k / 320, j = k % 320;
  float cD = 1.4f*ag[0], cL = 0.3f*lg[0];
  long src = (long)(j*320 + c)*9 + t;
  Wmix[idx] = cD*ad3_w[src] + cL*ld3_w[src];
}

// ---------------- conversions ----------------
__global__ void cvt_bf16_kernel(const float* __restrict__ src, unsigned short* __restrict__ dst, int n){
  int i = blockIdx.x*256 + threadIdx.x;
  if (i < n) dst[i] = f2bf(src[i]);
}
__global__ void cvt_split_kernel(const float* __restrict__ src,
    unsigned short* __restrict__ hi, unsigned short* __restrict__ lo, int n){
  int i = blockIdx.x*256 + threadIdx.x;
  if (i < n){
    float v = src[i];
    unsigned short h = f2bf(v);
    hi[i] = h;
    lo[i] = f2bf(v - bf2f(h));
  }
}
__global__ void cvt_pad_kernel(const float* __restrict__ src, unsigned short* __restrict__ dst){
  int i = blockIdx.x*256 + threadIdx.x;
  if (i >= 192*2880) return;
  int row = i / 2880;
  dst[i] = (row < 160) ? f2bf(src[i]) : (unsigned short)0;
}

// inT: transpose raw inputs to [B][4096][320] bf16 hi/lo
__global__ __launch_bounds__(256) void inT_kernel(
    const float* __restrict__ swin, const float* __restrict__ resnet,
    unsigned short* __restrict__ inThi, unsigned short* __restrict__ inTlo)
{
  __shared__ float t[64][65];
  const int b = blockIdx.z, ct = blockIdx.y, n0 = blockIdx.x*64;
  const float* src; int C, cs0;
  if (ct < 3){ src = swin;   C = 192; cs0 = ct*64; }
  else       { src = resnet; C = 128; cs0 = (ct-3)*64; }
  const int dst0 = ct*64;
  const int tid = threadIdx.x;
  #pragma unroll
  for (int it=0; it<16; ++it){
    int idx = it*256 + tid;
    int c = idx >> 6, n = idx & 63;
    t[c][n] = src[((long)b*C + cs0 + c)*NPIX + n0 + n];
  }
  __syncthreads();
  #pragma unroll
  for (int it=0; it<16; ++it){
    int idx = it*256 + tid;
    int n = idx >> 6, c = idx & 63;
    float v = t[c][n];
    unsigned short h = f2bf(v);
    long o = ((long)b*NPIX + n0 + n)*320 + dst0 + c;
    inThi[o] = h;
    inTlo[o] = f2bf(v - bf2f(h));
  }
}

// pT[n][c] = bf16(kl[c][n]*vl[c][n])
__global__ __launch_bounds__(256) void pT_kernel(
    const float* __restrict__ projL, unsigned short* __restrict__ pT)
{
  __shared__ float t[64][65];
  const int b = blockIdx.z, c0 = blockIdx.y*64, n0 = blockIdx.x*64;
  const float* kl = projL + (long)b*(640L*NPIX);
  const float* vl = kl + 320L*NPIX;
  const int tid = threadIdx.x;
  #pragma unroll
  for (int it=0; it<16; ++it){
    int idx = it*256 + tid;
    int c = idx >> 6, n = idx & 63;
    long s = (long)(c0+c)*NPIX + n0 + n;
    t[c][n] = kl[s]*vl[s];
  }
  __syncthreads();
  #pragma unroll
  for (int it=0; it<16; ++it){
    int idx = it*256 + tid;
    int n = idx >> 6, c = idx & 63;
    pT[((long)b*NPIX + n0 + n)*320 + c0 + c] = f2bf(t[c][n]);
  }
}

// W2h[b][o][c] = bf16(wc[o][c]*colsum[b][c])
__global__ void w2_kernel(const float* __restrict__ wc_w, const float* __restrict__ colsum,
    unsigned short* __restrict__ W2h)
{
  int idx = blockIdx.x*256 + threadIdx.x;
  if (idx >= B4*160*320) return;
  int b = idx / (160*320);
  int rem = idx - b*160*320;
  int c = rem % 320;
  W2h[idx] = f2bf(wc_w[rem]*colsum[b*320+c]);
}

// ---------------- fp64 q8/k8 ----------------
__global__ __launch_bounds__(256) void qk8_kernel(const double* __restrict__ Wsw,
    const double* __restrict__ Wres, const double* __restrict__ bqk,
    const float* __restrict__ swin, const float* __restrict__ resnet, double* __restrict__ q8d)
{
  int b = blockIdx.z, mb = blockIdx.y*16;
  int n = blockIdx.x*256 + threadIdx.x;
  __shared__ double Ws[16][192];
  __shared__ double Wr[16][128];
  for (int i=threadIdx.x; i<16*192; i+=256) Ws[i/192][i%192] = Wsw[(mb + i/192)*192 + i%192];
  for (int i=threadIdx.x; i<16*128; i+=256) Wr[i/128][i%128] = Wres[(mb + i/128)*128 + i%128];
  __syncthreads();
  double acc[16];
  #pragma unroll
  for (int i=0;i<16;i++) acc[i] = bqk[mb+i];
  const float* sw = swin + (long)b*192*NPIX;
  for (int j=0;j<192;j++){
    double xv = (double)sw[(long)j*NPIX + n];
    #pragma unroll
    for (int i=0;i<16;i++) acc[i] += Ws[i][j]*xv;
  }
  const float* rs = resnet + (long)b*128*NPIX;
  for (int j=0;j<128;j++){
    double xv = (double)rs[(long)j*NPIX + n];
    #pragma unroll
    for (int i=0;i<16;i++) acc[i] += Wr[i][j]*xv;
  }
  #pragma unroll
  for (int i=0;i<16;i++) q8d[((long)b*80 + mb + i)*NPIX + n] = acc[i];
}

// ---------------- reductions ----------------
__global__ void sumk_kernel(const double* __restrict__ q8d, double* __restrict__ sumkd)
{
  int b = blockIdx.y, m = blockIdx.x;
  const double* row = q8d + ((long)b*80 + 40 + m)*NPIX;
  double s = 0.0;
  for (int n=threadIdx.x; n<NPIX; n+=256) s += row[n];
  __shared__ double sd[256];
  sd[threadIdx.x] = s; __syncthreads();
  for (int o=128; o; o>>=1){ if (threadIdx.x < o) sd[threadIdx.x] += sd[threadIdx.x+o]; __syncthreads(); }
  if (threadIdx.x == 0) sumkd[b*40+m] = sd[0];
}

__global__ void colsum_kernel(const float* __restrict__ projL, const float* __restrict__ qsum,
    float* __restrict__ colsum)
{
  int b = blockIdx.y, c = blockIdx.x;
  const float* kl = projL + (long)b*640*NPIX + (long)c*NPIX;
  const float* qs = qsum + (long)b*NPIX;
  double s = 0.0;
  for (int n=threadIdx.x; n<NPIX; n+=256) s += (double)kl[n]*(double)qs[n];
  __shared__ double sd[256];
  sd[threadIdx.x] = s; __syncthreads();
  for (int o=128; o; o>>=1){ if (threadIdx.x < o) sd[threadIdx.x] += sd[threadIdx.x+o]; __syncthreads(); }
  if (threadIdx.x == 0) colsum[b*320+c] = (float)sd[0];
}

__global__ __launch_bounds__(256) void norm_kernel(const double* __restrict__ q8d,
    const float* __restrict__ projL, const double* __restrict__ sumkd,
    const float* __restrict__ colsum, float* __restrict__ norm_a, float* __restrict__ norm_l)
{
  int b = blockIdx.y;
  int lane = threadIdx.x & 63;
  int g = threadIdx.x >> 6;
  int px = blockIdx.x*64 + lane;
  __shared__ double sk[40];
  __shared__ float cs[320];
  if (threadIdx.x < 40) sk[threadIdx.x] = sumkd[b*40+threadIdx.x] + 1e-10;
  for (int i=threadIdx.x; i<320; i+=256) cs[i] = colsum[b*320+i];
  __syncthreads();
  const double* q8 = q8d + (long)b*80*NPIX;
  const float* kl = projL + (long)b*640*NPIX;
  double da = 0.0, dl = 0.0;
  for (int m=g; m<40;  m+=4) da += q8[(long)m*NPIX + px]*sk[m];
  for (int c=g; c<320; c+=4) dl += (double)kl[(long)c*NPIX + px]*(double)cs[c];
  __shared__ double redA[4][64], redL[4][64];
  redA[g][lane] = da; redL[g][lane] = dl;
  __syncthreads();
  if (g == 0){
    double a = redA[0][lane]+redA[1][lane]+redA[2][lane]+redA[3][lane];
    double l = redL[0][lane]+redL[1][lane]+redL[2][lane]+redL[3][lane];
    norm_a[(long)b*NPIX+px] = (float)(1.0/a);
    norm_l[(long)b*NPIX+px] = (float)(1.0/(l + 1e-10));
  }
}

extern "C" void kernel_launch(void* const* d_in, const int* in_sizes, int n_in,
                              void* d_out, int out_size, void* d_ws, size_t ws_size,
                              hipStream_t stream)
{
  const float* swin   = (const float*)d_in[0];
  const float* resnet = (const float*)d_in[1];
  const float* w_swin = (const float*)d_in[2];
  const float* b_swin = (const float*)d_in[3];
  const float* w_res  = (const float*)d_in[4];
  const float* b_res  = (const float*)d_in[5];
  const float* aq_w = (const float*)d_in[6];
  const float* aq_b = (const float*)d_in[7];
  const float* ak_w = (const float*)d_in[8];
  const float* ak_b = (const float*)d_in[9];
  const float* av_w = (const float*)d_in[10];
  const float* av_b = (const float*)d_in[11];
  const float* ad1_w = (const float*)d_in[12];
  const float* ad1_b = (const float*)d_in[13];
  const float* ad3_w = (const float*)d_in[14];
  const float* ad3_b = (const float*)d_in[15];
  const float* ag    = (const float*)d_in[16];
  const float* lq_w = (const float*)d_in[17];
  const float* lq_b = (const float*)d_in[18];
  const float* lk_w = (const float*)d_in[19];
  const float* lk_b = (const float*)d_in[20];
  const float* lv_w = (const float*)d_in[21];
  const float* lv_b = (const float*)d_in[22];
  const float* ld1_w = (const float*)d_in[23];
  const float* ld1_b = (const float*)d_in[24];
  const float* ld3_w = (const float*)d_in[25];
  const float* ld3_b = (const float*)d_in[26];
  const float* lg    = (const float*)d_in[27];
  const float* wc_w = (const float*)d_in[28];
  const float* wc_b = (const float*)d_in[29];
  float* out = (float*)d_out;

  // ---- workspace carve ----
  char* p = (char*)d_ws;
  double* q8d   = (double*)p; p += (size_t)B4*80*NPIX*8;
  double* Wsw   = (double*)p; p += (size_t)80*192*8;
  double* Wres  = (double*)p; p += (size_t)80*128*8;
  double* bqk   = (double*)p; p += (size_t)80*8;
  double* sumkd = (double*)p; p += (size_t)160*8;
  float* proj1  = (float*)p;  p += (size_t)B4*320*NPIX*4;  // rows 0..159 vp, 160..319 outacc
  float* projL  = (float*)p;  p += (size_t)B4*640*NPIX*4;  // rows 0..319 kl, 320..639 vl
  float* qsum   = (float*)p;  p += (size_t)B4*NPIX*4;
  float* norm_a = (float*)p;  p += (size_t)B4*NPIX*4;
  float* norm_l = (float*)p;  p += (size_t)B4*NPIX*4;
  float* colsum = (float*)p;  p += (size_t)B4*320*4;
  float* kvp    = (float*)p;  p += (size_t)B4*40*160*4;
  float* Wbig1  = (float*)p;  p += (size_t)320*320*4;
  float* bias1  = (float*)p;  p += (size_t)320*4;
  float* Wmix   = (float*)p;  p += (size_t)2880*320*4;
  float* Wd3eff = (float*)p;  p += (size_t)160*2880*4;
  p = (char*)(((uintptr_t)p + 255) & ~(uintptr_t)255);
  unsigned short* xTh  = (unsigned short*)p; p += (size_t)B4*NPIX*320*2;
  unsigned short* xTl  = (unsigned short*)p; p += (size_t)B4*NPIX*320*2;
  unsigned short* Wb1h = (unsigned short*)p; p += (size_t)320*320*2;
  unsigned short* Wb1l = (unsigned short*)p; p += (size_t)320*320*2;
  unsigned short* lqh  = (unsigned short*)p; p += (size_t)320*320*2;
  unsigned short* lkh  = (unsigned short*)p; p += (size_t)320*320*2;
  unsigned short* lvh  = (unsigned short*)p; p += (size_t)320*320*2;
  unsigned short* Wd3b = (unsigned short*)p; p += (size_t)192*2880*2;
  unsigned short* wswh = (unsigned short*)p; p += (size_t)192*192*2;
  unsigned short* wswl = (unsigned short*)p; p += (size_t)192*192*2;
  unsigned short* wrsh = (unsigned short*)p; p += (size_t)128*128*2;
  unsigned short* wrsl = (unsigned short*)p; p += (size_t)128*128*2;
  if ((size_t)(p - (char*)d_ws) > ws_size) return;

  // aliases over dead regions (stream-ordered safety):
  unsigned short* inThi = (unsigned short*)projL;
  unsigned short* inTlo = inThi + (size_t)B4*NPIX*320;
  unsigned short* pT = xTl;
  unsigned short* W2h = (unsigned short*)Wmix;

  hipMemsetAsync(qsum, 0, (size_t)B4*NPIX*4, stream);
  hipMemsetAsync(kvp,  0, (size_t)B4*40*160*4, stream);

  // ---- weight composition ----
  composeqk_kernel<<<(80*192 + 80*128 + 80 + 255)/256, 256, 0, stream>>>(
      aq_w, aq_b, ak_w, ak_b, w_swin, b_swin, w_res, b_res, Wsw, Wres, bqk);
  compose1_kernel<<<(320*320 + 255)/256, 256, 0, stream>>>(av_w, ad1_w, ld1_w, wc_w, ag, lg, Wbig1);
  bias1_kernel<<<5, 64, 0, stream>>>(av_b, ad1_b, ad3_b, ld1_b, ld3_b, wc_w, wc_b, ag, lg, bias1);
  t1_kernel<<<(2880*320 + 255)/256, 256, 0, stream>>>(ad3_w, ld3_w, ag, lg, Wmix);
  gemm_f32<<<dim3(5,3,9), 256, 0, stream>>>(wc_w, nullptr, Wmix, 320L*320, 320,
      Wd3eff, 320, 2880, 160, 320);

  // ---- weight bf16 conversions ----
  cvt_split_kernel<<<(320*320 + 255)/256, 256, 0, stream>>>(Wbig1, Wb1h, Wb1l, 320*320);
  cvt_bf16_kernel<<<(320*320 + 255)/256, 256, 0, stream>>>(lq_w, lqh, 320*320);
  cvt_bf16_kernel<<<(320*320 + 255)/256, 256, 0, stream>>>(lk_w, lkh, 320*320);
  cvt_bf16_kernel<<<(320*320 + 255)/256, 256, 0, stream>>>(lv_w, lvh, 320*320);
  cvt_pad_kernel<<<(192*2880 + 255)/256, 256, 0, stream>>>(Wd3eff, Wd3b);
  cvt_split_kernel<<<(192*192 + 255)/256, 256, 0, stream>>>(w_swin, wswh, wswl, 192*192);
  cvt_split_kernel<<<(128*128 + 255)/256, 256, 0, stream>>>(w_res, wrsh, wrsl, 128*128);

  // ---- input transpose + x-build via MFMA (writes xTh/xTl) ----
  inT_kernel<<<dim3(64,5,4), 256, 0, stream>>>(swin, resnet, inThi, inTlo);
  xbuild_mfma<<<dim3(2,64,4), 256, 0, stream>>>(inThi, inTlo, 0, 192,
      wswh, wswl, b_swin, 192, 0, xTh, xTl);
  xbuild_mfma<<<dim3(1,64,4), 256, 0, stream>>>(inThi, inTlo, 192, 128,
      wrsh, wrsl, b_res, 128, 192, xTh, xTl);

  // ---- fp64 q8/k8 path ----
  qk8_kernel<<<dim3(16,5,4), 256, 0, stream>>>(Wsw, Wres, bqk, swin, resnet, q8d);

  // ---- MFMA projections (proj1 last: frees xTl for pT alias) ----
  gemm_mfma<2,0><<<dim3(32,5,4), 256, 0, stream>>>(lqh, nullptr, lq_b, xTh, nullptr,
      nullptr, 0, qsum);
  gemm_mfma<1,0><<<dim3(32,5,4), 256, 0, stream>>>(lkh, nullptr, lk_b, xTh, nullptr,
      projL, 640L*NPIX, nullptr);
  gemm_mfma<0,0><<<dim3(32,5,4), 256, 0, stream>>>(lvh, nullptr, lv_b, xTh, nullptr,
      projL + 320L*NPIX, 640L*NPIX, nullptr);
  gemm_mfma<0,1><<<dim3(32,5,4), 256, 0, stream>>>(Wb1h, Wb1l, bias1, xTh, xTl,
      proj1, 320L*NPIX, nullptr);

  // ---- reductions ----
  sumk_kernel<<<dim3(40,4), 256, 0, stream>>>(q8d, sumkd);
  kvp_mfma<<<dim3(2,32,4), 256, 0, stream>>>(proj1, q8d, kvp);
  colsum_kernel<<<dim3(320,4), 256, 0, stream>>>(projL, qsum, colsum);
  norm_kernel<<<dim3(64,4), 256, 0, stream>>>(q8d, projL, sumkd, colsum, norm_a, norm_l);

  // ---- prep for final ----
  pT_kernel<<<dim3(64,5,4), 256, 0, stream>>>(projL, pT);
  w2_kernel<<<(B4*160*320 + 255)/256, 256, 0, stream>>>(wc_w, colsum, W2h);

  // ---- fused epilogue + composed conv ----
  final_mfma<<<dim3(32,3,4), 256, 0, stream>>>(W2h, pT, kvp, q8d, proj1,
                                               norm_a, norm_l, ag, lg, out);
  conv_mfma<<<dim3(32,3,4), 256, 0, stream>>>(Wd3b, xTh, out);
}

// Round 5
// 422.687 us; speedup vs baseline: 2.1079x; 1.0401x over previous
//
#include <hip/hip_runtime.h>
#include <stdint.h>

#define B4 4
#define NPIX 4096

typedef short sh8 __attribute__((ext_vector_type(8)));
typedef float f4 __attribute__((ext_vector_type(4)));

__device__ __forceinline__ float delu_f(float v){
  return v > 0.f ? __fmaf_rn(10.f, v, 1.f) : __expf(10.f*v);
}
__device__ __forceinline__ unsigned short f2bf(float f){
  unsigned u = __float_as_uint(f);
  u += 0x7fffu + ((u>>16)&1u);
  return (unsigned short)(u>>16);
}
__device__ __forceinline__ float bf2f(unsigned short h){
  return __uint_as_float(((unsigned)h)<<16);
}

// ---------------- generic 64x64x16 f32 tile GEMM (weight-compose only) ----------------
__global__ __launch_bounds__(256) void gemm_f32(
    const float* __restrict__ W, const float* __restrict__ bias,
    const float* __restrict__ X, long xStride, int ldX,
    float* __restrict__ Out, long outStride, int ldOut,
    int M, int K)
{
  __shared__ float Wt[16][64];
  __shared__ float Xt[16][64];
  const int b  = blockIdx.z;
  const int m0 = blockIdx.y * 64;
  const int n0 = blockIdx.x * 64;
  const int tid = threadIdx.x;
  const int tc = tid & 15, tr = tid >> 4;
  const int wm = tid >> 2, wk = (tid & 3) << 2;
  const int xk = tid >> 4, xn = (tid & 15) << 2;
  const float* Xb = X + (long)b * xStride;
  float acc[4][4] = {};

  for (int k0 = 0; k0 < K; k0 += 16) {
    float4 wv4;
    if (m0 + wm < M) wv4 = *reinterpret_cast<const float4*>(W + (long)(m0+wm)*K + k0 + wk);
    else wv4 = make_float4(0.f,0.f,0.f,0.f);
    Wt[wk+0][wm] = wv4.x; Wt[wk+1][wm] = wv4.y; Wt[wk+2][wm] = wv4.z; Wt[wk+3][wm] = wv4.w;
    *reinterpret_cast<float4*>(&Xt[xk][xn]) =
        *reinterpret_cast<const float4*>(Xb + (long)(k0+xk)*ldX + n0 + xn);
    __syncthreads();
    #pragma unroll
    for (int kk = 0; kk < 16; ++kk) {
      float4 a4 = *reinterpret_cast<const float4*>(&Wt[kk][tr<<2]);
      float4 b4 = *reinterpret_cast<const float4*>(&Xt[kk][tc<<2]);
      float av[4] = {a4.x,a4.y,a4.z,a4.w};
      float bv[4] = {b4.x,b4.y,b4.z,b4.w};
      #pragma unroll
      for (int i=0;i<4;i++)
        #pragma unroll
        for (int j=0;j<4;j++) acc[i][j] = __fmaf_rn(av[i], bv[j], acc[i][j]);
    }
    __syncthreads();
  }

  #pragma unroll
  for (int i=0;i<4;i++){
    int m = m0 + (tr<<2) + i;
    if (m < M) {
      float bv = bias ? bias[m] : 0.f;
      float r[4];
      #pragma unroll
      for (int j=0;j<4;j++) r[j] = acc[i][j] + bv;
      *reinterpret_cast<float4*>(Out + (long)b*outStride + (long)m*ldOut + n0 + (tc<<2)) =
          make_float4(r[0],r[1],r[2],r[3]);
    }
  }
}

// ---------------- bf16 MFMA GEMM: C[m][n] = sum_k W[m][k] * xT[n][k] ----------------
// EP: 0 = store acc+bias; 1 = delu(acc+bias); 2 = delu column-sum -> qsum
template<int EP, int SPLIT>
__global__ __launch_bounds__(256) void gemm_mfma(
    const unsigned short* __restrict__ Whi, const unsigned short* __restrict__ Wlo,
    const float* __restrict__ bias,
    const unsigned short* __restrict__ Xhi, const unsigned short* __restrict__ Xlo,
    float* __restrict__ Out, long outStride, float* __restrict__ qsum)
{
  __shared__ unsigned short Ah[64][40];
  __shared__ unsigned short Bh[128][40];
  __shared__ unsigned short Al[SPLIT?64:8][40];
  __shared__ unsigned short Bl[SPLIT?128:8][40];
  const int b  = blockIdx.z;
  const int m0 = blockIdx.y * 64;
  const int n0 = blockIdx.x * 128;
  const int tid = threadIdx.x;
  const int sRow = tid >> 2, sK = (tid & 3) << 3;
  const int lane = tid & 63, w = tid >> 6;
  const int wr = w >> 1, wc = w & 1;
  const int fr = lane & 15, fko = (lane >> 4) << 3;

  f4 z4 = {0.f,0.f,0.f,0.f};
  f4 acc[2][4];
  #pragma unroll
  for (int mf=0; mf<2; mf++)
    #pragma unroll
    for (int nf=0; nf<4; nf++) acc[mf][nf] = z4;

  for (int k0 = 0; k0 < 320; k0 += 32) {
    *reinterpret_cast<sh8*>(&Ah[sRow][sK]) =
        *reinterpret_cast<const sh8*>(Whi + (long)(m0+sRow)*320 + k0 + sK);
    if (SPLIT)
      *reinterpret_cast<sh8*>(&Al[sRow][sK]) =
          *reinterpret_cast<const sh8*>(Wlo + (long)(m0+sRow)*320 + k0 + sK);
    #pragma unroll
    for (int r=0; r<2; r++){
      int row = r*64 + sRow;
      long src = ((long)b*NPIX + n0 + row)*320 + k0 + sK;
      *reinterpret_cast<sh8*>(&Bh[row][sK]) = *reinterpret_cast<const sh8*>(Xhi + src);
      if (SPLIT)
        *reinterpret_cast<sh8*>(&Bl[row][sK]) = *reinterpret_cast<const sh8*>(Xlo + src);
    }
    __syncthreads();
    sh8 aH[2], bH[4];
    #pragma unroll
    for (int mf=0; mf<2; mf++)
      aH[mf] = *reinterpret_cast<const sh8*>(&Ah[wr*32 + mf*16 + fr][fko]);
    #pragma unroll
    for (int nf=0; nf<4; nf++)
      bH[nf] = *reinterpret_cast<const sh8*>(&Bh[wc*64 + nf*16 + fr][fko]);
    #pragma unroll
    for (int mf=0; mf<2; mf++)
      #pragma unroll
      for (int nf=0; nf<4; nf++)
        acc[mf][nf] = __builtin_amdgcn_mfma_f32_16x16x32_bf16(aH[mf], bH[nf], acc[mf][nf], 0,0,0);
    if (SPLIT){
      sh8 aL[2], bL[4];
      #pragma unroll
      for (int mf=0; mf<2; mf++)
        aL[mf] = *reinterpret_cast<const sh8*>(&Al[wr*32 + mf*16 + fr][fko]);
      #pragma unroll
      for (int nf=0; nf<4; nf++)
        bL[nf] = *reinterpret_cast<const sh8*>(&Bl[wc*64 + nf*16 + fr][fko]);
      #pragma unroll
      for (int mf=0; mf<2; mf++)
        #pragma unroll
        for (int nf=0; nf<4; nf++){
          acc[mf][nf] = __builtin_amdgcn_mfma_f32_16x16x32_bf16(aL[mf], bH[nf], acc[mf][nf], 0,0,0);
          acc[mf][nf] = __builtin_amdgcn_mfma_f32_16x16x32_bf16(aH[mf], bL[nf], acc[mf][nf], 0,0,0);
        }
    }
    __syncthreads();
  }

  const int orow0 = m0 + wr*32;
  const int ocol  = n0 + wc*64;
  if (EP == 2){
    #pragma unroll
    for (int nf=0; nf<4; nf++){
      float s = 0.f;
      #pragma unroll
      for (int mf=0; mf<2; mf++)
        #pragma unroll
        for (int r=0; r<4; r++)
          s += delu_f(acc[mf][nf][r] + bias[orow0 + mf*16 + ((lane>>4)<<2) + r]);
      s += __shfl_xor(s, 16, 64);
      s += __shfl_xor(s, 32, 64);
      if (lane < 16) atomicAdd(&qsum[(long)b*NPIX + ocol + nf*16 + fr], s);
    }
  } else {
    #pragma unroll
    for (int mf=0; mf<2; mf++)
      #pragma unroll
      for (int r=0; r<4; r++){
        int row = orow0 + mf*16 + ((lane>>4)<<2) + r;
        float bv = bias ? bias[row] : 0.f;
        #pragma unroll
        for (int nf=0; nf<4; nf++){
          float v = acc[mf][nf][r] + bv;
          if (EP == 1) v = delu_f(v);
          Out[(long)b*outStride + (long)row*NPIX + ocol + nf*16 + fr] = v;
        }
      }
  }
}

// ---------------- x-build MFMA: role-flipped (A = pixels, B = weight rows), 3-pass split ----------------
__global__ __launch_bounds__(256) void xbuild_mfma(
    const unsigned short* __restrict__ inThi, const unsigned short* __restrict__ inTlo,
    int cOff, int K,
    const unsigned short* __restrict__ Wh, const unsigned short* __restrict__ Wl,
    const float* __restrict__ bias, int outC, int tOff,
    unsigned short* __restrict__ xTh, unsigned short* __restrict__ xTl)
{
  __shared__ unsigned short Ah[64][40];
  __shared__ unsigned short Bh[128][40];
  __shared__ unsigned short Al[64][40];
  __shared__ unsigned short Bl[128][40];
  const int b  = blockIdx.z;
  const int m0 = blockIdx.y * 64;
  const int n0 = blockIdx.x * 128;
  const int tid = threadIdx.x;
  const int sRow = tid >> 2, sK = (tid & 3) << 3;
  const int lane = tid & 63, w = tid >> 6;
  const int wr = w >> 1, wc = w & 1;
  const int fr = lane & 15, fko = (lane >> 4) << 3;

  f4 z4 = {0.f,0.f,0.f,0.f};
  f4 acc[2][4];
  #pragma unroll
  for (int mf=0; mf<2; mf++)
    #pragma unroll
    for (int nf=0; nf<4; nf++) acc[mf][nf] = z4;

  for (int k0 = 0; k0 < K; k0 += 32) {
    long asrc = ((long)b*NPIX + m0 + sRow)*320 + cOff + k0 + sK;
    *reinterpret_cast<sh8*>(&Ah[sRow][sK]) = *reinterpret_cast<const sh8*>(inThi + asrc);
    *reinterpret_cast<sh8*>(&Al[sRow][sK]) = *reinterpret_cast<const sh8*>(inTlo + asrc);
    #pragma unroll
    for (int r=0; r<2; r++){
      int row = r*64 + sRow;
      sh8 vh = {0,0,0,0,0,0,0,0}, vl = {0,0,0,0,0,0,0,0};
      if (n0 + row < outC){
        vh = *reinterpret_cast<const sh8*>(Wh + (long)(n0+row)*K + k0 + sK);
        vl = *reinterpret_cast<const sh8*>(Wl + (long)(n0+row)*K + k0 + sK);
      }
      *reinterpret_cast<sh8*>(&Bh[row][sK]) = vh;
      *reinterpret_cast<sh8*>(&Bl[row][sK]) = vl;
    }
    __syncthreads();
    sh8 aH[2], aL[2], bH[4], bL[4];
    #pragma unroll
    for (int mf=0; mf<2; mf++){
      aH[mf] = *reinterpret_cast<const sh8*>(&Ah[wr*32 + mf*16 + fr][fko]);
      aL[mf] = *reinterpret_cast<const sh8*>(&Al[wr*32 + mf*16 + fr][fko]);
    }
    #pragma unroll
    for (int nf=0; nf<4; nf++){
      bH[nf] = *reinterpret_cast<const sh8*>(&Bh[wc*64 + nf*16 + fr][fko]);
      bL[nf] = *reinterpret_cast<const sh8*>(&Bl[wc*64 + nf*16 + fr][fko]);
    }
    #pragma unroll
    for (int mf=0; mf<2; mf++)
      #pragma unroll
      for (int nf=0; nf<4; nf++){
        acc[mf][nf] = __builtin_amdgcn_mfma_f32_16x16x32_bf16(aH[mf], bH[nf], acc[mf][nf], 0,0,0);
        acc[mf][nf] = __builtin_amdgcn_mfma_f32_16x16x32_bf16(aH[mf], bL[nf], acc[mf][nf], 0,0,0);
        acc[mf][nf] = __builtin_amdgcn_mfma_f32_16x16x32_bf16(aL[mf], bH[nf], acc[mf][nf], 0,0,0);
      }
    __syncthreads();
  }

  const int opix0 = m0 + wr*32;
  const int ocol  = n0 + wc*64;
  #pragma unroll
  for (int mf=0; mf<2; mf++)
    #pragma unroll
    for (int r=0; r<4; r++){
      int pix = opix0 + mf*16 + ((lane>>4)<<2) + r;
      #pragma unroll
      for (int nf=0; nf<4; nf++){
        int col = ocol + nf*16 + fr;
        if (col < outC){
          float v = acc[mf][nf][r] + bias[col];
          unsigned short h = f2bf(v);
          long o = ((long)b*NPIX + pix)*320 + tOff + col;
          xTh[o] = h;
          xTl[o] = f2bf(v - bf2f(h));
        }
      }
    }
}

// ---------------- kvp via MFMA, K-split: kvp[b][m][o] = sum_n k8[m][n]*vp[o][n] ----------------
__global__ __launch_bounds__(256) void kvp_mfma(
    const float* __restrict__ proj1, const float* __restrict__ q8f,
    float* __restrict__ kvp)
{
  __shared__ unsigned short Ah[64][40];
  __shared__ unsigned short Bh[128][40];
  __shared__ unsigned short Al[64][40];
  __shared__ unsigned short Bl[128][40];
  const int b = blockIdx.z;
  const int o0 = blockIdx.x * 128;
  const int kbase = blockIdx.y * 128;
  const int tid = threadIdx.x;
  const int sRow = tid >> 2, sK = (tid & 3) << 3;
  const int lane = tid & 63, w = tid >> 6;
  const int wr = w >> 1, wc = w & 1;
  const int fr = lane & 15, fko = (lane >> 4) << 3;
  const float* k8 = q8f + ((long)b*128 + 40)*NPIX;
  const float* vp = proj1 + (long)b*(320L*NPIX);

  f4 z4 = {0.f,0.f,0.f,0.f};
  f4 acc[2][4];
  #pragma unroll
  for (int mf=0; mf<2; mf++)
    #pragma unroll
    for (int nf=0; nf<4; nf++) acc[mf][nf] = z4;

  for (int k0 = 0; k0 < 128; k0 += 32) {
    {
      float vv[8] = {0,0,0,0,0,0,0,0};
      if (sRow < 40){
        float4 a4 = *reinterpret_cast<const float4*>(k8 + (long)sRow*NPIX + kbase + k0 + sK);
        float4 b4 = *reinterpret_cast<const float4*>(k8 + (long)sRow*NPIX + kbase + k0 + sK + 4);
        vv[0]=a4.x; vv[1]=a4.y; vv[2]=a4.z; vv[3]=a4.w;
        vv[4]=b4.x; vv[5]=b4.y; vv[6]=b4.z; vv[7]=b4.w;
      }
      #pragma unroll
      for (int i=0;i<8;i++){
        unsigned short h = f2bf(vv[i]);
        Ah[sRow][sK+i] = h;
        Al[sRow][sK+i] = f2bf(vv[i] - bf2f(h));
      }
    }
    #pragma unroll
    for (int r=0;r<2;r++){
      int row = r*64 + sRow;
      int o = o0 + row;
      float vv[8] = {0,0,0,0,0,0,0,0};
      if (o < 160){
        float4 v4a = *reinterpret_cast<const float4*>(vp + (long)o*NPIX + kbase + k0 + sK);
        float4 v4b = *reinterpret_cast<const float4*>(vp + (long)o*NPIX + kbase + k0 + sK + 4);
        vv[0]=v4a.x; vv[1]=v4a.y; vv[2]=v4a.z; vv[3]=v4a.w;
        vv[4]=v4b.x; vv[5]=v4b.y; vv[6]=v4b.z; vv[7]=v4b.w;
      }
      #pragma unroll
      for (int i=0;i<8;i++){
        unsigned short h = f2bf(vv[i]);
        Bh[row][sK+i] = h;
        Bl[row][sK+i] = f2bf(vv[i] - bf2f(h));
      }
    }
    __syncthreads();
    sh8 aH[2], aL[2], bH[4], bL[4];
    #pragma unroll
    for (int mf=0; mf<2; mf++){
      aH[mf] = *reinterpret_cast<const sh8*>(&Ah[wr*32 + mf*16 + fr][fko]);
      aL[mf] = *reinterpret_cast<const sh8*>(&Al[wr*32 + mf*16 + fr][fko]);
    }
    #pragma unroll
    for (int nf=0; nf<4; nf++){
      bH[nf] = *reinterpret_cast<const sh8*>(&Bh[wc*64 + nf*16 + fr][fko]);
      bL[nf] = *reinterpret_cast<const sh8*>(&Bl[wc*64 + nf*16 + fr][fko]);
    }
    #pragma unroll
    for (int mf=0; mf<2; mf++)
      #pragma unroll
      for (int nf=0; nf<4; nf++){
        acc[mf][nf] = __builtin_amdgcn_mfma_f32_16x16x32_bf16(aH[mf], bH[nf], acc[mf][nf], 0,0,0);
        acc[mf][nf] = __builtin_amdgcn_mfma_f32_16x16x32_bf16(aH[mf], bL[nf], acc[mf][nf], 0,0,0);
        acc[mf][nf] = __builtin_amdgcn_mfma_f32_16x16x32_bf16(aL[mf], bH[nf], acc[mf][nf], 0,0,0);
      }
    __syncthreads();
  }

  const int orow0 = wr*32;
  const int ocol  = o0 + wc*64;
  #pragma unroll
  for (int mf=0; mf<2; mf++)
    #pragma unroll
    for (int r=0; r<4; r++){
      int row = orow0 + mf*16 + ((lane>>4)<<2) + r;
      if (row < 40){
        #pragma unroll
        for (int nf=0; nf<4; nf++){
          int col = ocol + nf*16 + fr;
          if (col < 160)
            atomicAdd(&kvp[((long)b*40 + row)*160 + col], acc[mf][nf][r]);
        }
      }
    }
}

// ---------------- final MFMA: out = outacc + cL*norm_l*(W2@pT) + cA*norm_a*(kvpT@q8) ----------------
__global__ __launch_bounds__(256) void final_mfma(
    const unsigned short* __restrict__ W2h,
    const unsigned short* __restrict__ pT,
    const float* __restrict__ kvp,
    const float* __restrict__ q8f,
    const float* __restrict__ proj1,
    const float* __restrict__ norm_a, const float* __restrict__ norm_l,
    const float* __restrict__ ag, const float* __restrict__ lg,
    float* __restrict__ Out)
{
  __shared__ unsigned short Ah[64][40];
  __shared__ unsigned short Bh[128][40];
  __shared__ unsigned short Al[64][40];
  __shared__ unsigned short Bl[128][40];
  const int b  = blockIdx.z;
  const int m0 = blockIdx.y * 64;
  const int n0 = blockIdx.x * 128;
  const int tid = threadIdx.x;
  const int sRow = tid >> 2, sK = (tid & 3) << 3;
  const int lane = tid & 63, w = tid >> 6;
  const int wr = w >> 1, wc = w & 1;
  const int fr = lane & 15, fko = (lane >> 4) << 3;

  f4 z4 = {0.f,0.f,0.f,0.f};
  f4 acc1[2][4], acc2[2][4];
  #pragma unroll
  for (int mf=0; mf<2; mf++)
    #pragma unroll
    for (int nf=0; nf<4; nf++){ acc1[mf][nf] = z4; acc2[mf][nf] = z4; }

  for (int k0 = 0; k0 < 320; k0 += 32) {
    sh8 av = {0,0,0,0,0,0,0,0};
    if (m0 + sRow < 160)
      av = *reinterpret_cast<const sh8*>(W2h + ((long)b*160 + m0 + sRow)*320 + k0 + sK);
    *reinterpret_cast<sh8*>(&Ah[sRow][sK]) = av;
    #pragma unroll
    for (int r=0; r<2; r++){
      int row = r*64 + sRow;
      *reinterpret_cast<sh8*>(&Bh[row][sK]) =
          *reinterpret_cast<const sh8*>(pT + ((long)b*NPIX + n0 + row)*320 + k0 + sK);
    }
    __syncthreads();
    sh8 aH[2], bH[4];
    #pragma unroll
    for (int mf=0; mf<2; mf++)
      aH[mf] = *reinterpret_cast<const sh8*>(&Ah[wr*32 + mf*16 + fr][fko]);
    #pragma unroll
    for (int nf=0; nf<4; nf++)
      bH[nf] = *reinterpret_cast<const sh8*>(&Bh[wc*64 + nf*16 + fr][fko]);
    #pragma unroll
    for (int mf=0; mf<2; mf++)
      #pragma unroll
      for (int nf=0; nf<4; nf++)
        acc1[mf][nf] = __builtin_amdgcn_mfma_f32_16x16x32_bf16(aH[mf], bH[nf], acc1[mf][nf], 0,0,0);
    __syncthreads();
  }

  for (int k0 = 0; k0 < 64; k0 += 32) {
    {
      int m = m0 + sRow;
      #pragma unroll
      for (int i=0;i<8;i++){
        int kk = k0 + sK + i;
        float v = (kk < 40 && m < 160) ? kvp[((long)b*40 + kk)*160 + m] : 0.f;
        unsigned short h = f2bf(v);
        Ah[sRow][sK+i] = h;
        Al[sRow][sK+i] = f2bf(v - bf2f(h));
      }
    }
    #pragma unroll
    for (int r=0; r<2; r++){
      int row = r*64 + sRow;
      int pix = n0 + row;
      #pragma unroll
      for (int i=0;i<8;i++){
        int kk = k0 + sK + i;
        float v = (kk < 40) ? q8f[((long)b*128 + kk)*NPIX + pix] : 0.f;
        unsigned short h = f2bf(v);
        Bh[row][sK+i] = h;
        Bl[row][sK+i] = f2bf(v - bf2f(h));
      }
    }
    __syncthreads();
    sh8 aH[2], aL[2], bH[4], bL[4];
    #pragma unroll
    for (int mf=0; mf<2; mf++){
      aH[mf] = *reinterpret_cast<const sh8*>(&Ah[wr*32 + mf*16 + fr][fko]);
      aL[mf] = *reinterpret_cast<const sh8*>(&Al[wr*32 + mf*16 + fr][fko]);
    }
    #pragma unroll
    for (int nf=0; nf<4; nf++){
      bH[nf] = *reinterpret_cast<const sh8*>(&Bh[wc*64 + nf*16 + fr][fko]);
      bL[nf] = *reinterpret_cast<const sh8*>(&Bl[wc*64 + nf*16 + fr][fko]);
    }
    #pragma unroll
    for (int mf=0; mf<2; mf++)
      #pragma unroll
      for (int nf=0; nf<4; nf++){
        acc2[mf][nf] = __builtin_amdgcn_mfma_f32_16x16x32_bf16(aH[mf], bH[nf], acc2[mf][nf], 0,0,0);
        acc2[mf][nf] = __builtin_amdgcn_mfma_f32_16x16x32_bf16(aH[mf], bL[nf], acc2[mf][nf], 0,0,0);
        acc2[mf][nf] = __builtin_amdgcn_mfma_f32_16x16x32_bf16(aL[mf], bH[nf], acc2[mf][nf], 0,0,0);
      }
    __syncthreads();
  }

  const float cA = 0.7f*ag[0], cL = 0.3f*lg[0];
  const int orow0 = m0 + wr*32;
  const int ocol  = n0 + wc*64;
  #pragma unroll
  for (int mf=0; mf<2; mf++)
    #pragma unroll
    for (int r=0; r<4; r++){
      int row = orow0 + mf*16 + ((lane>>4)<<2) + r;
      if (row < 160){
        const float* oa = proj1 + (long)b*(320L*NPIX) + (long)(160+row)*NPIX;
        #pragma unroll
        for (int nf=0; nf<4; nf++){
          int col = ocol + nf*16 + fr;
          Out[((long)b*160 + row)*NPIX + col] =
              oa[col] + cL*norm_l[(long)b*NPIX+col]*acc1[mf][nf][r]
                      + cA*norm_a[(long)b*NPIX+col]*acc2[mf][nf][r];
        }
      }
    }
}

// ---------------- composed 3x3 conv via MFMA (K = 9*320), accumulates into Out ----------------
__global__ __launch_bounds__(256) void conv_mfma(
    const unsigned short* __restrict__ Wd3,
    const unsigned short* __restrict__ Xhi,
    float* __restrict__ Out)
{
  __shared__ unsigned short Ah[64][40];
  __shared__ unsigned short Bh[128][40];
  const int b  = blockIdx.z;
  const int m0 = blockIdx.y * 64;
  const int n0 = blockIdx.x * 128;
  const int tid = threadIdx.x;
  const int sRow = tid >> 2, sK = (tid & 3) << 3;
  const int lane = tid & 63, w = tid >> 6;
  const int wr = w >> 1, wc = w & 1;
  const int fr = lane & 15, fko = (lane >> 4) << 3;

  f4 z4 = {0.f,0.f,0.f,0.f};
  f4 acc[2][4];
  #pragma unroll
  for (int mf=0; mf<2; mf++)
    #pragma unroll
    for (int nf=0; nf<4; nf++) acc[mf][nf] = z4;

  for (int t = 0; t < 9; t++){
    const int dh = t/3 - 1, dw = t%3 - 1;
    for (int c0 = 0; c0 < 320; c0 += 32){
      *reinterpret_cast<sh8*>(&Ah[sRow][sK]) =
          *reinterpret_cast<const sh8*>(Wd3 + (long)(m0+sRow)*2880 + t*320 + c0 + sK);
      #pragma unroll
      for (int r=0; r<2; r++){
        int row = r*64 + sRow;
        int p = n0 + row;
        int h = p >> 6, wq = p & 63;
        int hp = h + dh, wp = wq + dw;
        sh8 v = {0,0,0,0,0,0,0,0};
        if (hp >= 0 && hp < 64 && wp >= 0 && wp < 64)
          v = *reinterpret_cast<const sh8*>(Xhi + ((long)b*NPIX + hp*64 + wp)*320 + c0 + sK);
        *reinterpret_cast<sh8*>(&Bh[row][sK]) = v;
      }
      __syncthreads();
      sh8 aH[2], bH[4];
      #pragma unroll
      for (int mf=0; mf<2; mf++)
        aH[mf] = *reinterpret_cast<const sh8*>(&Ah[wr*32 + mf*16 + fr][fko]);
      #pragma unroll
      for (int nf=0; nf<4; nf++)
        bH[nf] = *reinterpret_cast<const sh8*>(&Bh[wc*64 + nf*16 + fr][fko]);
      #pragma unroll
      for (int mf=0; mf<2; mf++)
        #pragma unroll
        for (int nf=0; nf<4; nf++)
          acc[mf][nf] = __builtin_amdgcn_mfma_f32_16x16x32_bf16(aH[mf], bH[nf], acc[mf][nf], 0,0,0);
      __syncthreads();
    }
  }

  const int orow0 = m0 + wr*32;
  const int ocol  = n0 + wc*64;
  #pragma unroll
  for (int mf=0; mf<2; mf++)
    #pragma unroll
    for (int r=0; r<4; r++){
      int row = orow0 + mf*16 + ((lane>>4)<<2) + r;
      if (row < 160){
        #pragma unroll
        for (int nf=0; nf<4; nf++){
          long o = ((long)b*160 + row)*NPIX + ocol + nf*16 + fr;
          Out[o] += acc[mf][nf][r];
        }
      }
    }
}

// ---------------- weight composition kernels ----------------
__global__ void compose1_kernel(const float* __restrict__ av_w, const float* __restrict__ ad1_w,
    const float* __restrict__ ld1_w, const float* __restrict__ wc_w,
    const float* __restrict__ ag, const float* __restrict__ lg, float* __restrict__ Wbig1)
{
  int idx = blockIdx.x*256 + threadIdx.x;
  if (idx >= 320*320) return;
  int r = idx / 320, c = idx % 320;
  float cD = 1.4f*ag[0], cL = 0.3f*lg[0];
  if (r < 160) {
    float s = 0.f;
    for (int j=0;j<320;j++) s += wc_w[r*320+j]*av_w[j*320+c];
    Wbig1[idx] = s;
  } else {
    int o = r - 160;
    float s1 = 0.f, s2 = 0.f;
    for (int j=0;j<320;j++){
      float w = wc_w[o*320+j];
      s1 += w*ad1_w[j*320+c];
      s2 += w*ld1_w[j*320+c];
    }
    Wbig1[idx] = 2.f*wc_w[o*320+c] + cD*s1 + cL*s2;
  }
}

__global__ void bias1_kernel(const float* __restrict__ av_b, const float* __restrict__ ad1_b,
    const float* __restrict__ ad3_b, const float* __restrict__ ld1_b, const float* __restrict__ ld3_b,
    const float* __restrict__ wc_w, const float* __restrict__ wc_b,
    const float* __restrict__ ag, const float* __restrict__ lg, float* __restrict__ bias1)
{
  int r = blockIdx.x*64 + threadIdx.x;
  if (r >= 320) return;
  float cD = 1.4f*ag[0], cL = 0.3f*lg[0];
  if (r < 160){
    float s = 0.f;
    for (int j=0;j<320;j++) s += wc_w[r*320+j]*av_b[j];
    bias1[r] = s;
  } else {
    int o = r - 160;
    float s = wc_b[o];
    for (int j=0;j<320;j++){
      float w = wc_w[o*320+j];
      s += cD*w*(ad1_b[j]+ad3_b[j]) + cL*w*(ld1_b[j]+ld3_b[j]);
    }
    bias1[r] = s;
  }
}

__global__ void composeqk_kernel(const float* __restrict__ aq_w, const float* __restrict__ aq_b,
    const float* __restrict__ ak_w, const float* __restrict__ ak_b,
    const float* __restrict__ w_swin, const float* __restrict__ b_swin,
    const float* __restrict__ w_res, const float* __restrict__ b_res,
    double* __restrict__ Wsw, double* __restrict__ Wres, double* __restrict__ bqk)
{
  int idx = blockIdx.x*256 + threadIdx.x;
  if (idx < 80*192){
    int m = idx/192, j = idx%192;
    const float* aw = (m < 40) ? aq_w + m*320 : ak_w + (m-40)*320;
    double s = 0.0;
    for (int i=0;i<192;i++) s += (double)aw[i]*(double)w_swin[i*192+j];
    Wsw[idx] = s;
  }
  int idx2 = idx - 80*192;
  if (idx2 >= 0 && idx2 < 80*128){
    int m = idx2/128, j = idx2%128;
    const float* aw = (m < 40) ? aq_w + m*320 + 192 : ak_w + (m-40)*320 + 192;
    double s = 0.0;
    for (int i=0;i<128;i++) s += (double)aw[i]*(double)w_res[i*128+j];
    Wres[idx2] = s;
  }
  int idx3 = idx - 80*192 - 80*128;
  if (idx3 >= 0 && idx3 < 80){
    int m = idx3;
    const float* aw = (m < 40) ? aq_w + m*320 : ak_w + (m-40)*320;
    double s = (double)((m < 40) ? aq_b[m] : ak_b[m-40]);
    for (int i=0;i<192;i++) s += (double)aw[i]*(double)b_swin[i];
    for (int i=0;i<128;i++) s += (double)aw[192+i]*(double)b_res[i];
    bqk[m] = s;
  }
}

__global__ void t1_kernel(const float* __restrict__ ad3_w, const float* __restrict__ ld3_w,
    const float* __restrict__ ag, const float* __restrict__ lg, float* __restrict__ Wmix)
{
  long idx = (long)blockIdx.x*256 + threadIdx.x;
  if (idx >= 2880L*320) return;
  int k = (int)(idx / 320), c = (int)(idx % 320);
  int t = k / 320, j = k % 320;
  float cD = 1.4f*ag[0], cL = 0.3f*lg[0];
  long src = (long)(j*320 + c)*9 + t;
  Wmix[idx] = cD*ad3_w[src] + cL*ld3_w[src];
}

// padded composed qk weight [128][320] bf16 hi/lo + fp32 bias[128]
__global__ void cvtqk_kernel(const double* __restrict__ Wsw, const double* __restrict__ Wres,
    const double* __restrict__ bqk,
    unsigned short* __restrict__ Wqkh, unsigned short* __restrict__ Wqkl,
    float* __restrict__ biasqk)
{
  int idx = blockIdx.x*256 + threadIdx.x;
  if (idx < 128*320){
    int row = idx / 320, col = idx % 320;
    double v = 0.0;
    if (row < 80) v = (col < 192) ? Wsw[row*192+col] : Wres[row*128+(col-192)];
    float f = (float)v;
    unsigned short h = f2bf(f);
    Wqkh[idx] = h;
    Wqkl[idx] = f2bf(f - bf2f(h));
  }
  if (idx < 128) biasqk[idx] = (idx < 80) ? (float)bqk[idx] : 0.f;
}

// ---------------- conversions ----------------
__global__ void cvt_bf16_kernel(const float* __restrict__ src, unsigned short* __restrict__ dst, int n){
  int i = blockIdx.x*256 + threadIdx.x;
  if (i < n) dst[i] = f2bf(src[i]);
}
__global__ void cvt_split_kernel(const float* __restrict__ src,
    unsigned short* __restrict__ hi, unsigned short* __restrict__ lo, int n){
  int i = blockIdx.x*256 + threadIdx.x;
  if (i < n){
    float v = src[i];
    unsigned short h = f2bf(v);
    hi[i] = h;
    lo[i] = f2bf(v - bf2f(h));
  }
}
__global__ void cvt_pad_kernel(const float* __restrict__ src, unsigned short* __restrict__ dst){
  int i = blockIdx.x*256 + threadIdx.x;
  if (i >= 192*2880) return;
  int row = i / 2880;
  dst[i] = (row < 160) ? f2bf(src[i]) : (unsigned short)0;
}

// inT: transpose raw inputs to [B][4096][320] bf16 hi/lo
__global__ __launch_bounds__(256) void inT_kernel(
    const float* __restrict__ swin, const float* __restrict__ resnet,
    unsigned short* __restrict__ inThi, unsigned short* __restrict__ inTlo)
{
  __shared__ float t[64][65];
  const int b = blockIdx.z, ct = blockIdx.y, n0 = blockIdx.x*64;
  const float* src; int C, cs0;
  if (ct < 3){ src = swin;   C = 192; cs0 = ct*64; }
  else       { src = resnet; C = 128; cs0 = (ct-3)*64; }
  const int dst0 = ct*64;
  const int tid = threadIdx.x;
  #pragma unroll
  for (int it=0; it<16; ++it){
    int idx = it*256 + tid;
    int c = idx >> 6, n = idx & 63;
    t[c][n] = src[((long)b*C + cs0 + c)*NPIX + n0 + n];
  }
  __syncthreads();
  #pragma unroll
  for (int it=0; it<16; ++it){
    int idx = it*256 + tid;
    int n = idx >> 6, c = idx & 63;
    float v = t[c][n];
    unsigned short h = f2bf(v);
    long o = ((long)b*NPIX + n0 + n)*320 + dst0 + c;
    inThi[o] = h;
    inTlo[o] = f2bf(v - bf2f(h));
  }
}

// pT[n][c] = bf16(kl[c][n]*vl[c][n])
__global__ __launch_bounds__(256) void pT_kernel(
    const float* __restrict__ projL, unsigned short* __restrict__ pT)
{
  __shared__ float t[64][65];
  const int b = blockIdx.z, c0 = blockIdx.y*64, n0 = blockIdx.x*64;
  const float* kl = projL + (long)b*(640L*NPIX);
  const float* vl = kl + 320L*NPIX;
  const int tid = threadIdx.x;
  #pragma unroll
  for (int it=0; it<16; ++it){
    int idx = it*256 + tid;
    int c = idx >> 6, n = idx & 63;
    long s = (long)(c0+c)*NPIX + n0 + n;
    t[c][n] = kl[s]*vl[s];
  }
  __syncthreads();
  #pragma unroll
  for (int it=0; it<16; ++it){
    int idx = it*256 + tid;
    int n = idx >> 6, c = idx & 63;
    pT[((long)b*NPIX + n0 + n)*320 + c0 + c] = f2bf(t[c][n]);
  }
}

// W2h[b][o][c] = bf16(wc[o][c]*colsum[b][c])
__global__ void w2_kernel(const float* __restrict__ wc_w, const float* __restrict__ colsum,
    unsigned short* __restrict__ W2h)
{
  int idx = blockIdx.x*256 + threadIdx.x;
  if (idx >= B4*160*320) return;
  int b = idx / (160*320);
  int rem = idx - b*160*320;
  int c = rem % 320;
  W2h[idx] = f2bf(wc_w[rem]*colsum[b*320+c]);
}

// ---------------- fp64 rank-1 denominator path ----------------
// chsum[b][c] = sum_n input[c][n]  (fp64)
__global__ __launch_bounds__(256) void chsum_kernel(
    const float* __restrict__ swin, const float* __restrict__ resnet,
    double* __restrict__ chsumd)
{
  int b = blockIdx.y, c = blockIdx.x;
  const float* row = (c < 192) ? swin + ((long)b*192 + c)*NPIX
                               : resnet + ((long)b*128 + (c-192))*NPIX;
  double s = 0.0;
  for (int n = threadIdx.x; n < NPIX; n += 256) s += (double)row[n];
  __shared__ double sd[256];
  sd[threadIdx.x] = s; __syncthreads();
  for (int o=128; o; o>>=1){ if (threadIdx.x < o) sd[threadIdx.x] += sd[threadIdx.x+o]; __syncthreads(); }
  if (threadIdx.x == 0) chsumd[b*320+c] = sd[0];
}

// sk[m] = Wk[m,:]@chsum + 4096*bk[m]; wda[b][c] = sum_m sk'[m]*Wq[m][c]; cda[b] = sum_m sk'[m]*bq[m]
__global__ __launch_bounds__(320) void skda_kernel(
    const double* __restrict__ Wsw, const double* __restrict__ Wres,
    const double* __restrict__ bqk, const double* __restrict__ chsumd,
    double* __restrict__ wdad, double* __restrict__ cdad)
{
  int b = blockIdx.x;
  __shared__ double sk[40];
  int tid = threadIdx.x;
  if (tid < 40){
    int m = 40 + tid;   // k rows
    double s = 4096.0 * bqk[m];
    for (int j=0;j<192;j++) s += Wsw[m*192+j]*chsumd[b*320+j];
    for (int j=0;j<128;j++) s += Wres[m*128+j]*chsumd[b*320+192+j];
    sk[tid] = s + 1e-10;
  }
  __syncthreads();
  {
    int c = tid;
    double s = 0.0;
    if (c < 192){ for (int m=0;m<40;m++) s += sk[m]*Wsw[m*192+c]; }
    else        { for (int m=0;m<40;m++) s += sk[m]*Wres[m*128+(c-192)]; }
    wdad[b*320+c] = s;
  }
  if (tid == 0){
    double s = 0.0;
    for (int m=0;m<40;m++) s += sk[m]*bqk[m];
    cdad[b] = s;
  }
}

// norm_a = 1/(wda@in + cda)  [fp64];  norm_l = 1/(cs@kl + eps)
__global__ __launch_bounds__(256) void norm2_kernel(
    const float* __restrict__ swin, const float* __restrict__ resnet,
    const float* __restrict__ projL,
    const double* __restrict__ wdad, const double* __restrict__ cdad,
    const float* __restrict__ colsum,
    float* __restrict__ norm_a, float* __restrict__ norm_l)
{
  int b = blockIdx.y;
  int lane = threadIdx.x & 63;
  int g = threadIdx.x >> 6;
  int px = blockIdx.x*64 + lane;
  __shared__ float cs[320];
  for (int i=threadIdx.x; i<320; i+=256) cs[i] = colsum[b*320+i];
  __syncthreads();
  const float* kl = projL + (long)b*640*NPIX;
  double da = 0.0, dl = 0.0;
  for (int c=g; c<192; c+=4)
    da += wdad[b*320+c]*(double)swin[((long)b*192+c)*NPIX + px];
  for (int c=192+g; c<320; c+=4)
    da += wdad[b*320+c]*(double)resnet[((long)b*128+(c-192))*NPIX + px];
  for (int c=g; c<320; c+=4) dl += (double)kl[(long)c*NPIX + px]*(double)cs[c];
  __shared__ double redA[4][64], redL[4][64];
  redA[g][lane] = da; redL[g][lane] = dl;
  __syncthreads();
  if (g == 0){
    double a = redA[0][lane]+redA[1][lane]+redA[2][lane]+redA[3][lane] + cdad[b];
    double l = redL[0][lane]+redL[1][lane]+redL[2][lane]+redL[3][lane];
    norm_a[(long)b*NPIX+px] = (float)(1.0/a);
    norm_l[(long)b*NPIX+px] = (float)(1.0/(l + 1e-10));
  }
}

// ---------------- reductions ----------------
__global__ void colsum_kernel(const float* __restrict__ projL, const float* __restrict__ qsum,
    float* __restrict__ colsum)
{
  int b = blockIdx.y, c = blockIdx.x;
  const float* kl = projL + (long)b*640*NPIX + (long)c*NPIX;
  const float* qs = qsum + (long)b*NPIX;
  double s = 0.0;
  for (int n=threadIdx.x; n<NPIX; n+=256) s += (double)kl[n]*(double)qs[n];
  __shared__ double sd[256];
  sd[threadIdx.x] = s; __syncthreads();
  for (int o=128; o; o>>=1){ if (threadIdx.x < o) sd[threadIdx.x] += sd[threadIdx.x+o]; __syncthreads(); }
  if (threadIdx.x == 0) colsum[b*320+c] = (float)sd[0];
}

extern "C" void kernel_launch(void* const* d_in, const int* in_sizes, int n_in,
                              void* d_out, int out_size, void* d_ws, size_t ws_size,
                              hipStream_t stream)
{
  const float* swin   = (const float*)d_in[0];
  const float* resnet = (const float*)d_in[1];
  const float* w_swin = (const float*)d_in[2];
  const float* b_swin = (const float*)d_in[3];
  const float* w_res  = (const float*)d_in[4];
  const float* b_res  = (const float*)d_in[5];
  const float* aq_w = (const float*)d_in[6];
  const float* aq_b = (const float*)d_in[7];
  const float* ak_w = (const float*)d_in[8];
  const float* ak_b = (const float*)d_in[9];
  const float* av_w = (const float*)d_in[10];
  const float* av_b = (const float*)d_in[11];
  const float* ad1_w = (const float*)d_in[12];
  const float* ad1_b = (const float*)d_in[13];
  const float* ad3_w = (const float*)d_in[14];
  const float* ad3_b = (const float*)d_in[15];
  const float* ag    = (const float*)d_in[16];
  const float* lq_w = (const float*)d_in[17];
  const float* lq_b = (const float*)d_in[18];
  const float* lk_w = (const float*)d_in[19];
  const float* lk_b = (const float*)d_in[20];
  const float* lv_w = (const float*)d_in[21];
  const float* lv_b = (const float*)d_in[22];
  const float* ld1_w = (const float*)d_in[23];
  const float* ld1_b = (const float*)d_in[24];
  const float* ld3_w = (const float*)d_in[25];
  const float* ld3_b = (const float*)d_in[26];
  const float* lg    = (const float*)d_in[27];
  const float* wc_w = (const float*)d_in[28];
  const float* wc_b = (const float*)d_in[29];
  float* out = (float*)d_out;

  // ---- workspace carve ----
  char* p = (char*)d_ws;
  double* Wsw   = (double*)p; p += (size_t)80*192*8;
  double* Wres  = (double*)p; p += (size_t)80*128*8;
  double* bqk   = (double*)p; p += (size_t)80*8;
  double* chsumd= (double*)p; p += (size_t)B4*320*8;
  double* wdad  = (double*)p; p += (size_t)B4*320*8;
  double* cdad  = (double*)p; p += (size_t)B4*8;
  float* q8f    = (float*)p;  p += (size_t)B4*128*NPIX*4;
  float* proj1  = (float*)p;  p += (size_t)B4*320*NPIX*4;  // rows 0..159 vp, 160..319 outacc
  float* projL  = (float*)p;  p += (size_t)B4*640*NPIX*4;  // rows 0..319 kl, 320..639 vl
  float* qsum   = (float*)p;  p += (size_t)B4*NPIX*4;
  float* norm_a = (float*)p;  p += (size_t)B4*NPIX*4;
  float* norm_l = (float*)p;  p += (size_t)B4*NPIX*4;
  float* colsum = (float*)p;  p += (size_t)B4*320*4;
  float* kvp    = (float*)p;  p += (size_t)B4*40*160*4;
  float* Wbig1  = (float*)p;  p += (size_t)320*320*4;
  float* bias1  = (float*)p;  p += (size_t)320*4;
  float* Wmix   = (float*)p;  p += (size_t)2880*320*4;
  float* Wd3eff = (float*)p;  p += (size_t)160*2880*4;
  float* biasqk = (float*)p;  p += (size_t)128*4;
  p = (char*)(((uintptr_t)p + 255) & ~(uintptr_t)255);
  unsigned short* xTh  = (unsigned short*)p; p += (size_t)B4*NPIX*320*2;
  unsigned short* xTl  = (unsigned short*)p; p += (size_t)B4*NPIX*320*2;
  unsigned short* Wb1h = (unsigned short*)p; p += (size_t)320*320*2;
  unsigned short* Wb1l = (unsigned short*)p; p += (size_t)320*320*2;
  unsigned short* lqh  = (unsigned short*)p; p += (size_t)320*320*2;
  unsigned short* lkh  = (unsigned short*)p; p += (size_t)320*320*2;
  unsigned short* lvh  = (unsigned short*)p; p += (size_t)320*320*2;
  unsigned short* Wd3b = (unsigned short*)p; p += (size_t)192*2880*2;
  unsigned short* wswh = (unsigned short*)p; p += (size_t)192*192*2;
  unsigned short* wswl = (unsigned short*)p; p += (size_t)192*192*2;
  unsigned short* wrsh = (unsigned short*)p; p += (size_t)128*128*2;
  unsigned short* wrsl = (unsigned short*)p; p += (size_t)128*128*2;
  unsigned short* Wqkh = (unsigned short*)p; p += (size_t)128*320*2;
  unsigned short* Wqkl = (unsigned short*)p; p += (size_t)128*320*2;
  if ((size_t)(p - (char*)d_ws) > ws_size) return;

  // aliases over dead regions (stream-ordered safety):
  unsigned short* inThi = (unsigned short*)projL;          // dead once lk/lv write projL
  unsigned short* inTlo = inThi + (size_t)B4*NPIX*320;
  unsigned short* pT = xTl;                                // dead once proj1 split GEMM done
  unsigned short* W2h = (unsigned short*)Wmix;             // dead once Wd3eff composed

  hipMemsetAsync(qsum, 0, (size_t)B4*NPIX*4, stream);
  hipMemsetAsync(kvp,  0, (size_t)B4*40*160*4, stream);

  // ---- weight composition ----
  composeqk_kernel<<<(80*192 + 80*128 + 80 + 255)/256, 256, 0, stream>>>(
      aq_w, aq_b, ak_w, ak_b, w_swin, b_swin, w_res, b_res, Wsw, Wres, bqk);
  compose1_kernel<<<(320*320 + 255)/256, 256, 0, stream>>>(av_w, ad1_w, ld1_w, wc_w, ag, lg, Wbig1);
  bias1_kernel<<<5, 64, 0, stream>>>(av_b, ad1_b, ad3_b, ld1_b, ld3_b, wc_w, wc_b, ag, lg, bias1);
  t1_kernel<<<(2880*320 + 255)/256, 256, 0, stream>>>(ad3_w, ld3_w, ag, lg, Wmix);
  gemm_f32<<<dim3(5,3,9), 256, 0, stream>>>(wc_w, nullptr, Wmix, 320L*320, 320,
      Wd3eff, 320, 2880, 160, 320);

  // ---- weight bf16 conversions ----
  cvt_split_kernel<<<(320*320 + 255)/256, 256, 0, stream>>>(Wbig1, Wb1h, Wb1l, 320*320);
  cvt_bf16_kernel<<<(320*320 + 255)/256, 256, 0, stream>>>(lq_w, lqh, 320*320);
  cvt_bf16_kernel<<<(320*320 + 255)/256, 256, 0, stream>>>(lk_w, lkh, 320*320);
  cvt_bf16_kernel<<<(320*320 + 255)/256, 256, 0, stream>>>(lv_w, lvh, 320*320);
  cvt_pad_kernel<<<(192*2880 + 255)/256, 256, 0, stream>>>(Wd3eff, Wd3b);
  cvt_split_kernel<<<(192*192 + 255)/256, 256, 0, stream>>>(w_swin, wswh, wswl, 192*192);
  cvt_split_kernel<<<(128*128 + 255)/256, 256, 0, stream>>>(w_res, wrsh, wrsl, 128*128);
  cvtqk_kernel<<<(128*320 + 255)/256, 256, 0, stream>>>(Wsw, Wres, bqk, Wqkh, Wqkl, biasqk);

  // ---- fp64 rank-1 denominator composition ----
  chsum_kernel<<<dim3(320,4), 256, 0, stream>>>(swin, resnet, chsumd);
  skda_kernel<<<4, 320, 0, stream>>>(Wsw, Wres, bqk, chsumd, wdad, cdad);

  // ---- input transpose + x-build + q8/k8 via MFMA ----
  inT_kernel<<<dim3(64,5,4), 256, 0, stream>>>(swin, resnet, inThi, inTlo);
  xbuild_mfma<<<dim3(2,64,4), 256, 0, stream>>>(inThi, inTlo, 0, 192,
      wswh, wswl, b_swin, 192, 0, xTh, xTl);
  xbuild_mfma<<<dim3(1,64,4), 256, 0, stream>>>(inThi, inTlo, 192, 128,
      wrsh, wrsl, b_res, 128, 192, xTh, xTl);
  gemm_mfma<0,1><<<dim3(32,2,4), 256, 0, stream>>>(Wqkh, Wqkl, biasqk, inThi, inTlo,
      q8f, 128L*NPIX, nullptr);   // q8f rows 0..39 = q, 40..79 = k (must run before lk/lv overwrite inT)

  // ---- MFMA projections (proj1 last: frees xTl for pT alias) ----
  gemm_mfma<2,0><<<dim3(32,5,4), 256, 0, stream>>>(lqh, nullptr, lq_b, xTh, nullptr,
      nullptr, 0, qsum);
  gemm_mfma<1,0><<<dim3(32,5,4), 256, 0, stream>>>(lkh, nullptr, lk_b, xTh, nullptr,
      projL, 640L*NPIX, nullptr);
  gemm_mfma<0,0><<<dim3(32,5,4), 256, 0, stream>>>(lvh, nullptr, lv_b, xTh, nullptr,
      projL + 320L*NPIX, 640L*NPIX, nullptr);
  gemm_mfma<0,1><<<dim3(32,5,4), 256, 0, stream>>>(Wb1h, Wb1l, bias1, xTh, xTl,
      proj1, 320L*NPIX, nullptr);

  // ---- reductions ----
  kvp_mfma<<<dim3(2,32,4), 256, 0, stream>>>(proj1, q8f, kvp);
  colsum_kernel<<<dim3(320,4), 256, 0, stream>>>(projL, qsum, colsum);
  norm2_kernel<<<dim3(64,4), 256, 0, stream>>>(swin, resnet, projL, wdad, cdad, colsum,
                                               norm_a, norm_l);

  // ---- prep for final ----
  pT_kernel<<<dim3(64,5,4), 256, 0, stream>>>(projL, pT);
  w2_kernel<<<(B4*160*320 + 255)/256, 256, 0, stream>>>(wc_w, colsum, W2h);

  // ---- fused epilogue + composed conv ----
  final_mfma<<<dim3(32,3,4), 256, 0, stream>>>(W2h, pT, kvp, q8f, proj1,
                                               norm_a, norm_l, ag, lg, out);
  conv_mfma<<<dim3(32,3,4), 256, 0, stream>>>(Wd3b, xTh, out);
}

// Round 6
// 388.689 us; speedup vs baseline: 2.2923x; 1.0875x over previous
//
#include <hip/hip_runtime.h>
#include <stdint.h>

#define B4 4
#define NPIX 4096

typedef short sh8 __attribute__((ext_vector_type(8)));
typedef float f4 __attribute__((ext_vector_type(4)));

__device__ __forceinline__ float delu_f(float v){
  return v > 0.f ? __fmaf_rn(10.f, v, 1.f) : __expf(10.f*v);
}
__device__ __forceinline__ unsigned short f2bf(float f){
  unsigned u = __float_as_uint(f);
  u += 0x7fffu + ((u>>16)&1u);
  return (unsigned short)(u>>16);
}
__device__ __forceinline__ float bf2f(unsigned short h){
  return __uint_as_float(((unsigned)h)<<16);
}

// ---------------- generic 64x64x16 f32 tile GEMM (weight-compose only) ----------------
__global__ __launch_bounds__(256) void gemm_f32(
    const float* __restrict__ W, const float* __restrict__ bias,
    const float* __restrict__ X, long xStride, int ldX,
    float* __restrict__ Out, long outStride, int ldOut,
    int M, int K)
{
  __shared__ float Wt[16][64];
  __shared__ float Xt[16][64];
  const int b  = blockIdx.z;
  const int m0 = blockIdx.y * 64;
  const int n0 = blockIdx.x * 64;
  const int tid = threadIdx.x;
  const int tc = tid & 15, tr = tid >> 4;
  const int wm = tid >> 2, wk = (tid & 3) << 2;
  const int xk = tid >> 4, xn = (tid & 15) << 2;
  const float* Xb = X + (long)b * xStride;
  float acc[4][4] = {};

  for (int k0 = 0; k0 < K; k0 += 16) {
    float4 wv4;
    if (m0 + wm < M) wv4 = *reinterpret_cast<const float4*>(W + (long)(m0+wm)*K + k0 + wk);
    else wv4 = make_float4(0.f,0.f,0.f,0.f);
    Wt[wk+0][wm] = wv4.x; Wt[wk+1][wm] = wv4.y; Wt[wk+2][wm] = wv4.z; Wt[wk+3][wm] = wv4.w;
    *reinterpret_cast<float4*>(&Xt[xk][xn]) =
        *reinterpret_cast<const float4*>(Xb + (long)(k0+xk)*ldX + n0 + xn);
    __syncthreads();
    #pragma unroll
    for (int kk = 0; kk < 16; ++kk) {
      float4 a4 = *reinterpret_cast<const float4*>(&Wt[kk][tr<<2]);
      float4 b4 = *reinterpret_cast<const float4*>(&Xt[kk][tc<<2]);
      float av[4] = {a4.x,a4.y,a4.z,a4.w};
      float bv[4] = {b4.x,b4.y,b4.z,b4.w};
      #pragma unroll
      for (int i=0;i<4;i++)
        #pragma unroll
        for (int j=0;j<4;j++) acc[i][j] = __fmaf_rn(av[i], bv[j], acc[i][j]);
    }
    __syncthreads();
  }

  #pragma unroll
  for (int i=0;i<4;i++){
    int m = m0 + (tr<<2) + i;
    if (m < M) {
      float bv = bias ? bias[m] : 0.f;
      float r[4];
      #pragma unroll
      for (int j=0;j<4;j++) r[j] = acc[i][j] + bv;
      *reinterpret_cast<float4*>(Out + (long)b*outStride + (long)m*ldOut + n0 + (tc<<2)) =
          make_float4(r[0],r[1],r[2],r[3]);
    }
  }
}

// ---------------- bf16 MFMA GEMM: C[m][n] = sum_k W[m][k] * xT[n][k] ----------------
// EP: 0 = store acc+bias; 1 = delu(acc+bias); 2 = delu column-sum -> qsum
template<int EP, int SPLIT>
__global__ __launch_bounds__(256) void gemm_mfma(
    const unsigned short* __restrict__ Whi, const unsigned short* __restrict__ Wlo,
    const float* __restrict__ bias,
    const unsigned short* __restrict__ Xhi, const unsigned short* __restrict__ Xlo,
    float* __restrict__ Out, long outStride, float* __restrict__ qsum)
{
  __shared__ unsigned short Ah[64][40];
  __shared__ unsigned short Bh[128][40];
  __shared__ unsigned short Al[SPLIT?64:8][40];
  __shared__ unsigned short Bl[SPLIT?128:8][40];
  const int b  = blockIdx.z;
  const int m0 = blockIdx.y * 64;
  const int n0 = blockIdx.x * 128;
  const int tid = threadIdx.x;
  const int sRow = tid >> 2, sK = (tid & 3) << 3;
  const int lane = tid & 63, w = tid >> 6;
  const int wr = w >> 1, wc = w & 1;
  const int fr = lane & 15, fko = (lane >> 4) << 3;

  f4 z4 = {0.f,0.f,0.f,0.f};
  f4 acc[2][4];
  #pragma unroll
  for (int mf=0; mf<2; mf++)
    #pragma unroll
    for (int nf=0; nf<4; nf++) acc[mf][nf] = z4;

  for (int k0 = 0; k0 < 320; k0 += 32) {
    *reinterpret_cast<sh8*>(&Ah[sRow][sK]) =
        *reinterpret_cast<const sh8*>(Whi + (long)(m0+sRow)*320 + k0 + sK);
    if (SPLIT)
      *reinterpret_cast<sh8*>(&Al[sRow][sK]) =
          *reinterpret_cast<const sh8*>(Wlo + (long)(m0+sRow)*320 + k0 + sK);
    #pragma unroll
    for (int r=0; r<2; r++){
      int row = r*64 + sRow;
      long src = ((long)b*NPIX + n0 + row)*320 + k0 + sK;
      *reinterpret_cast<sh8*>(&Bh[row][sK]) = *reinterpret_cast<const sh8*>(Xhi + src);
      if (SPLIT)
        *reinterpret_cast<sh8*>(&Bl[row][sK]) = *reinterpret_cast<const sh8*>(Xlo + src);
    }
    __syncthreads();
    sh8 aH[2], bH[4];
    #pragma unroll
    for (int mf=0; mf<2; mf++)
      aH[mf] = *reinterpret_cast<const sh8*>(&Ah[wr*32 + mf*16 + fr][fko]);
    #pragma unroll
    for (int nf=0; nf<4; nf++)
      bH[nf] = *reinterpret_cast<const sh8*>(&Bh[wc*64 + nf*16 + fr][fko]);
    #pragma unroll
    for (int mf=0; mf<2; mf++)
      #pragma unroll
      for (int nf=0; nf<4; nf++)
        acc[mf][nf] = __builtin_amdgcn_mfma_f32_16x16x32_bf16(aH[mf], bH[nf], acc[mf][nf], 0,0,0);
    if (SPLIT){
      sh8 aL[2], bL[4];
      #pragma unroll
      for (int mf=0; mf<2; mf++)
        aL[mf] = *reinterpret_cast<const sh8*>(&Al[wr*32 + mf*16 + fr][fko]);
      #pragma unroll
      for (int nf=0; nf<4; nf++)
        bL[nf] = *reinterpret_cast<const sh8*>(&Bl[wc*64 + nf*16 + fr][fko]);
      #pragma unroll
      for (int mf=0; mf<2; mf++)
        #pragma unroll
        for (int nf=0; nf<4; nf++){
          acc[mf][nf] = __builtin_amdgcn_mfma_f32_16x16x32_bf16(aL[mf], bH[nf], acc[mf][nf], 0,0,0);
          acc[mf][nf] = __builtin_amdgcn_mfma_f32_16x16x32_bf16(aH[mf], bL[nf], acc[mf][nf], 0,0,0);
        }
    }
    __syncthreads();
  }

  const int orow0 = m0 + wr*32;
  const int ocol  = n0 + wc*64;
  if (EP == 2){
    #pragma unroll
    for (int nf=0; nf<4; nf++){
      float s = 0.f;
      #pragma unroll
      for (int mf=0; mf<2; mf++)
        #pragma unroll
        for (int r=0; r<4; r++)
          s += delu_f(acc[mf][nf][r] + bias[orow0 + mf*16 + ((lane>>4)<<2) + r]);
      s += __shfl_xor(s, 16, 64);
      s += __shfl_xor(s, 32, 64);
      if (lane < 16) atomicAdd(&qsum[(long)b*NPIX + ocol + nf*16 + fr], s);
    }
  } else {
    #pragma unroll
    for (int mf=0; mf<2; mf++)
      #pragma unroll
      for (int r=0; r<4; r++){
        int row = orow0 + mf*16 + ((lane>>4)<<2) + r;
        float bv = bias ? bias[row] : 0.f;
        #pragma unroll
        for (int nf=0; nf<4; nf++){
          float v = acc[mf][nf][r] + bv;
          if (EP == 1) v = delu_f(v);
          Out[(long)b*outStride + (long)row*NPIX + ocol + nf*16 + fr] = v;
        }
      }
  }
}

// ---------------- x-build MFMA: role-flipped (A = pixels, B = weight rows), 3-pass split ----------------
__global__ __launch_bounds__(256) void xbuild_mfma(
    const unsigned short* __restrict__ inThi, const unsigned short* __restrict__ inTlo,
    int cOff, int K,
    const unsigned short* __restrict__ Wh, const unsigned short* __restrict__ Wl,
    const float* __restrict__ bias, int outC, int tOff,
    unsigned short* __restrict__ xTh, unsigned short* __restrict__ xTl)
{
  __shared__ unsigned short Ah[64][40];
  __shared__ unsigned short Bh[128][40];
  __shared__ unsigned short Al[64][40];
  __shared__ unsigned short Bl[128][40];
  const int b  = blockIdx.z;
  const int m0 = blockIdx.y * 64;
  const int n0 = blockIdx.x * 128;
  const int tid = threadIdx.x;
  const int sRow = tid >> 2, sK = (tid & 3) << 3;
  const int lane = tid & 63, w = tid >> 6;
  const int wr = w >> 1, wc = w & 1;
  const int fr = lane & 15, fko = (lane >> 4) << 3;

  f4 z4 = {0.f,0.f,0.f,0.f};
  f4 acc[2][4];
  #pragma unroll
  for (int mf=0; mf<2; mf++)
    #pragma unroll
    for (int nf=0; nf<4; nf++) acc[mf][nf] = z4;

  for (int k0 = 0; k0 < K; k0 += 32) {
    long asrc = ((long)b*NPIX + m0 + sRow)*320 + cOff + k0 + sK;
    *reinterpret_cast<sh8*>(&Ah[sRow][sK]) = *reinterpret_cast<const sh8*>(inThi + asrc);
    *reinterpret_cast<sh8*>(&Al[sRow][sK]) = *reinterpret_cast<const sh8*>(inTlo + asrc);
    #pragma unroll
    for (int r=0; r<2; r++){
      int row = r*64 + sRow;
      sh8 vh = {0,0,0,0,0,0,0,0}, vl = {0,0,0,0,0,0,0,0};
      if (n0 + row < outC){
        vh = *reinterpret_cast<const sh8*>(Wh + (long)(n0+row)*K + k0 + sK);
        vl = *reinterpret_cast<const sh8*>(Wl + (long)(n0+row)*K + k0 + sK);
      }
      *reinterpret_cast<sh8*>(&Bh[row][sK]) = vh;
      *reinterpret_cast<sh8*>(&Bl[row][sK]) = vl;
    }
    __syncthreads();
    sh8 aH[2], aL[2], bH[4], bL[4];
    #pragma unroll
    for (int mf=0; mf<2; mf++){
      aH[mf] = *reinterpret_cast<const sh8*>(&Ah[wr*32 + mf*16 + fr][fko]);
      aL[mf] = *reinterpret_cast<const sh8*>(&Al[wr*32 + mf*16 + fr][fko]);
    }
    #pragma unroll
    for (int nf=0; nf<4; nf++){
      bH[nf] = *reinterpret_cast<const sh8*>(&Bh[wc*64 + nf*16 + fr][fko]);
      bL[nf] = *reinterpret_cast<const sh8*>(&Bl[wc*64 + nf*16 + fr][fko]);
    }
    #pragma unroll
    for (int mf=0; mf<2; mf++)
      #pragma unroll
      for (int nf=0; nf<4; nf++){
        acc[mf][nf] = __builtin_amdgcn_mfma_f32_16x16x32_bf16(aH[mf], bH[nf], acc[mf][nf], 0,0,0);
        acc[mf][nf] = __builtin_amdgcn_mfma_f32_16x16x32_bf16(aH[mf], bL[nf], acc[mf][nf], 0,0,0);
        acc[mf][nf] = __builtin_amdgcn_mfma_f32_16x16x32_bf16(aL[mf], bH[nf], acc[mf][nf], 0,0,0);
      }
    __syncthreads();
  }

  const int opix0 = m0 + wr*32;
  const int ocol  = n0 + wc*64;
  #pragma unroll
  for (int mf=0; mf<2; mf++)
    #pragma unroll
    for (int r=0; r<4; r++){
      int pix = opix0 + mf*16 + ((lane>>4)<<2) + r;
      #pragma unroll
      for (int nf=0; nf<4; nf++){
        int col = ocol + nf*16 + fr;
        if (col < outC){
          float v = acc[mf][nf][r] + bias[col];
          unsigned short h = f2bf(v);
          long o = ((long)b*NPIX + pix)*320 + tOff + col;
          xTh[o] = h;
          xTl[o] = f2bf(v - bf2f(h));
        }
      }
    }
}

// ---------------- kvp via MFMA, K-split: kvp[b][m][o] = sum_n k8[m][n]*vp[o][n] ----------------
__global__ __launch_bounds__(256) void kvp_mfma(
    const float* __restrict__ proj1, const float* __restrict__ q8f,
    float* __restrict__ kvp)
{
  __shared__ unsigned short Ah[64][40];
  __shared__ unsigned short Bh[128][40];
  __shared__ unsigned short Al[64][40];
  __shared__ unsigned short Bl[128][40];
  const int b = blockIdx.z;
  const int o0 = blockIdx.x * 128;
  const int kbase = blockIdx.y * 128;
  const int tid = threadIdx.x;
  const int sRow = tid >> 2, sK = (tid & 3) << 3;
  const int lane = tid & 63, w = tid >> 6;
  const int wr = w >> 1, wc = w & 1;
  const int fr = lane & 15, fko = (lane >> 4) << 3;
  const float* k8 = q8f + ((long)b*128 + 40)*NPIX;
  const float* vp = proj1 + (long)b*(320L*NPIX);

  f4 z4 = {0.f,0.f,0.f,0.f};
  f4 acc[2][4];
  #pragma unroll
  for (int mf=0; mf<2; mf++)
    #pragma unroll
    for (int nf=0; nf<4; nf++) acc[mf][nf] = z4;

  for (int k0 = 0; k0 < 128; k0 += 32) {
    {
      float vv[8] = {0,0,0,0,0,0,0,0};
      if (sRow < 40){
        float4 a4 = *reinterpret_cast<const float4*>(k8 + (long)sRow*NPIX + kbase + k0 + sK);
        float4 b4 = *reinterpret_cast<const float4*>(k8 + (long)sRow*NPIX + kbase + k0 + sK + 4);
        vv[0]=a4.x; vv[1]=a4.y; vv[2]=a4.z; vv[3]=a4.w;
        vv[4]=b4.x; vv[5]=b4.y; vv[6]=b4.z; vv[7]=b4.w;
      }
      #pragma unroll
      for (int i=0;i<8;i++){
        unsigned short h = f2bf(vv[i]);
        Ah[sRow][sK+i] = h;
        Al[sRow][sK+i] = f2bf(vv[i] - bf2f(h));
      }
    }
    #pragma unroll
    for (int r=0;r<2;r++){
      int row = r*64 + sRow;
      int o = o0 + row;
      float vv[8] = {0,0,0,0,0,0,0,0};
      if (o < 160){
        float4 v4a = *reinterpret_cast<const float4*>(vp + (long)o*NPIX + kbase + k0 + sK);
        float4 v4b = *reinterpret_cast<const float4*>(vp + (long)o*NPIX + kbase + k0 + sK + 4);
        vv[0]=v4a.x; vv[1]=v4a.y; vv[2]=v4a.z; vv[3]=v4a.w;
        vv[4]=v4b.x; vv[5]=v4b.y; vv[6]=v4b.z; vv[7]=v4b.w;
      }
      #pragma unroll
      for (int i=0;i<8;i++){
        unsigned short h = f2bf(vv[i]);
        Bh[row][sK+i] = h;
        Bl[row][sK+i] = f2bf(vv[i] - bf2f(h));
      }
    }
    __syncthreads();
    sh8 aH[2], aL[2], bH[4], bL[4];
    #pragma unroll
    for (int mf=0; mf<2; mf++){
      aH[mf] = *reinterpret_cast<const sh8*>(&Ah[wr*32 + mf*16 + fr][fko]);
      aL[mf] = *reinterpret_cast<const sh8*>(&Al[wr*32 + mf*16 + fr][fko]);
    }
    #pragma unroll
    for (int nf=0; nf<4; nf++){
      bH[nf] = *reinterpret_cast<const sh8*>(&Bh[wc*64 + nf*16 + fr][fko]);
      bL[nf] = *reinterpret_cast<const sh8*>(&Bl[wc*64 + nf*16 + fr][fko]);
    }
    #pragma unroll
    for (int mf=0; mf<2; mf++)
      #pragma unroll
      for (int nf=0; nf<4; nf++){
        acc[mf][nf] = __builtin_amdgcn_mfma_f32_16x16x32_bf16(aH[mf], bH[nf], acc[mf][nf], 0,0,0);
        acc[mf][nf] = __builtin_amdgcn_mfma_f32_16x16x32_bf16(aH[mf], bL[nf], acc[mf][nf], 0,0,0);
        acc[mf][nf] = __builtin_amdgcn_mfma_f32_16x16x32_bf16(aL[mf], bH[nf], acc[mf][nf], 0,0,0);
      }
    __syncthreads();
  }

  const int orow0 = wr*32;
  const int ocol  = o0 + wc*64;
  #pragma unroll
  for (int mf=0; mf<2; mf++)
    #pragma unroll
    for (int r=0; r<4; r++){
      int row = orow0 + mf*16 + ((lane>>4)<<2) + r;
      if (row < 40){
        #pragma unroll
        for (int nf=0; nf<4; nf++){
          int col = ocol + nf*16 + fr;
          if (col < 160)
            atomicAdd(&kvp[((long)b*40 + row)*160 + col], acc[mf][nf][r]);
        }
      }
    }
}

// ---------------- final MFMA: out = outacc + cL*norm_l*(W2@pT) + cA*norm_a*(kvpT@q8) ----------------
__global__ __launch_bounds__(256) void final_mfma(
    const unsigned short* __restrict__ W2h,
    const unsigned short* __restrict__ pT,
    const float* __restrict__ kvp,
    const float* __restrict__ q8f,
    const float* __restrict__ proj1,
    const float* __restrict__ norm_a, const float* __restrict__ norm_l,
    const float* __restrict__ ag, const float* __restrict__ lg,
    float* __restrict__ Out)
{
  __shared__ unsigned short Ah[64][40];
  __shared__ unsigned short Bh[128][40];
  __shared__ unsigned short Al[64][40];
  __shared__ unsigned short Bl[128][40];
  const int b  = blockIdx.z;
  const int m0 = blockIdx.y * 64;
  const int n0 = blockIdx.x * 128;
  const int tid = threadIdx.x;
  const int sRow = tid >> 2, sK = (tid & 3) << 3;
  const int lane = tid & 63, w = tid >> 6;
  const int wr = w >> 1, wc = w & 1;
  const int fr = lane & 15, fko = (lane >> 4) << 3;

  f4 z4 = {0.f,0.f,0.f,0.f};
  f4 acc1[2][4], acc2[2][4];
  #pragma unroll
  for (int mf=0; mf<2; mf++)
    #pragma unroll
    for (int nf=0; nf<4; nf++){ acc1[mf][nf] = z4; acc2[mf][nf] = z4; }

  for (int k0 = 0; k0 < 320; k0 += 32) {
    sh8 av = {0,0,0,0,0,0,0,0};
    if (m0 + sRow < 160)
      av = *reinterpret_cast<const sh8*>(W2h + ((long)b*160 + m0 + sRow)*320 + k0 + sK);
    *reinterpret_cast<sh8*>(&Ah[sRow][sK]) = av;
    #pragma unroll
    for (int r=0; r<2; r++){
      int row = r*64 + sRow;
      *reinterpret_cast<sh8*>(&Bh[row][sK]) =
          *reinterpret_cast<const sh8*>(pT + ((long)b*NPIX + n0 + row)*320 + k0 + sK);
    }
    __syncthreads();
    sh8 aH[2], bH[4];
    #pragma unroll
    for (int mf=0; mf<2; mf++)
      aH[mf] = *reinterpret_cast<const sh8*>(&Ah[wr*32 + mf*16 + fr][fko]);
    #pragma unroll
    for (int nf=0; nf<4; nf++)
      bH[nf] = *reinterpret_cast<const sh8*>(&Bh[wc*64 + nf*16 + fr][fko]);
    #pragma unroll
    for (int mf=0; mf<2; mf++)
      #pragma unroll
      for (int nf=0; nf<4; nf++)
        acc1[mf][nf] = __builtin_amdgcn_mfma_f32_16x16x32_bf16(aH[mf], bH[nf], acc1[mf][nf], 0,0,0);
    __syncthreads();
  }

  for (int k0 = 0; k0 < 64; k0 += 32) {
    {
      int m = m0 + sRow;
      #pragma unroll
      for (int i=0;i<8;i++){
        int kk = k0 + sK + i;
        float v = (kk < 40 && m < 160) ? kvp[((long)b*40 + kk)*160 + m] : 0.f;
        unsigned short h = f2bf(v);
        Ah[sRow][sK+i] = h;
        Al[sRow][sK+i] = f2bf(v - bf2f(h));
      }
    }
    #pragma unroll
    for (int r=0; r<2; r++){
      int row = r*64 + sRow;
      int pix = n0 + row;
      #pragma unroll
      for (int i=0;i<8;i++){
        int kk = k0 + sK + i;
        float v = (kk < 40) ? q8f[((long)b*128 + kk)*NPIX + pix] : 0.f;
        unsigned short h = f2bf(v);
        Bh[row][sK+i] = h;
        Bl[row][sK+i] = f2bf(v - bf2f(h));
      }
    }
    __syncthreads();
    sh8 aH[2], aL[2], bH[4], bL[4];
    #pragma unroll
    for (int mf=0; mf<2; mf++){
      aH[mf] = *reinterpret_cast<const sh8*>(&Ah[wr*32 + mf*16 + fr][fko]);
      aL[mf] = *reinterpret_cast<const sh8*>(&Al[wr*32 + mf*16 + fr][fko]);
    }
    #pragma unroll
    for (int nf=0; nf<4; nf++){
      bH[nf] = *reinterpret_cast<const sh8*>(&Bh[wc*64 + nf*16 + fr][fko]);
      bL[nf] = *reinterpret_cast<const sh8*>(&Bl[wc*64 + nf*16 + fr][fko]);
    }
    #pragma unroll
    for (int mf=0; mf<2; mf++)
      #pragma unroll
      for (int nf=0; nf<4; nf++){
        acc2[mf][nf] = __builtin_amdgcn_mfma_f32_16x16x32_bf16(aH[mf], bH[nf], acc2[mf][nf], 0,0,0);
        acc2[mf][nf] = __builtin_amdgcn_mfma_f32_16x16x32_bf16(aH[mf], bL[nf], acc2[mf][nf], 0,0,0);
        acc2[mf][nf] = __builtin_amdgcn_mfma_f32_16x16x32_bf16(aL[mf], bH[nf], acc2[mf][nf], 0,0,0);
      }
    __syncthreads();
  }

  const float cA = 0.7f*ag[0], cL = 0.3f*lg[0];
  const int orow0 = m0 + wr*32;
  const int ocol  = n0 + wc*64;
  #pragma unroll
  for (int mf=0; mf<2; mf++)
    #pragma unroll
    for (int r=0; r<4; r++){
      int row = orow0 + mf*16 + ((lane>>4)<<2) + r;
      if (row < 160){
        const float* oa = proj1 + (long)b*(320L*NPIX) + (long)(160+row)*NPIX;
        #pragma unroll
        for (int nf=0; nf<4; nf++){
          int col = ocol + nf*16 + fr;
          Out[((long)b*160 + row)*NPIX + col] =
              oa[col] + cL*norm_l[(long)b*NPIX+col]*acc1[mf][nf][r]
                      + cA*norm_a[(long)b*NPIX+col]*acc2[mf][nf][r];
        }
      }
    }
}

// ---------------- composed 3x3 conv via MFMA, halo-staged (one barrier pair per 32-ch chunk) ----
// Block: 64 out-rows x 128 pixels (2 image rows). A: all 9 taps staged; B: 4x66 halo staged.
// Horizontal halo (cols -1 / 64) is always zero since image width == 64.
__global__ __launch_bounds__(256) void conv_mfma(
    const unsigned short* __restrict__ Wd3,   // [192][2880] bf16 (rows 160.. zero)
    const unsigned short* __restrict__ Xhi,   // [B][4096][320] bf16
    float* __restrict__ Out)                  // [B][160][4096] +=
{
  __shared__ unsigned short Ah[64][296];        // [row][t*32+c], pad 288->296
  __shared__ unsigned short Bs[4*66*40];        // [(r*66+w)*40 + c]
  const int b  = blockIdx.z;
  const int m0 = blockIdx.y * 64;
  const int n0 = blockIdx.x * 128;
  const int h0 = n0 >> 6;                       // first of 2 image rows
  const int tid = threadIdx.x;
  const int lane = tid & 63, w = tid >> 6;
  const int wr = w >> 1, wc = w & 1;
  const int fr = lane & 15, fko = (lane >> 4) << 3;

  f4 z4 = {0.f,0.f,0.f,0.f};
  f4 acc[2][4];
  #pragma unroll
  for (int mf=0; mf<2; mf++)
    #pragma unroll
    for (int nf=0; nf<4; nf++) acc[mf][nf] = z4;

  // precompute per-thread B staging coords
  const int sr = tid >> 6;          // halo row 0..3
  const int sw = tid & 63;          // image col 0..63
  const int hp = h0 - 1 + sr;
  const bool rowok = (hp >= 0) && (hp < 64);
  // zero the horizontal halo columns once (w-slot 0 and 65)
  if (tid < 32){
    int r = tid >> 3;               // 0..3
    int ws = (tid & 4) ? 65 : 0;
    int j = tid & 3;
    sh8 z = {0,0,0,0,0,0,0,0};
    *reinterpret_cast<sh8*>(&Bs[(r*66 + ws)*40 + j*8]) = z;
  }

  // A staging coords: row = tid>>2, cc = (tid&3)*8
  const int arow = tid >> 2;
  const int acc8 = (tid & 3) << 3;

  for (int c0 = 0; c0 < 320; c0 += 32){
    // stage A: 9 taps x 32 ch for 64 rows
    #pragma unroll
    for (int t=0; t<9; t++)
      *reinterpret_cast<sh8*>(&Ah[arow][t*32 + acc8]) =
          *reinterpret_cast<const sh8*>(Wd3 + (long)(m0+arow)*2880 + t*320 + c0 + acc8);
    // stage B halo center: 4 rows x 64 cols x 32 ch
    {
      const unsigned short* src = Xhi + ((long)b*NPIX + hp*64 + sw)*320 + c0;
      unsigned short* dst = &Bs[(sr*66 + sw + 1)*40];
      sh8 z = {0,0,0,0,0,0,0,0};
      #pragma unroll
      for (int j=0;j<4;j++){
        sh8 v = z;
        if (rowok) v = *reinterpret_cast<const sh8*>(src + j*8);
        *reinterpret_cast<sh8*>(dst + j*8) = v;
      }
    }
    __syncthreads();
    #pragma unroll
    for (int t=0; t<9; t++){
      const int dh = t/3 - 1, dw = t%3 - 1;
      sh8 aH[2], bH[4];
      #pragma unroll
      for (int mf=0; mf<2; mf++)
        aH[mf] = *reinterpret_cast<const sh8*>(&Ah[wr*32 + mf*16 + fr][t*32 + fko]);
      #pragma unroll
      for (int nf=0; nf<4; nf++){
        int np = wc*64 + nf*16 + fr;          // local pixel 0..127
        int lr = (np >> 6) + dh + 1;          // halo row 0..3
        int lw = (np & 63) + dw + 1;          // halo col 0..65
        bH[nf] = *reinterpret_cast<const sh8*>(&Bs[(lr*66 + lw)*40 + fko]);
      }
      #pragma unroll
      for (int mf=0; mf<2; mf++)
        #pragma unroll
        for (int nf=0; nf<4; nf++)
          acc[mf][nf] = __builtin_amdgcn_mfma_f32_16x16x32_bf16(aH[mf], bH[nf], acc[mf][nf], 0,0,0);
    }
    __syncthreads();
  }

  const int orow0 = m0 + wr*32;
  const int ocol  = n0 + wc*64;
  #pragma unroll
  for (int mf=0; mf<2; mf++)
    #pragma unroll
    for (int r=0; r<4; r++){
      int row = orow0 + mf*16 + ((lane>>4)<<2) + r;
      if (row < 160){
        #pragma unroll
        for (int nf=0; nf<4; nf++){
          long o = ((long)b*160 + row)*NPIX + ocol + nf*16 + fr;
          Out[o] += acc[mf][nf][r];
        }
      }
    }
}

// ---------------- weight composition kernels ----------------
__global__ void compose1_kernel(const float* __restrict__ av_w, const float* __restrict__ ad1_w,
    const float* __restrict__ ld1_w, const float* __restrict__ wc_w,
    const float* __restrict__ ag, const float* __restrict__ lg, float* __restrict__ Wbig1)
{
  int idx = blockIdx.x*256 + threadIdx.x;
  if (idx >= 320*320) return;
  int r = idx / 320, c = idx % 320;
  float cD = 1.4f*ag[0], cL = 0.3f*lg[0];
  if (r < 160) {
    float s = 0.f;
    for (int j=0;j<320;j++) s += wc_w[r*320+j]*av_w[j*320+c];
    Wbig1[idx] = s;
  } else {
    int o = r - 160;
    float s1 = 0.f, s2 = 0.f;
    for (int j=0;j<320;j++){
      float w = wc_w[o*320+j];
      s1 += w*ad1_w[j*320+c];
      s2 += w*ld1_w[j*320+c];
    }
    Wbig1[idx] = 2.f*wc_w[o*320+c] + cD*s1 + cL*s2;
  }
}

__global__ void bias1_kernel(const float* __restrict__ av_b, const float* __restrict__ ad1_b,
    const float* __restrict__ ad3_b, const float* __restrict__ ld1_b, const float* __restrict__ ld3_b,
    const float* __restrict__ wc_w, const float* __restrict__ wc_b,
    const float* __restrict__ ag, const float* __restrict__ lg, float* __restrict__ bias1)
{
  int r = blockIdx.x*64 + threadIdx.x;
  if (r >= 320) return;
  float cD = 1.4f*ag[0], cL = 0.3f*lg[0];
  if (r < 160){
    float s = 0.f;
    for (int j=0;j<320;j++) s += wc_w[r*320+j]*av_b[j];
    bias1[r] = s;
  } else {
    int o = r - 160;
    float s = wc_b[o];
    for (int j=0;j<320;j++){
      float w = wc_w[o*320+j];
      s += cD*w*(ad1_b[j]+ad3_b[j]) + cL*w*(ld1_b[j]+ld3_b[j]);
    }
    bias1[r] = s;
  }
}

__global__ void composeqk_kernel(const float* __restrict__ aq_w, const float* __restrict__ aq_b,
    const float* __restrict__ ak_w, const float* __restrict__ ak_b,
    const float* __restrict__ w_swin, const float* __restrict__ b_swin,
    const float* __restrict__ w_res, const float* __restrict__ b_res,
    double* __restrict__ Wsw, double* __restrict__ Wres, double* __restrict__ bqk)
{
  int idx = blockIdx.x*256 + threadIdx.x;
  if (idx < 80*192){
    int m = idx/192, j = idx%192;
    const float* aw = (m < 40) ? aq_w + m*320 : ak_w + (m-40)*320;
    double s = 0.0;
    for (int i=0;i<192;i++) s += (double)aw[i]*(double)w_swin[i*192+j];
    Wsw[idx] = s;
  }
  int idx2 = idx - 80*192;
  if (idx2 >= 0 && idx2 < 80*128){
    int m = idx2/128, j = idx2%128;
    const float* aw = (m < 40) ? aq_w + m*320 + 192 : ak_w + (m-40)*320 + 192;
    double s = 0.0;
    for (int i=0;i<128;i++) s += (double)aw[i]*(double)w_res[i*128+j];
    Wres[idx2] = s;
  }
  int idx3 = idx - 80*192 - 80*128;
  if (idx3 >= 0 && idx3 < 80){
    int m = idx3;
    const float* aw = (m < 40) ? aq_w + m*320 : ak_w + (m-40)*320;
    double s = (double)((m < 40) ? aq_b[m] : ak_b[m-40]);
    for (int i=0;i<192;i++) s += (double)aw[i]*(double)b_swin[i];
    for (int i=0;i<128;i++) s += (double)aw[192+i]*(double)b_res[i];
    bqk[m] = s;
  }
}

__global__ void t1_kernel(const float* __restrict__ ad3_w, const float* __restrict__ ld3_w,
    const float* __restrict__ ag, const float* __restrict__ lg, float* __restrict__ Wmix)
{
  long idx = (long)blockIdx.x*256 + threadIdx.x;
  if (idx >= 2880L*320) return;
  int k = (int)(idx / 320), c = (int)(idx % 320);
  int t = k / 320, j = k % 320;
  float cD = 1.4f*ag[0], cL = 0.3f*lg[0];
  long src = (long)(j*320 + c)*9 + t;
  Wmix[idx] = cD*ad3_w[src] + cL*ld3_w[src];
}

// padded composed qk weight [128][320] bf16 hi/lo + fp32 bias[128]
__global__ void cvtqk_kernel(const double* __restrict__ Wsw, const double* __restrict__ Wres,
    const double* __restrict__ bqk,
    unsigned short* __restrict__ Wqkh, unsigned short* __restrict__ Wqkl,
    float* __restrict__ biasqk)
{
  int idx = blockIdx.x*256 + threadIdx.x;
  if (idx < 128*320){
    int row = idx / 320, col = idx % 320;
    double v = 0.0;
    if (row < 80) v = (col < 192) ? Wsw[row*192+col] : Wres[row*128+(col-192)];
    float f = (float)v;
    unsigned short h = f2bf(f);
    Wqkh[idx] = h;
    Wqkl[idx] = f2bf(f - bf2f(h));
  }
  if (idx < 128) biasqk[idx] = (idx < 80) ? (float)bqk[idx] : 0.f;
}

// ---------------- conversions ----------------
__global__ void cvt_bf16_kernel(const float* __restrict__ src, unsigned short* __restrict__ dst, int n){
  int i = blockIdx.x*256 + threadIdx.x;
  if (i < n) dst[i] = f2bf(src[i]);
}
__global__ void cvt_split_kernel(const float* __restrict__ src,
    unsigned short* __restrict__ hi, unsigned short* __restrict__ lo, int n){
  int i = blockIdx.x*256 + threadIdx.x;
  if (i < n){
    float v = src[i];
    unsigned short h = f2bf(v);
    hi[i] = h;
    lo[i] = f2bf(v - bf2f(h));
  }
}
__global__ void cvt_pad_kernel(const float* __restrict__ src, unsigned short* __restrict__ dst){
  int i = blockIdx.x*256 + threadIdx.x;
  if (i >= 192*2880) return;
  int row = i / 2880;
  dst[i] = (row < 160) ? f2bf(src[i]) : (unsigned short)0;
}

// inT: transpose raw inputs to [B][4096][320] bf16 hi/lo
__global__ __launch_bounds__(256) void inT_kernel(
    const float* __restrict__ swin, const float* __restrict__ resnet,
    unsigned short* __restrict__ inThi, unsigned short* __restrict__ inTlo)
{
  __shared__ float t[64][65];
  const int b = blockIdx.z, ct = blockIdx.y, n0 = blockIdx.x*64;
  const float* src; int C, cs0;
  if (ct < 3){ src = swin;   C = 192; cs0 = ct*64; }
  else       { src = resnet; C = 128; cs0 = (ct-3)*64; }
  const int dst0 = ct*64;
  const int tid = threadIdx.x;
  #pragma unroll
  for (int it=0; it<16; ++it){
    int idx = it*256 + tid;
    int c = idx >> 6, n = idx & 63;
    t[c][n] = src[((long)b*C + cs0 + c)*NPIX + n0 + n];
  }
  __syncthreads();
  #pragma unroll
  for (int it=0; it<16; ++it){
    int idx = it*256 + tid;
    int n = idx >> 6, c = idx & 63;
    float v = t[c][n];
    unsigned short h = f2bf(v);
    long o = ((long)b*NPIX + n0 + n)*320 + dst0 + c;
    inThi[o] = h;
    inTlo[o] = f2bf(v - bf2f(h));
  }
}

// pT[n][c] = bf16(kl[c][n]*vl[c][n])
__global__ __launch_bounds__(256) void pT_kernel(
    const float* __restrict__ projL, unsigned short* __restrict__ pT)
{
  __shared__ float t[64][65];
  const int b = blockIdx.z, c0 = blockIdx.y*64, n0 = blockIdx.x*64;
  const float* kl = projL + (long)b*(640L*NPIX);
  const float* vl = kl + 320L*NPIX;
  const int tid = threadIdx.x;
  #pragma unroll
  for (int it=0; it<16; ++it){
    int idx = it*256 + tid;
    int c = idx >> 6, n = idx & 63;
    long s = (long)(c0+c)*NPIX + n0 + n;
    t[c][n] = kl[s]*vl[s];
  }
  __syncthreads();
  #pragma unroll
  for (int it=0; it<16; ++it){
    int idx = it*256 + tid;
    int n = idx >> 6, c = idx & 63;
    pT[((long)b*NPIX + n0 + n)*320 + c0 + c] = f2bf(t[c][n]);
  }
}

// W2h[b][o][c] = bf16(wc[o][c]*colsum[b][c])
__global__ void w2_kernel(const float* __restrict__ wc_w, const float* __restrict__ colsum,
    unsigned short* __restrict__ W2h)
{
  int idx = blockIdx.x*256 + threadIdx.x;
  if (idx >= B4*160*320) return;
  int b = idx / (160*320);
  int rem = idx - b*160*320;
  int c = rem % 320;
  W2h[idx] = f2bf(wc_w[rem]*colsum[b*320+c]);
}

// ---------------- fp64 rank-1 denominator path ----------------
__global__ __launch_bounds__(256) void chsum_kernel(
    const float* __restrict__ swin, const float* __restrict__ resnet,
    double* __restrict__ chsumd)
{
  int b = blockIdx.y, c = blockIdx.x;
  const float* row = (c < 192) ? swin + ((long)b*192 + c)*NPIX
                               : resnet + ((long)b*128 + (c-192))*NPIX;
  double s = 0.0;
  for (int n = threadIdx.x; n < NPIX; n += 256) s += (double)row[n];
  __shared__ double sd[256];
  sd[threadIdx.x] = s; __syncthreads();
  for (int o=128; o; o>>=1){ if (threadIdx.x < o) sd[threadIdx.x] += sd[threadIdx.x+o]; __syncthreads(); }
  if (threadIdx.x == 0) chsumd[b*320+c] = sd[0];
}

__global__ __launch_bounds__(320) void skda_kernel(
    const double* __restrict__ Wsw, const double* __restrict__ Wres,
    const double* __restrict__ bqk, const double* __restrict__ chsumd,
    double* __restrict__ wdad, double* __restrict__ cdad)
{
  int b = blockIdx.x;
  __shared__ double sk[40];
  int tid = threadIdx.x;
  if (tid < 40){
    int m = 40 + tid;   // k rows
    double s = 4096.0 * bqk[m];
    for (int j=0;j<192;j++) s += Wsw[m*192+j]*chsumd[b*320+j];
    for (int j=0;j<128;j++) s += Wres[m*128+j]*chsumd[b*320+192+j];
    sk[tid] = s + 1e-10;
  }
  __syncthreads();
  {
    int c = tid;
    double s = 0.0;
    if (c < 192){ for (int m=0;m<40;m++) s += sk[m]*Wsw[m*192+c]; }
    else        { for (int m=0;m<40;m++) s += sk[m]*Wres[m*128+(c-192)]; }
    wdad[b*320+c] = s;
  }
  if (tid == 0){
    double s = 0.0;
    for (int m=0;m<40;m++) s += sk[m]*bqk[m];
    cdad[b] = s;
  }
}

__global__ __launch_bounds__(256) void norm2_kernel(
    const float* __restrict__ swin, const float* __restrict__ resnet,
    const float* __restrict__ projL,
    const double* __restrict__ wdad, const double* __restrict__ cdad,
    const float* __restrict__ colsum,
    float* __restrict__ norm_a, float* __restrict__ norm_l)
{
  int b = blockIdx.y;
  int lane = threadIdx.x & 63;
  int g = threadIdx.x >> 6;
  int px = blockIdx.x*64 + lane;
  __shared__ float cs[320];
  for (int i=threadIdx.x; i<320; i+=256) cs[i] = colsum[b*320+i];
  __syncthreads();
  const float* kl = projL + (long)b*640*NPIX;
  double da = 0.0, dl = 0.0;
  for (int c=g; c<192; c+=4)
    da += wdad[b*320+c]*(double)swin[((long)b*192+c)*NPIX + px];
  for (int c=192+g; c<320; c+=4)
    da += wdad[b*320+c]*(double)resnet[((long)b*128+(c-192))*NPIX + px];
  for (int c=g; c<320; c+=4) dl += (double)kl[(long)c*NPIX + px]*(double)cs[c];
  __shared__ double redA[4][64], redL[4][64];
  redA[g][lane] = da; redL[g][lane] = dl;
  __syncthreads();
  if (g == 0){
    double a = redA[0][lane]+redA[1][lane]+redA[2][lane]+redA[3][lane] + cdad[b];
    double l = redL[0][lane]+redL[1][lane]+redL[2][lane]+redL[3][lane];
    norm_a[(long)b*NPIX+px] = (float)(1.0/a);
    norm_l[(long)b*NPIX+px] = (float)(1.0/(l + 1e-10));
  }
}

// ---------------- reductions ----------------
__global__ void colsum_kernel(const float* __restrict__ projL, const float* __restrict__ qsum,
    float* __restrict__ colsum)
{
  int b = blockIdx.y, c = blockIdx.x;
  const float* kl = projL + (long)b*640*NPIX + (long)c*NPIX;
  const float* qs = qsum + (long)b*NPIX;
  double s = 0.0;
  for (int n=threadIdx.x; n<NPIX; n+=256) s += (double)kl[n]*(double)qs[n];
  __shared__ double sd[256];
  sd[threadIdx.x] = s; __syncthreads();
  for (int o=128; o; o>>=1){ if (threadIdx.x < o) sd[threadIdx.x] += sd[threadIdx.x+o]; __syncthreads(); }
  if (threadIdx.x == 0) colsum[b*320+c] = (float)sd[0];
}

extern "C" void kernel_launch(void* const* d_in, const int* in_sizes, int n_in,
                              void* d_out, int out_size, void* d_ws, size_t ws_size,
                              hipStream_t stream)
{
  const float* swin   = (const float*)d_in[0];
  const float* resnet = (const float*)d_in[1];
  const float* w_swin = (const float*)d_in[2];
  const float* b_swin = (const float*)d_in[3];
  const float* w_res  = (const float*)d_in[4];
  const float* b_res  = (const float*)d_in[5];
  const float* aq_w = (const float*)d_in[6];
  const float* aq_b = (const float*)d_in[7];
  const float* ak_w = (const float*)d_in[8];
  const float* ak_b = (const float*)d_in[9];
  const float* av_w = (const float*)d_in[10];
  const float* av_b = (const float*)d_in[11];
  const float* ad1_w = (const float*)d_in[12];
  const float* ad1_b = (const float*)d_in[13];
  const float* ad3_w = (const float*)d_in[14];
  const float* ad3_b = (const float*)d_in[15];
  const float* ag    = (const float*)d_in[16];
  const float* lq_w = (const float*)d_in[17];
  const float* lq_b = (const float*)d_in[18];
  const float* lk_w = (const float*)d_in[19];
  const float* lk_b = (const float*)d_in[20];
  const float* lv_w = (const float*)d_in[21];
  const float* lv_b = (const float*)d_in[22];
  const float* ld1_w = (const float*)d_in[23];
  const float* ld1_b = (const float*)d_in[24];
  const float* ld3_w = (const float*)d_in[25];
  const float* ld3_b = (const float*)d_in[26];
  const float* lg    = (const float*)d_in[27];
  const float* wc_w = (const float*)d_in[28];
  const float* wc_b = (const float*)d_in[29];
  float* out = (float*)d_out;

  // ---- workspace carve ----
  char* p = (char*)d_ws;
  double* Wsw   = (double*)p; p += (size_t)80*192*8;
  double* Wres  = (double*)p; p += (size_t)80*128*8;
  double* bqk   = (double*)p; p += (size_t)80*8;
  double* chsumd= (double*)p; p += (size_t)B4*320*8;
  double* wdad  = (double*)p; p += (size_t)B4*320*8;
  double* cdad  = (double*)p; p += (size_t)B4*8;
  float* q8f    = (float*)p;  p += (size_t)B4*128*NPIX*4;
  float* proj1  = (float*)p;  p += (size_t)B4*320*NPIX*4;  // rows 0..159 vp, 160..319 outacc
  float* projL  = (float*)p;  p += (size_t)B4*640*NPIX*4;  // rows 0..319 kl, 320..639 vl
  float* qsum   = (float*)p;  p += (size_t)B4*NPIX*4;
  float* norm_a = (float*)p;  p += (size_t)B4*NPIX*4;
  float* norm_l = (float*)p;  p += (size_t)B4*NPIX*4;
  float* colsum = (float*)p;  p += (size_t)B4*320*4;
  float* kvp    = (float*)p;  p += (size_t)B4*40*160*4;
  float* Wbig1  = (float*)p;  p += (size_t)320*320*4;
  float* bias1  = (float*)p;  p += (size_t)320*4;
  float* Wmix   = (float*)p;  p += (size_t)2880*320*4;
  float* Wd3eff = (float*)p;  p += (size_t)160*2880*4;
  float* biasqk = (float*)p;  p += (size_t)128*4;
  p = (char*)(((uintptr_t)p + 255) & ~(uintptr_t)255);
  unsigned short* xTh  = (unsigned short*)p; p += (size_t)B4*NPIX*320*2;
  unsigned short* xTl  = (unsigned short*)p; p += (size_t)B4*NPIX*320*2;
  unsigned short* Wb1h = (unsigned short*)p; p += (size_t)320*320*2;
  unsigned short* Wb1l = (unsigned short*)p; p += (size_t)320*320*2;
  unsigned short* lqh  = (unsigned short*)p; p += (size_t)320*320*2;
  unsigned short* lkh  = (unsigned short*)p; p += (size_t)320*320*2;
  unsigned short* lvh  = (unsigned short*)p; p += (size_t)320*320*2;
  unsigned short* Wd3b = (unsigned short*)p; p += (size_t)192*2880*2;
  unsigned short* wswh = (unsigned short*)p; p += (size_t)192*192*2;
  unsigned short* wswl = (unsigned short*)p; p += (size_t)192*192*2;
  unsigned short* wrsh = (unsigned short*)p; p += (size_t)128*128*2;
  unsigned short* wrsl = (unsigned short*)p; p += (size_t)128*128*2;
  unsigned short* Wqkh = (unsigned short*)p; p += (size_t)128*320*2;
  unsigned short* Wqkl = (unsigned short*)p; p += (size_t)128*320*2;
  if ((size_t)(p - (char*)d_ws) > ws_size) return;

  // aliases over dead regions (stream-ordered safety):
  unsigned short* inThi = (unsigned short*)projL;          // dead once lk/lv write projL
  unsigned short* inTlo = inThi + (size_t)B4*NPIX*320;
  unsigned short* pT = xTl;                                // dead once proj1 split GEMM done
  unsigned short* W2h = (unsigned short*)Wmix;             // dead once Wd3eff composed

  hipMemsetAsync(qsum, 0, (size_t)B4*NPIX*4, stream);
  hipMemsetAsync(kvp,  0, (size_t)B4*40*160*4, stream);

  // ---- weight composition ----
  composeqk_kernel<<<(80*192 + 80*128 + 80 + 255)/256, 256, 0, stream>>>(
      aq_w, aq_b, ak_w, ak_b, w_swin, b_swin, w_res, b_res, Wsw, Wres, bqk);
  compose1_kernel<<<(320*320 + 255)/256, 256, 0, stream>>>(av_w, ad1_w, ld1_w, wc_w, ag, lg, Wbig1);
  bias1_kernel<<<5, 64, 0, stream>>>(av_b, ad1_b, ad3_b, ld1_b, ld3_b, wc_w, wc_b, ag, lg, bias1);
  t1_kernel<<<(2880*320 + 255)/256, 256, 0, stream>>>(ad3_w, ld3_w, ag, lg, Wmix);
  gemm_f32<<<dim3(5,3,9), 256, 0, stream>>>(wc_w, nullptr, Wmix, 320L*320, 320,
      Wd3eff, 320, 2880, 160, 320);

  // ---- weight bf16 conversions ----
  cvt_split_kernel<<<(320*320 + 255)/256, 256, 0, stream>>>(Wbig1, Wb1h, Wb1l, 320*320);
  cvt_bf16_kernel<<<(320*320 + 255)/256, 256, 0, stream>>>(lq_w, lqh, 320*320);
  cvt_bf16_kernel<<<(320*320 + 255)/256, 256, 0, stream>>>(lk_w, lkh, 320*320);
  cvt_bf16_kernel<<<(320*320 + 255)/256, 256, 0, stream>>>(lv_w, lvh, 320*320);
  cvt_pad_kernel<<<(192*2880 + 255)/256, 256, 0, stream>>>(Wd3eff, Wd3b);
  cvt_split_kernel<<<(192*192 + 255)/256, 256, 0, stream>>>(w_swin, wswh, wswl, 192*192);
  cvt_split_kernel<<<(128*128 + 255)/256, 256, 0, stream>>>(w_res, wrsh, wrsl, 128*128);
  cvtqk_kernel<<<(128*320 + 255)/256, 256, 0, stream>>>(Wsw, Wres, bqk, Wqkh, Wqkl, biasqk);

  // ---- fp64 rank-1 denominator composition ----
  chsum_kernel<<<dim3(320,4), 256, 0, stream>>>(swin, resnet, chsumd);
  skda_kernel<<<4, 320, 0, stream>>>(Wsw, Wres, bqk, chsumd, wdad, cdad);

  // ---- input transpose + x-build + q8/k8 via MFMA ----
  inT_kernel<<<dim3(64,5,4), 256, 0, stream>>>(swin, resnet, inThi, inTlo);
  xbuild_mfma<<<dim3(2,64,4), 256, 0, stream>>>(inThi, inTlo, 0, 192,
      wswh, wswl, b_swin, 192, 0, xTh, xTl);
  xbuild_mfma<<<dim3(1,64,4), 256, 0, stream>>>(inThi, inTlo, 192, 128,
      wrsh, wrsl, b_res, 128, 192, xTh, xTl);
  gemm_mfma<0,1><<<dim3(32,2,4), 256, 0, stream>>>(Wqkh, Wqkl, biasqk, inThi, inTlo,
      q8f, 128L*NPIX, nullptr);   // q8f rows 0..39 = q, 40..79 = k (before lk/lv overwrite inT)

  // ---- MFMA projections (proj1 last: frees xTl for pT alias) ----
  gemm_mfma<2,0><<<dim3(32,5,4), 256, 0, stream>>>(lqh, nullptr, lq_b, xTh, nullptr,
      nullptr, 0, qsum);
  gemm_mfma<1,0><<<dim3(32,5,4), 256, 0, stream>>>(lkh, nullptr, lk_b, xTh, nullptr,
      projL, 640L*NPIX, nullptr);
  gemm_mfma<0,0><<<dim3(32,5,4), 256, 0, stream>>>(lvh, nullptr, lv_b, xTh, nullptr,
      projL + 320L*NPIX, 640L*NPIX, nullptr);
  gemm_mfma<0,1><<<dim3(32,5,4), 256, 0, stream>>>(Wb1h, Wb1l, bias1, xTh, xTl,
      proj1, 320L*NPIX, nullptr);

  // ---- reductions ----
  kvp_mfma<<<dim3(2,32,4), 256, 0, stream>>>(proj1, q8f, kvp);
  colsum_kernel<<<dim3(320,4), 256, 0, stream>>>(projL, qsum, colsum);
  norm2_kernel<<<dim3(64,4), 256, 0, stream>>>(swin, resnet, projL, wdad, cdad, colsum,
                                               norm_a, norm_l);

  // ---- prep for final ----
  pT_kernel<<<dim3(64,5,4), 256, 0, stream>>>(projL, pT);
  w2_kernel<<<(B4*160*320 + 255)/256, 256, 0, stream>>>(wc_w, colsum, W2h);

  // ---- fused epilogue + composed conv ----
  final_mfma<<<dim3(32,3,4), 256, 0, stream>>>(W2h, pT, kvp, q8f, proj1,
                                               norm_a, norm_l, ag, lg, out);
  conv_mfma<<<dim3(32,3,4), 256, 0, stream>>>(Wd3b, xTh, out);
}

// Round 7
// 354.763 us; speedup vs baseline: 2.5115x; 1.0956x over previous
//
#include <hip/hip_runtime.h>
#include <stdint.h>

#define B4 4
#define NPIX 4096

typedef short sh8 __attribute__((ext_vector_type(8)));
typedef float f4 __attribute__((ext_vector_type(4)));

__device__ __forceinline__ float delu_f(float v){
  return v > 0.f ? __fmaf_rn(10.f, v, 1.f) : __expf(10.f*v);
}
__device__ __forceinline__ unsigned short f2bf(float f){
  unsigned u = __float_as_uint(f);
  u += 0x7fffu + ((u>>16)&1u);
  return (unsigned short)(u>>16);
}
__device__ __forceinline__ float bf2f(unsigned short h){
  return __uint_as_float(((unsigned)h)<<16);
}

// ---------------- generic 64x64x16 f32 tile GEMM (weight-compose only) ----------------
__global__ __launch_bounds__(256) void gemm_f32(
    const float* __restrict__ W, const float* __restrict__ bias,
    const float* __restrict__ X, long xStride, int ldX,
    float* __restrict__ Out, long outStride, int ldOut,
    int M, int K)
{
  __shared__ float Wt[16][64];
  __shared__ float Xt[16][64];
  const int b  = blockIdx.z;
  const int m0 = blockIdx.y * 64;
  const int n0 = blockIdx.x * 64;
  const int tid = threadIdx.x;
  const int tc = tid & 15, tr = tid >> 4;
  const int wm = tid >> 2, wk = (tid & 3) << 2;
  const int xk = tid >> 4, xn = (tid & 15) << 2;
  const float* Xb = X + (long)b * xStride;
  float acc[4][4] = {};

  for (int k0 = 0; k0 < K; k0 += 16) {
    float4 wv4;
    if (m0 + wm < M) wv4 = *reinterpret_cast<const float4*>(W + (long)(m0+wm)*K + k0 + wk);
    else wv4 = make_float4(0.f,0.f,0.f,0.f);
    Wt[wk+0][wm] = wv4.x; Wt[wk+1][wm] = wv4.y; Wt[wk+2][wm] = wv4.z; Wt[wk+3][wm] = wv4.w;
    *reinterpret_cast<float4*>(&Xt[xk][xn]) =
        *reinterpret_cast<const float4*>(Xb + (long)(k0+xk)*ldX + n0 + xn);
    __syncthreads();
    #pragma unroll
    for (int kk = 0; kk < 16; ++kk) {
      float4 a4 = *reinterpret_cast<const float4*>(&Wt[kk][tr<<2]);
      float4 b4 = *reinterpret_cast<const float4*>(&Xt[kk][tc<<2]);
      float av[4] = {a4.x,a4.y,a4.z,a4.w};
      float bv[4] = {b4.x,b4.y,b4.z,b4.w};
      #pragma unroll
      for (int i=0;i<4;i++)
        #pragma unroll
        for (int j=0;j<4;j++) acc[i][j] = __fmaf_rn(av[i], bv[j], acc[i][j]);
    }
    __syncthreads();
  }

  #pragma unroll
  for (int i=0;i<4;i++){
    int m = m0 + (tr<<2) + i;
    if (m < M) {
      float bv = bias ? bias[m] : 0.f;
      float r[4];
      #pragma unroll
      for (int j=0;j<4;j++) r[j] = acc[i][j] + bv;
      *reinterpret_cast<float4*>(Out + (long)b*outStride + (long)m*ldOut + n0 + (tc<<2)) =
          make_float4(r[0],r[1],r[2],r[3]);
    }
  }
}

// ---------------- bf16 MFMA GEMM: C[m][n] = sum_k W[m][k] * xT[n][k] ----------------
// EP: 0 = store acc+bias; 1 = delu(acc+bias); 2 = delu column-sum -> qsum
template<int EP, int SPLIT>
__global__ __launch_bounds__(256) void gemm_mfma(
    const unsigned short* __restrict__ Whi, const unsigned short* __restrict__ Wlo,
    const float* __restrict__ bias,
    const unsigned short* __restrict__ Xhi, const unsigned short* __restrict__ Xlo,
    float* __restrict__ Out, long outStride, float* __restrict__ qsum)
{
  __shared__ unsigned short Ah[64][40];
  __shared__ unsigned short Bh[128][40];
  __shared__ unsigned short Al[SPLIT?64:8][40];
  __shared__ unsigned short Bl[SPLIT?128:8][40];
  const int b  = blockIdx.z;
  const int m0 = blockIdx.y * 64;
  const int n0 = blockIdx.x * 128;
  const int tid = threadIdx.x;
  const int sRow = tid >> 2, sK = (tid & 3) << 3;
  const int lane = tid & 63, w = tid >> 6;
  const int wr = w >> 1, wc = w & 1;
  const int fr = lane & 15, fko = (lane >> 4) << 3;

  f4 z4 = {0.f,0.f,0.f,0.f};
  f4 acc[2][4];
  #pragma unroll
  for (int mf=0; mf<2; mf++)
    #pragma unroll
    for (int nf=0; nf<4; nf++) acc[mf][nf] = z4;

  for (int k0 = 0; k0 < 320; k0 += 32) {
    *reinterpret_cast<sh8*>(&Ah[sRow][sK]) =
        *reinterpret_cast<const sh8*>(Whi + (long)(m0+sRow)*320 + k0 + sK);
    if (SPLIT)
      *reinterpret_cast<sh8*>(&Al[sRow][sK]) =
          *reinterpret_cast<const sh8*>(Wlo + (long)(m0+sRow)*320 + k0 + sK);
    #pragma unroll
    for (int r=0; r<2; r++){
      int row = r*64 + sRow;
      long src = ((long)b*NPIX + n0 + row)*320 + k0 + sK;
      *reinterpret_cast<sh8*>(&Bh[row][sK]) = *reinterpret_cast<const sh8*>(Xhi + src);
      if (SPLIT)
        *reinterpret_cast<sh8*>(&Bl[row][sK]) = *reinterpret_cast<const sh8*>(Xlo + src);
    }
    __syncthreads();
    sh8 aH[2], bH[4];
    #pragma unroll
    for (int mf=0; mf<2; mf++)
      aH[mf] = *reinterpret_cast<const sh8*>(&Ah[wr*32 + mf*16 + fr][fko]);
    #pragma unroll
    for (int nf=0; nf<4; nf++)
      bH[nf] = *reinterpret_cast<const sh8*>(&Bh[wc*64 + nf*16 + fr][fko]);
    #pragma unroll
    for (int mf=0; mf<2; mf++)
      #pragma unroll
      for (int nf=0; nf<4; nf++)
        acc[mf][nf] = __builtin_amdgcn_mfma_f32_16x16x32_bf16(aH[mf], bH[nf], acc[mf][nf], 0,0,0);
    if (SPLIT){
      sh8 aL[2], bL[4];
      #pragma unroll
      for (int mf=0; mf<2; mf++)
        aL[mf] = *reinterpret_cast<const sh8*>(&Al[wr*32 + mf*16 + fr][fko]);
      #pragma unroll
      for (int nf=0; nf<4; nf++)
        bL[nf] = *reinterpret_cast<const sh8*>(&Bl[wc*64 + nf*16 + fr][fko]);
      #pragma unroll
      for (int mf=0; mf<2; mf++)
        #pragma unroll
        for (int nf=0; nf<4; nf++){
          acc[mf][nf] = __builtin_amdgcn_mfma_f32_16x16x32_bf16(aL[mf], bH[nf], acc[mf][nf], 0,0,0);
          acc[mf][nf] = __builtin_amdgcn_mfma_f32_16x16x32_bf16(aH[mf], bL[nf], acc[mf][nf], 0,0,0);
        }
    }
    __syncthreads();
  }

  const int orow0 = m0 + wr*32;
  const int ocol  = n0 + wc*64;
  if (EP == 2){
    #pragma unroll
    for (int nf=0; nf<4; nf++){
      float s = 0.f;
      #pragma unroll
      for (int mf=0; mf<2; mf++)
        #pragma unroll
        for (int r=0; r<4; r++)
          s += delu_f(acc[mf][nf][r] + bias[orow0 + mf*16 + ((lane>>4)<<2) + r]);
      s += __shfl_xor(s, 16, 64);
      s += __shfl_xor(s, 32, 64);
      if (lane < 16) atomicAdd(&qsum[(long)b*NPIX + ocol + nf*16 + fr], s);
    }
  } else {
    #pragma unroll
    for (int mf=0; mf<2; mf++)
      #pragma unroll
      for (int r=0; r<4; r++){
        int row = orow0 + mf*16 + ((lane>>4)<<2) + r;
        float bv = bias ? bias[row] : 0.f;
        #pragma unroll
        for (int nf=0; nf<4; nf++){
          float v = acc[mf][nf][r] + bv;
          if (EP == 1) v = delu_f(v);
          Out[(long)b*outStride + (long)row*NPIX + ocol + nf*16 + fr] = v;
        }
      }
  }
}

// ---------------- x-build MFMA: role-flipped (A = pixels, B = weight rows), 3-pass split ----------------
__global__ __launch_bounds__(256) void xbuild_mfma(
    const unsigned short* __restrict__ inThi, const unsigned short* __restrict__ inTlo,
    int cOff, int K,
    const unsigned short* __restrict__ Wh, const unsigned short* __restrict__ Wl,
    const float* __restrict__ bias, int outC, int tOff,
    unsigned short* __restrict__ xTh, unsigned short* __restrict__ xTl)
{
  __shared__ unsigned short Ah[64][40];
  __shared__ unsigned short Bh[128][40];
  __shared__ unsigned short Al[64][40];
  __shared__ unsigned short Bl[128][40];
  const int b  = blockIdx.z;
  const int m0 = blockIdx.y * 64;
  const int n0 = blockIdx.x * 128;
  const int tid = threadIdx.x;
  const int sRow = tid >> 2, sK = (tid & 3) << 3;
  const int lane = tid & 63, w = tid >> 6;
  const int wr = w >> 1, wc = w & 1;
  const int fr = lane & 15, fko = (lane >> 4) << 3;

  f4 z4 = {0.f,0.f,0.f,0.f};
  f4 acc[2][4];
  #pragma unroll
  for (int mf=0; mf<2; mf++)
    #pragma unroll
    for (int nf=0; nf<4; nf++) acc[mf][nf] = z4;

  for (int k0 = 0; k0 < K; k0 += 32) {
    long asrc = ((long)b*NPIX + m0 + sRow)*320 + cOff + k0 + sK;
    *reinterpret_cast<sh8*>(&Ah[sRow][sK]) = *reinterpret_cast<const sh8*>(inThi + asrc);
    *reinterpret_cast<sh8*>(&Al[sRow][sK]) = *reinterpret_cast<const sh8*>(inTlo + asrc);
    #pragma unroll
    for (int r=0; r<2; r++){
      int row = r*64 + sRow;
      sh8 vh = {0,0,0,0,0,0,0,0}, vl = {0,0,0,0,0,0,0,0};
      if (n0 + row < outC){
        vh = *reinterpret_cast<const sh8*>(Wh + (long)(n0+row)*K + k0 + sK);
        vl = *reinterpret_cast<const sh8*>(Wl + (long)(n0+row)*K + k0 + sK);
      }
      *reinterpret_cast<sh8*>(&Bh[row][sK]) = vh;
      *reinterpret_cast<sh8*>(&Bl[row][sK]) = vl;
    }
    __syncthreads();
    sh8 aH[2], aL[2], bH[4], bL[4];
    #pragma unroll
    for (int mf=0; mf<2; mf++){
      aH[mf] = *reinterpret_cast<const sh8*>(&Ah[wr*32 + mf*16 + fr][fko]);
      aL[mf] = *reinterpret_cast<const sh8*>(&Al[wr*32 + mf*16 + fr][fko]);
    }
    #pragma unroll
    for (int nf=0; nf<4; nf++){
      bH[nf] = *reinterpret_cast<const sh8*>(&Bh[wc*64 + nf*16 + fr][fko]);
      bL[nf] = *reinterpret_cast<const sh8*>(&Bl[wc*64 + nf*16 + fr][fko]);
    }
    #pragma unroll
    for (int mf=0; mf<2; mf++)
      #pragma unroll
      for (int nf=0; nf<4; nf++){
        acc[mf][nf] = __builtin_amdgcn_mfma_f32_16x16x32_bf16(aH[mf], bH[nf], acc[mf][nf], 0,0,0);
        acc[mf][nf] = __builtin_amdgcn_mfma_f32_16x16x32_bf16(aH[mf], bL[nf], acc[mf][nf], 0,0,0);
        acc[mf][nf] = __builtin_amdgcn_mfma_f32_16x16x32_bf16(aL[mf], bH[nf], acc[mf][nf], 0,0,0);
      }
    __syncthreads();
  }

  const int opix0 = m0 + wr*32;
  const int ocol  = n0 + wc*64;
  #pragma unroll
  for (int mf=0; mf<2; mf++)
    #pragma unroll
    for (int r=0; r<4; r++){
      int pix = opix0 + mf*16 + ((lane>>4)<<2) + r;
      #pragma unroll
      for (int nf=0; nf<4; nf++){
        int col = ocol + nf*16 + fr;
        if (col < outC){
          float v = acc[mf][nf][r] + bias[col];
          unsigned short h = f2bf(v);
          long o = ((long)b*NPIX + pix)*320 + tOff + col;
          xTh[o] = h;
          xTl[o] = f2bf(v - bf2f(h));
        }
      }
    }
}

// ---------------- kvp via MFMA, K-split: kvp[b][m][o] = sum_n k8[m][n]*vp[o][n] ----------------
__global__ __launch_bounds__(256) void kvp_mfma(
    const float* __restrict__ proj1, const float* __restrict__ q8f,
    float* __restrict__ kvp)
{
  __shared__ unsigned short Ah[64][40];
  __shared__ unsigned short Bh[128][40];
  __shared__ unsigned short Al[64][40];
  __shared__ unsigned short Bl[128][40];
  const int b = blockIdx.z;
  const int o0 = blockIdx.x * 128;
  const int kbase = blockIdx.y * 128;
  const int tid = threadIdx.x;
  const int sRow = tid >> 2, sK = (tid & 3) << 3;
  const int lane = tid & 63, w = tid >> 6;
  const int wr = w >> 1, wc = w & 1;
  const int fr = lane & 15, fko = (lane >> 4) << 3;
  const float* k8 = q8f + ((long)b*128 + 40)*NPIX;
  const float* vp = proj1 + (long)b*(320L*NPIX);

  f4 z4 = {0.f,0.f,0.f,0.f};
  f4 acc[2][4];
  #pragma unroll
  for (int mf=0; mf<2; mf++)
    #pragma unroll
    for (int nf=0; nf<4; nf++) acc[mf][nf] = z4;

  for (int k0 = 0; k0 < 128; k0 += 32) {
    {
      float vv[8] = {0,0,0,0,0,0,0,0};
      if (sRow < 40){
        float4 a4 = *reinterpret_cast<const float4*>(k8 + (long)sRow*NPIX + kbase + k0 + sK);
        float4 b4 = *reinterpret_cast<const float4*>(k8 + (long)sRow*NPIX + kbase + k0 + sK + 4);
        vv[0]=a4.x; vv[1]=a4.y; vv[2]=a4.z; vv[3]=a4.w;
        vv[4]=b4.x; vv[5]=b4.y; vv[6]=b4.z; vv[7]=b4.w;
      }
      #pragma unroll
      for (int i=0;i<8;i++){
        unsigned short h = f2bf(vv[i]);
        Ah[sRow][sK+i] = h;
        Al[sRow][sK+i] = f2bf(vv[i] - bf2f(h));
      }
    }
    #pragma unroll
    for (int r=0;r<2;r++){
      int row = r*64 + sRow;
      int o = o0 + row;
      float vv[8] = {0,0,0,0,0,0,0,0};
      if (o < 160){
        float4 v4a = *reinterpret_cast<const float4*>(vp + (long)o*NPIX + kbase + k0 + sK);
        float4 v4b = *reinterpret_cast<const float4*>(vp + (long)o*NPIX + kbase + k0 + sK + 4);
        vv[0]=v4a.x; vv[1]=v4a.y; vv[2]=v4a.z; vv[3]=v4a.w;
        vv[4]=v4b.x; vv[5]=v4b.y; vv[6]=v4b.z; vv[7]=v4b.w;
      }
      #pragma unroll
      for (int i=0;i<8;i++){
        unsigned short h = f2bf(vv[i]);
        Bh[row][sK+i] = h;
        Bl[row][sK+i] = f2bf(vv[i] - bf2f(h));
      }
    }
    __syncthreads();
    sh8 aH[2], aL[2], bH[4], bL[4];
    #pragma unroll
    for (int mf=0; mf<2; mf++){
      aH[mf] = *reinterpret_cast<const sh8*>(&Ah[wr*32 + mf*16 + fr][fko]);
      aL[mf] = *reinterpret_cast<const sh8*>(&Al[wr*32 + mf*16 + fr][fko]);
    }
    #pragma unroll
    for (int nf=0; nf<4; nf++){
      bH[nf] = *reinterpret_cast<const sh8*>(&Bh[wc*64 + nf*16 + fr][fko]);
      bL[nf] = *reinterpret_cast<const sh8*>(&Bl[wc*64 + nf*16 + fr][fko]);
    }
    #pragma unroll
    for (int mf=0; mf<2; mf++)
      #pragma unroll
      for (int nf=0; nf<4; nf++){
        acc[mf][nf] = __builtin_amdgcn_mfma_f32_16x16x32_bf16(aH[mf], bH[nf], acc[mf][nf], 0,0,0);
        acc[mf][nf] = __builtin_amdgcn_mfma_f32_16x16x32_bf16(aH[mf], bL[nf], acc[mf][nf], 0,0,0);
        acc[mf][nf] = __builtin_amdgcn_mfma_f32_16x16x32_bf16(aL[mf], bH[nf], acc[mf][nf], 0,0,0);
      }
    __syncthreads();
  }

  const int orow0 = wr*32;
  const int ocol  = o0 + wc*64;
  #pragma unroll
  for (int mf=0; mf<2; mf++)
    #pragma unroll
    for (int r=0; r<4; r++){
      int row = orow0 + mf*16 + ((lane>>4)<<2) + r;
      if (row < 40){
        #pragma unroll
        for (int nf=0; nf<4; nf++){
          int col = ocol + nf*16 + fr;
          if (col < 160)
            atomicAdd(&kvp[((long)b*40 + row)*160 + col], acc[mf][nf][r]);
        }
      }
    }
}

// ---------------- final MFMA: out = outacc + cL*norm_l*(W2@pT) + cA*norm_a*(kvpT@q8) ----------------
__global__ __launch_bounds__(256) void final_mfma(
    const unsigned short* __restrict__ W2h,
    const unsigned short* __restrict__ pT,
    const float* __restrict__ kvp,
    const float* __restrict__ q8f,
    const float* __restrict__ proj1,
    const float* __restrict__ norm_a, const float* __restrict__ norm_l,
    const float* __restrict__ ag, const float* __restrict__ lg,
    float* __restrict__ Out)
{
  __shared__ unsigned short Ah[64][40];
  __shared__ unsigned short Bh[128][40];
  __shared__ unsigned short Al[64][40];
  __shared__ unsigned short Bl[128][40];
  const int b  = blockIdx.z;
  const int m0 = blockIdx.y * 64;
  const int n0 = blockIdx.x * 128;
  const int tid = threadIdx.x;
  const int sRow = tid >> 2, sK = (tid & 3) << 3;
  const int lane = tid & 63, w = tid >> 6;
  const int wr = w >> 1, wc = w & 1;
  const int fr = lane & 15, fko = (lane >> 4) << 3;

  f4 z4 = {0.f,0.f,0.f,0.f};
  f4 acc1[2][4], acc2[2][4];
  #pragma unroll
  for (int mf=0; mf<2; mf++)
    #pragma unroll
    for (int nf=0; nf<4; nf++){ acc1[mf][nf] = z4; acc2[mf][nf] = z4; }

  for (int k0 = 0; k0 < 320; k0 += 32) {
    sh8 av = {0,0,0,0,0,0,0,0};
    if (m0 + sRow < 160)
      av = *reinterpret_cast<const sh8*>(W2h + ((long)b*160 + m0 + sRow)*320 + k0 + sK);
    *reinterpret_cast<sh8*>(&Ah[sRow][sK]) = av;
    #pragma unroll
    for (int r=0; r<2; r++){
      int row = r*64 + sRow;
      *reinterpret_cast<sh8*>(&Bh[row][sK]) =
          *reinterpret_cast<const sh8*>(pT + ((long)b*NPIX + n0 + row)*320 + k0 + sK);
    }
    __syncthreads();
    sh8 aH[2], bH[4];
    #pragma unroll
    for (int mf=0; mf<2; mf++)
      aH[mf] = *reinterpret_cast<const sh8*>(&Ah[wr*32 + mf*16 + fr][fko]);
    #pragma unroll
    for (int nf=0; nf<4; nf++)
      bH[nf] = *reinterpret_cast<const sh8*>(&Bh[wc*64 + nf*16 + fr][fko]);
    #pragma unroll
    for (int mf=0; mf<2; mf++)
      #pragma unroll
      for (int nf=0; nf<4; nf++)
        acc1[mf][nf] = __builtin_amdgcn_mfma_f32_16x16x32_bf16(aH[mf], bH[nf], acc1[mf][nf], 0,0,0);
    __syncthreads();
  }

  for (int k0 = 0; k0 < 64; k0 += 32) {
    {
      int m = m0 + sRow;
      #pragma unroll
      for (int i=0;i<8;i++){
        int kk = k0 + sK + i;
        float v = (kk < 40 && m < 160) ? kvp[((long)b*40 + kk)*160 + m] : 0.f;
        unsigned short h = f2bf(v);
        Ah[sRow][sK+i] = h;
        Al[sRow][sK+i] = f2bf(v - bf2f(h));
      }
    }
    #pragma unroll
    for (int r=0; r<2; r++){
      int row = r*64 + sRow;
      int pix = n0 + row;
      #pragma unroll
      for (int i=0;i<8;i++){
        int kk = k0 + sK + i;
        float v = (kk < 40) ? q8f[((long)b*128 + kk)*NPIX + pix] : 0.f;
        unsigned short h = f2bf(v);
        Bh[row][sK+i] = h;
        Bl[row][sK+i] = f2bf(v - bf2f(h));
      }
    }
    __syncthreads();
    sh8 aH[2], aL[2], bH[4], bL[4];
    #pragma unroll
    for (int mf=0; mf<2; mf++){
      aH[mf] = *reinterpret_cast<const sh8*>(&Ah[wr*32 + mf*16 + fr][fko]);
      aL[mf] = *reinterpret_cast<const sh8*>(&Al[wr*32 + mf*16 + fr][fko]);
    }
    #pragma unroll
    for (int nf=0; nf<4; nf++){
      bH[nf] = *reinterpret_cast<const sh8*>(&Bh[wc*64 + nf*16 + fr][fko]);
      bL[nf] = *reinterpret_cast<const sh8*>(&Bl[wc*64 + nf*16 + fr][fko]);
    }
    #pragma unroll
    for (int mf=0; mf<2; mf++)
      #pragma unroll
      for (int nf=0; nf<4; nf++){
        acc2[mf][nf] = __builtin_amdgcn_mfma_f32_16x16x32_bf16(aH[mf], bH[nf], acc2[mf][nf], 0,0,0);
        acc2[mf][nf] = __builtin_amdgcn_mfma_f32_16x16x32_bf16(aH[mf], bL[nf], acc2[mf][nf], 0,0,0);
        acc2[mf][nf] = __builtin_amdgcn_mfma_f32_16x16x32_bf16(aL[mf], bH[nf], acc2[mf][nf], 0,0,0);
      }
    __syncthreads();
  }

  const float cA = 0.7f*ag[0], cL = 0.3f*lg[0];
  const int orow0 = m0 + wr*32;
  const int ocol  = n0 + wc*64;
  #pragma unroll
  for (int mf=0; mf<2; mf++)
    #pragma unroll
    for (int r=0; r<4; r++){
      int row = orow0 + mf*16 + ((lane>>4)<<2) + r;
      if (row < 160){
        const float* oa = proj1 + (long)b*(320L*NPIX) + (long)(160+row)*NPIX;
        #pragma unroll
        for (int nf=0; nf<4; nf++){
          int col = ocol + nf*16 + fr;
          Out[((long)b*160 + row)*NPIX + col] =
              oa[col] + cL*norm_l[(long)b*NPIX+col]*acc1[mf][nf][r]
                      + cA*norm_a[(long)b*NPIX+col]*acc2[mf][nf][r];
        }
      }
    }
}

// ---------------- composed 3x3 conv via MFMA, halo-staged ----------------
__global__ __launch_bounds__(256) void conv_mfma(
    const unsigned short* __restrict__ Wd3,
    const unsigned short* __restrict__ Xhi,
    float* __restrict__ Out)
{
  __shared__ unsigned short Ah[64][296];
  __shared__ unsigned short Bs[4*66*40];
  const int b  = blockIdx.z;
  const int m0 = blockIdx.y * 64;
  const int n0 = blockIdx.x * 128;
  const int h0 = n0 >> 6;
  const int tid = threadIdx.x;
  const int lane = tid & 63, w = tid >> 6;
  const int wr = w >> 1, wc = w & 1;
  const int fr = lane & 15, fko = (lane >> 4) << 3;

  f4 z4 = {0.f,0.f,0.f,0.f};
  f4 acc[2][4];
  #pragma unroll
  for (int mf=0; mf<2; mf++)
    #pragma unroll
    for (int nf=0; nf<4; nf++) acc[mf][nf] = z4;

  const int sr = tid >> 6;
  const int sw = tid & 63;
  const int hp = h0 - 1 + sr;
  const bool rowok = (hp >= 0) && (hp < 64);
  if (tid < 32){
    int r = tid >> 3;
    int ws = (tid & 4) ? 65 : 0;
    int j = tid & 3;
    sh8 z = {0,0,0,0,0,0,0,0};
    *reinterpret_cast<sh8*>(&Bs[(r*66 + ws)*40 + j*8]) = z;
  }

  const int arow = tid >> 2;
  const int acc8 = (tid & 3) << 3;

  for (int c0 = 0; c0 < 320; c0 += 32){
    #pragma unroll
    for (int t=0; t<9; t++)
      *reinterpret_cast<sh8*>(&Ah[arow][t*32 + acc8]) =
          *reinterpret_cast<const sh8*>(Wd3 + (long)(m0+arow)*2880 + t*320 + c0 + acc8);
    {
      const unsigned short* src = Xhi + ((long)b*NPIX + hp*64 + sw)*320 + c0;
      unsigned short* dst = &Bs[(sr*66 + sw + 1)*40];
      sh8 z = {0,0,0,0,0,0,0,0};
      #pragma unroll
      for (int j=0;j<4;j++){
        sh8 v = z;
        if (rowok) v = *reinterpret_cast<const sh8*>(src + j*8);
        *reinterpret_cast<sh8*>(dst + j*8) = v;
      }
    }
    __syncthreads();
    #pragma unroll
    for (int t=0; t<9; t++){
      const int dh = t/3 - 1, dw = t%3 - 1;
      sh8 aH[2], bH[4];
      #pragma unroll
      for (int mf=0; mf<2; mf++)
        aH[mf] = *reinterpret_cast<const sh8*>(&Ah[wr*32 + mf*16 + fr][t*32 + fko]);
      #pragma unroll
      for (int nf=0; nf<4; nf++){
        int np = wc*64 + nf*16 + fr;
        int lr = (np >> 6) + dh + 1;
        int lw = (np & 63) + dw + 1;
        bH[nf] = *reinterpret_cast<const sh8*>(&Bs[(lr*66 + lw)*40 + fko]);
      }
      #pragma unroll
      for (int mf=0; mf<2; mf++)
        #pragma unroll
        for (int nf=0; nf<4; nf++)
          acc[mf][nf] = __builtin_amdgcn_mfma_f32_16x16x32_bf16(aH[mf], bH[nf], acc[mf][nf], 0,0,0);
    }
    __syncthreads();
  }

  const int orow0 = m0 + wr*32;
  const int ocol  = n0 + wc*64;
  #pragma unroll
  for (int mf=0; mf<2; mf++)
    #pragma unroll
    for (int r=0; r<4; r++){
      int row = orow0 + mf*16 + ((lane>>4)<<2) + r;
      if (row < 160){
        #pragma unroll
        for (int nf=0; nf<4; nf++){
          long o = ((long)b*160 + row)*NPIX + ocol + nf*16 + fr;
          Out[o] += acc[mf][nf][r];
        }
      }
    }
}

// ---------------- weight composition kernels ----------------
__global__ void compose1_kernel(const float* __restrict__ av_w, const float* __restrict__ ad1_w,
    const float* __restrict__ ld1_w, const float* __restrict__ wc_w,
    const float* __restrict__ ag, const float* __restrict__ lg, float* __restrict__ Wbig1)
{
  int idx = blockIdx.x*256 + threadIdx.x;
  if (idx >= 320*320) return;
  int r = idx / 320, c = idx % 320;
  float cD = 1.4f*ag[0], cL = 0.3f*lg[0];
  if (r < 160) {
    float s = 0.f;
    for (int j=0;j<320;j++) s += wc_w[r*320+j]*av_w[j*320+c];
    Wbig1[idx] = s;
  } else {
    int o = r - 160;
    float s1 = 0.f, s2 = 0.f;
    for (int j=0;j<320;j++){
      float w = wc_w[o*320+j];
      s1 += w*ad1_w[j*320+c];
      s2 += w*ld1_w[j*320+c];
    }
    Wbig1[idx] = 2.f*wc_w[o*320+c] + cD*s1 + cL*s2;
  }
}

__global__ void bias1_kernel(const float* __restrict__ av_b, const float* __restrict__ ad1_b,
    const float* __restrict__ ad3_b, const float* __restrict__ ld1_b, const float* __restrict__ ld3_b,
    const float* __restrict__ wc_w, const float* __restrict__ wc_b,
    const float* __restrict__ ag, const float* __restrict__ lg, float* __restrict__ bias1)
{
  int r = blockIdx.x*64 + threadIdx.x;
  if (r >= 320) return;
  float cD = 1.4f*ag[0], cL = 0.3f*lg[0];
  if (r < 160){
    float s = 0.f;
    for (int j=0;j<320;j++) s += wc_w[r*320+j]*av_b[j];
    bias1[r] = s;
  } else {
    int o = r - 160;
    float s = wc_b[o];
    for (int j=0;j<320;j++){
      float w = wc_w[o*320+j];
      s += cD*w*(ad1_b[j]+ad3_b[j]) + cL*w*(ld1_b[j]+ld3_b[j]);
    }
    bias1[r] = s;
  }
}

__global__ void composeqk_kernel(const float* __restrict__ aq_w, const float* __restrict__ aq_b,
    const float* __restrict__ ak_w, const float* __restrict__ ak_b,
    const float* __restrict__ w_swin, const float* __restrict__ b_swin,
    const float* __restrict__ w_res, const float* __restrict__ b_res,
    double* __restrict__ Wsw, double* __restrict__ Wres, double* __restrict__ bqk)
{
  int idx = blockIdx.x*256 + threadIdx.x;
  if (idx < 80*192){
    int m = idx/192, j = idx%192;
    const float* aw = (m < 40) ? aq_w + m*320 : ak_w + (m-40)*320;
    double s = 0.0;
    for (int i=0;i<192;i++) s += (double)aw[i]*(double)w_swin[i*192+j];
    Wsw[idx] = s;
  }
  int idx2 = idx - 80*192;
  if (idx2 >= 0 && idx2 < 80*128){
    int m = idx2/128, j = idx2%128;
    const float* aw = (m < 40) ? aq_w + m*320 + 192 : ak_w + (m-40)*320 + 192;
    double s = 0.0;
    for (int i=0;i<128;i++) s += (double)aw[i]*(double)w_res[i*128+j];
    Wres[idx2] = s;
  }
  int idx3 = idx - 80*192 - 80*128;
  if (idx3 >= 0 && idx3 < 80){
    int m = idx3;
    const float* aw = (m < 40) ? aq_w + m*320 : ak_w + (m-40)*320;
    double s = (double)((m < 40) ? aq_b[m] : ak_b[m-40]);
    for (int i=0;i<192;i++) s += (double)aw[i]*(double)b_swin[i];
    for (int i=0;i<128;i++) s += (double)aw[192+i]*(double)b_res[i];
    bqk[m] = s;
  }
}

__global__ void t1_kernel(const float* __restrict__ ad3_w, const float* __restrict__ ld3_w,
    const float* __restrict__ ag, const float* __restrict__ lg, float* __restrict__ Wmix)
{
  long idx = (long)blockIdx.x*256 + threadIdx.x;
  if (idx >= 2880L*320) return;
  int k = (int)(idx / 320), c = (int)(idx % 320);
  int t = k / 320, j = k % 320;
  float cD = 1.4f*ag[0], cL = 0.3f*lg[0];
  long src = (long)(j*320 + c)*9 + t;
  Wmix[idx] = cD*ad3_w[src] + cL*ld3_w[src];
}

// padded composed qk weight [128][320] bf16 hi/lo + fp32 bias[128]
__global__ void cvtqk_kernel(const double* __restrict__ Wsw, const double* __restrict__ Wres,
    const double* __restrict__ bqk,
    unsigned short* __restrict__ Wqkh, unsigned short* __restrict__ Wqkl,
    float* __restrict__ biasqk)
{
  int idx = blockIdx.x*256 + threadIdx.x;
  if (idx < 128*320){
    int row = idx / 320, col = idx % 320;
    double v = 0.0;
    if (row < 80) v = (col < 192) ? Wsw[row*192+col] : Wres[row*128+(col-192)];
    float f = (float)v;
    unsigned short h = f2bf(f);
    Wqkh[idx] = h;
    Wqkl[idx] = f2bf(f - bf2f(h));
  }
  if (idx < 128) biasqk[idx] = (idx < 80) ? (float)bqk[idx] : 0.f;
}

// ---------------- conversions ----------------
__global__ void cvt_bf16_kernel(const float* __restrict__ src, unsigned short* __restrict__ dst, int n){
  int i = blockIdx.x*256 + threadIdx.x;
  if (i < n) dst[i] = f2bf(src[i]);
}
__global__ void cvt_split_kernel(const float* __restrict__ src,
    unsigned short* __restrict__ hi, unsigned short* __restrict__ lo, int n){
  int i = blockIdx.x*256 + threadIdx.x;
  if (i < n){
    float v = src[i];
    unsigned short h = f2bf(v);
    hi[i] = h;
    lo[i] = f2bf(v - bf2f(h));
  }
}
__global__ void cvt_pad_kernel(const float* __restrict__ src, unsigned short* __restrict__ dst){
  int i = blockIdx.x*256 + threadIdx.x;
  if (i >= 192*2880) return;
  int row = i / 2880;
  dst[i] = (row < 160) ? f2bf(src[i]) : (unsigned short)0;
}

// inT: transpose raw inputs to [B][4096][320] bf16 hi/lo + fused fp64 da partial (wda . in)
__global__ __launch_bounds__(256) void inT_kernel(
    const float* __restrict__ swin, const float* __restrict__ resnet,
    const double* __restrict__ wdad, double* __restrict__ dabuf,
    unsigned short* __restrict__ inThi, unsigned short* __restrict__ inTlo)
{
  __shared__ float t[64][65];
  __shared__ double redD[4][64];
  const int b = blockIdx.z, ct = blockIdx.y, n0 = blockIdx.x*64;
  const float* src; int C, cs0;
  if (ct < 3){ src = swin;   C = 192; cs0 = ct*64; }
  else       { src = resnet; C = 128; cs0 = (ct-3)*64; }
  const int dst0 = ct*64;
  const int tid = threadIdx.x;
  #pragma unroll
  for (int it=0; it<16; ++it){
    int idx = it*256 + tid;
    int c = idx >> 6, n = idx & 63;
    t[c][n] = src[((long)b*C + cs0 + c)*NPIX + n0 + n];
  }
  __syncthreads();
  // fused da partial (fp64): sum over this block's 64 channels
  {
    int cg = tid >> 6, n = tid & 63;
    double s = 0.0;
    #pragma unroll
    for (int j=0;j<16;j++){
      int c = cg*16 + j;
      s += wdad[b*320 + dst0 + c] * (double)t[c][n];
    }
    redD[cg][n] = s;
  }
  __syncthreads();
  if (tid < 64){
    double s = redD[0][tid]+redD[1][tid]+redD[2][tid]+redD[3][tid];
    atomicAdd(&dabuf[(long)b*NPIX + n0 + tid], s);
  }
  #pragma unroll
  for (int it=0; it<16; ++it){
    int idx = it*256 + tid;
    int n = idx >> 6, c = idx & 63;
    float v = t[c][n];
    unsigned short h = f2bf(v);
    long o = ((long)b*NPIX + n0 + n)*320 + dst0 + c;
    inThi[o] = h;
    inTlo[o] = f2bf(v - bf2f(h));
  }
}

// pT[n][c] = bf16(kl[c][n]*vl[c][n]) + fused fp32 dl partial (cs . kl)
__global__ __launch_bounds__(256) void pT_kernel(
    const float* __restrict__ projL, const float* __restrict__ colsum,
    unsigned short* __restrict__ pT, float* __restrict__ dlbuf)
{
  __shared__ float t[64][65];
  __shared__ float css[64];
  __shared__ float redF[4][64];
  const int b = blockIdx.z, c0 = blockIdx.y*64, n0 = blockIdx.x*64;
  const float* kl = projL + (long)b*(640L*NPIX);
  const float* vl = kl + 320L*NPIX;
  const int tid = threadIdx.x;
  if (tid < 64) css[tid] = colsum[b*320 + c0 + tid];
  __syncthreads();
  float sdl = 0.f;
  #pragma unroll
  for (int it=0; it<16; ++it){
    int idx = it*256 + tid;
    int c = idx >> 6, n = idx & 63;
    long s = (long)(c0+c)*NPIX + n0 + n;
    float klv = kl[s];
    t[c][n] = klv*vl[s];
    sdl = __fmaf_rn(css[c], klv, sdl);
  }
  redF[tid>>6][tid&63] = sdl;
  __syncthreads();
  if (tid < 64)
    atomicAdd(&dlbuf[(long)b*NPIX + n0 + tid],
              redF[0][tid]+redF[1][tid]+redF[2][tid]+redF[3][tid]);
  #pragma unroll
  for (int it=0; it<16; ++it){
    int idx = it*256 + tid;
    int n = idx >> 6, c = idx & 63;
    pT[((long)b*NPIX + n0 + n)*320 + c0 + c] = f2bf(t[c][n]);
  }
}

// norm finisher: norm_a = 1/(da + cda), norm_l = 1/(dl + eps)
__global__ void normfin_kernel(const double* __restrict__ dabuf, const double* __restrict__ cdad,
    const float* __restrict__ dlbuf, float* __restrict__ norm_a, float* __restrict__ norm_l)
{
  int i = blockIdx.x*256 + threadIdx.x;
  if (i >= B4*NPIX) return;
  int b = i >> 12;
  norm_a[i] = (float)(1.0/(dabuf[i] + cdad[b]));
  norm_l[i] = 1.f/(dlbuf[i] + 1e-10f);
}

// W2h[b][o][c] = bf16(wc[o][c]*colsum[b][c])
__global__ void w2_kernel(const float* __restrict__ wc_w, const float* __restrict__ colsum,
    unsigned short* __restrict__ W2h)
{
  int idx = blockIdx.x*256 + threadIdx.x;
  if (idx >= B4*160*320) return;
  int b = idx / (160*320);
  int rem = idx - b*160*320;
  int c = rem % 320;
  W2h[idx] = f2bf(wc_w[rem]*colsum[b*320+c]);
}

// ---------------- fp64 rank-1 denominator path ----------------
__global__ __launch_bounds__(256) void chsum_kernel(
    const float* __restrict__ swin, const float* __restrict__ resnet,
    double* __restrict__ chsumd)
{
  int b = blockIdx.y, c = blockIdx.x;
  const float* row = (c < 192) ? swin + ((long)b*192 + c)*NPIX
                               : resnet + ((long)b*128 + (c-192))*NPIX;
  double s = 0.0;
  for (int n = threadIdx.x; n < NPIX; n += 256) s += (double)row[n];
  __shared__ double sd[256];
  sd[threadIdx.x] = s; __syncthreads();
  for (int o=128; o; o>>=1){ if (threadIdx.x < o) sd[threadIdx.x] += sd[threadIdx.x+o]; __syncthreads(); }
  if (threadIdx.x == 0) chsumd[b*320+c] = sd[0];
}

__global__ __launch_bounds__(320) void skda_kernel(
    const double* __restrict__ Wsw, const double* __restrict__ Wres,
    const double* __restrict__ bqk, const double* __restrict__ chsumd,
    double* __restrict__ wdad, double* __restrict__ cdad)
{
  int b = blockIdx.x;
  __shared__ double sk[40];
  int tid = threadIdx.x;
  if (tid < 40){
    int m = 40 + tid;   // k rows
    double s = 4096.0 * bqk[m];
    for (int j=0;j<192;j++) s += Wsw[m*192+j]*chsumd[b*320+j];
    for (int j=0;j<128;j++) s += Wres[m*128+j]*chsumd[b*320+192+j];
    sk[tid] = s + 1e-10;
  }
  __syncthreads();
  {
    int c = tid;
    double s = 0.0;
    if (c < 192){ for (int m=0;m<40;m++) s += sk[m]*Wsw[m*192+c]; }
    else        { for (int m=0;m<40;m++) s += sk[m]*Wres[m*128+(c-192)]; }
    wdad[b*320+c] = s;
  }
  if (tid == 0){
    double s = 0.0;
    for (int m=0;m<40;m++) s += sk[m]*bqk[m];
    cdad[b] = s;
  }
}

// ---------------- reductions ----------------
__global__ void colsum_kernel(const float* __restrict__ projL, const float* __restrict__ qsum,
    float* __restrict__ colsum)
{
  int b = blockIdx.y, c = blockIdx.x;
  const float* kl = projL + (long)b*640*NPIX + (long)c*NPIX;
  const float* qs = qsum + (long)b*NPIX;
  double s = 0.0;
  for (int n=threadIdx.x; n<NPIX; n+=256) s += (double)kl[n]*(double)qs[n];
  __shared__ double sd[256];
  sd[threadIdx.x] = s; __syncthreads();
  for (int o=128; o; o>>=1){ if (threadIdx.x < o) sd[threadIdx.x] += sd[threadIdx.x+o]; __syncthreads(); }
  if (threadIdx.x == 0) colsum[b*320+c] = (float)sd[0];
}

extern "C" void kernel_launch(void* const* d_in, const int* in_sizes, int n_in,
                              void* d_out, int out_size, void* d_ws, size_t ws_size,
                              hipStream_t stream)
{
  const float* swin   = (const float*)d_in[0];
  const float* resnet = (const float*)d_in[1];
  const float* w_swin = (const float*)d_in[2];
  const float* b_swin = (const float*)d_in[3];
  const float* w_res  = (const float*)d_in[4];
  const float* b_res  = (const float*)d_in[5];
  const float* aq_w = (const float*)d_in[6];
  const float* aq_b = (const float*)d_in[7];
  const float* ak_w = (const float*)d_in[8];
  const float* ak_b = (const float*)d_in[9];
  const float* av_w = (const float*)d_in[10];
  const float* av_b = (const float*)d_in[11];
  const float* ad1_w = (const float*)d_in[12];
  const float* ad1_b = (const float*)d_in[13];
  const float* ad3_w = (const float*)d_in[14];
  const float* ad3_b = (const float*)d_in[15];
  const float* ag    = (const float*)d_in[16];
  const float* lq_w = (const float*)d_in[17];
  const float* lq_b = (const float*)d_in[18];
  const float* lk_w = (const float*)d_in[19];
  const float* lk_b = (const float*)d_in[20];
  const float* lv_w = (const float*)d_in[21];
  const float* lv_b = (const float*)d_in[22];
  const float* ld1_w = (const float*)d_in[23];
  const float* ld1_b = (const float*)d_in[24];
  const float* ld3_w = (const float*)d_in[25];
  const float* ld3_b = (const float*)d_in[26];
  const float* lg    = (const float*)d_in[27];
  const float* wc_w = (const float*)d_in[28];
  const float* wc_b = (const float*)d_in[29];
  float* out = (float*)d_out;

  // ---- workspace carve ----
  char* p = (char*)d_ws;
  double* Wsw   = (double*)p; p += (size_t)80*192*8;
  double* Wres  = (double*)p; p += (size_t)80*128*8;
  double* bqk   = (double*)p; p += (size_t)80*8;
  double* chsumd= (double*)p; p += (size_t)B4*320*8;
  double* wdad  = (double*)p; p += (size_t)B4*320*8;
  double* cdad  = (double*)p; p += (size_t)B4*8;
  double* dabuf = (double*)p; p += (size_t)B4*NPIX*8;
  float* dlbuf  = (float*)p;  p += (size_t)B4*NPIX*4;
  float* q8f    = (float*)p;  p += (size_t)B4*128*NPIX*4;
  float* proj1  = (float*)p;  p += (size_t)B4*320*NPIX*4;  // rows 0..159 vp, 160..319 outacc
  float* projL  = (float*)p;  p += (size_t)B4*640*NPIX*4;  // rows 0..319 kl, 320..639 vl
  float* qsum   = (float*)p;  p += (size_t)B4*NPIX*4;
  float* norm_a = (float*)p;  p += (size_t)B4*NPIX*4;
  float* norm_l = (float*)p;  p += (size_t)B4*NPIX*4;
  float* colsum = (float*)p;  p += (size_t)B4*320*4;
  float* kvp    = (float*)p;  p += (size_t)B4*40*160*4;
  float* Wbig1  = (float*)p;  p += (size_t)320*320*4;
  float* bias1  = (float*)p;  p += (size_t)320*4;
  float* Wmix   = (float*)p;  p += (size_t)2880*320*4;
  float* Wd3eff = (float*)p;  p += (size_t)160*2880*4;
  float* biasqk = (float*)p;  p += (size_t)128*4;
  p = (char*)(((uintptr_t)p + 255) & ~(uintptr_t)255);
  unsigned short* xTh  = (unsigned short*)p; p += (size_t)B4*NPIX*320*2;
  unsigned short* xTl  = (unsigned short*)p; p += (size_t)B4*NPIX*320*2;
  unsigned short* Wb1h = (unsigned short*)p; p += (size_t)320*320*2;
  unsigned short* Wb1l = (unsigned short*)p; p += (size_t)320*320*2;
  unsigned short* lqh  = (unsigned short*)p; p += (size_t)320*320*2;
  unsigned short* lkh  = (unsigned short*)p; p += (size_t)320*320*2;
  unsigned short* lvh  = (unsigned short*)p; p += (size_t)320*320*2;
  unsigned short* Wd3b = (unsigned short*)p; p += (size_t)192*2880*2;
  unsigned short* wswh = (unsigned short*)p; p += (size_t)192*192*2;
  unsigned short* wswl = (unsigned short*)p; p += (size_t)192*192*2;
  unsigned short* wrsh = (unsigned short*)p; p += (size_t)128*128*2;
  unsigned short* wrsl = (unsigned short*)p; p += (size_t)128*128*2;
  unsigned short* Wqkh = (unsigned short*)p; p += (size_t)128*320*2;
  unsigned short* Wqkl = (unsigned short*)p; p += (size_t)128*320*2;
  if ((size_t)(p - (char*)d_ws) > ws_size) return;

  // aliases over dead regions (stream-ordered safety):
  unsigned short* inThi = (unsigned short*)projL;          // dead once lk/lv write projL
  unsigned short* inTlo = inThi + (size_t)B4*NPIX*320;
  unsigned short* pT = xTl;                                // dead once proj1 split GEMM done
  unsigned short* W2h = (unsigned short*)Wmix;             // dead once Wd3eff composed

  hipMemsetAsync(qsum, 0, (size_t)B4*NPIX*4, stream);
  hipMemsetAsync(kvp,  0, (size_t)B4*40*160*4, stream);
  hipMemsetAsync(dabuf, 0, (size_t)B4*NPIX*8, stream);
  hipMemsetAsync(dlbuf, 0, (size_t)B4*NPIX*4, stream);

  // ---- weight composition ----
  composeqk_kernel<<<(80*192 + 80*128 + 80 + 255)/256, 256, 0, stream>>>(
      aq_w, aq_b, ak_w, ak_b, w_swin, b_swin, w_res, b_res, Wsw, Wres, bqk);
  compose1_kernel<<<(320*320 + 255)/256, 256, 0, stream>>>(av_w, ad1_w, ld1_w, wc_w, ag, lg, Wbig1);
  bias1_kernel<<<5, 64, 0, stream>>>(av_b, ad1_b, ad3_b, ld1_b, ld3_b, wc_w, wc_b, ag, lg, bias1);
  t1_kernel<<<(2880*320 + 255)/256, 256, 0, stream>>>(ad3_w, ld3_w, ag, lg, Wmix);
  gemm_f32<<<dim3(5,3,9), 256, 0, stream>>>(wc_w, nullptr, Wmix, 320L*320, 320,
      Wd3eff, 320, 2880, 160, 320);

  // ---- weight bf16 conversions ----
  cvt_split_kernel<<<(320*320 + 255)/256, 256, 0, stream>>>(Wbig1, Wb1h, Wb1l, 320*320);
  cvt_bf16_kernel<<<(320*320 + 255)/256, 256, 0, stream>>>(lq_w, lqh, 320*320);
  cvt_bf16_kernel<<<(320*320 + 255)/256, 256, 0, stream>>>(lk_w, lkh, 320*320);
  cvt_bf16_kernel<<<(320*320 + 255)/256, 256, 0, stream>>>(lv_w, lvh, 320*320);
  cvt_pad_kernel<<<(192*2880 + 255)/256, 256, 0, stream>>>(Wd3eff, Wd3b);
  cvt_split_kernel<<<(192*192 + 255)/256, 256, 0, stream>>>(w_swin, wswh, wswl, 192*192);
  cvt_split_kernel<<<(128*128 + 255)/256, 256, 0, stream>>>(w_res, wrsh, wrsl, 128*128);
  cvtqk_kernel<<<(128*320 + 255)/256, 256, 0, stream>>>(Wsw, Wres, bqk, Wqkh, Wqkl, biasqk);

  // ---- fp64 rank-1 denominator composition (must precede inT) ----
  chsum_kernel<<<dim3(320,4), 256, 0, stream>>>(swin, resnet, chsumd);
  skda_kernel<<<4, 320, 0, stream>>>(Wsw, Wres, bqk, chsumd, wdad, cdad);

  // ---- input transpose (+fused da partial) + x-build + q8/k8 via MFMA ----
  inT_kernel<<<dim3(64,5,4), 256, 0, stream>>>(swin, resnet, wdad, dabuf, inThi, inTlo);
  xbuild_mfma<<<dim3(2,64,4), 256, 0, stream>>>(inThi, inTlo, 0, 192,
      wswh, wswl, b_swin, 192, 0, xTh, xTl);
  xbuild_mfma<<<dim3(1,64,4), 256, 0, stream>>>(inThi, inTlo, 192, 128,
      wrsh, wrsl, b_res, 128, 192, xTh, xTl);
  gemm_mfma<0,1><<<dim3(32,2,4), 256, 0, stream>>>(Wqkh, Wqkl, biasqk, inThi, inTlo,
      q8f, 128L*NPIX, nullptr);   // before lk/lv overwrite inT

  // ---- MFMA projections (proj1 last: frees xTl for pT alias) ----
  gemm_mfma<2,0><<<dim3(32,5,4), 256, 0, stream>>>(lqh, nullptr, lq_b, xTh, nullptr,
      nullptr, 0, qsum);
  gemm_mfma<1,0><<<dim3(32,5,4), 256, 0, stream>>>(lkh, nullptr, lk_b, xTh, nullptr,
      projL, 640L*NPIX, nullptr);
  gemm_mfma<0,0><<<dim3(32,5,4), 256, 0, stream>>>(lvh, nullptr, lv_b, xTh, nullptr,
      projL + 320L*NPIX, 640L*NPIX, nullptr);
  gemm_mfma<0,1><<<dim3(32,5,4), 256, 0, stream>>>(Wb1h, Wb1l, bias1, xTh, xTl,
      proj1, 320L*NPIX, nullptr);

  // ---- reductions ----
  kvp_mfma<<<dim3(2,32,4), 256, 0, stream>>>(proj1, q8f, kvp);
  colsum_kernel<<<dim3(320,4), 256, 0, stream>>>(projL, qsum, colsum);

  // ---- prep for final (pT fuses dl partial) ----
  pT_kernel<<<dim3(64,5,4), 256, 0, stream>>>(projL, colsum, pT, dlbuf);
  normfin_kernel<<<(B4*NPIX + 255)/256, 256, 0, stream>>>(dabuf, cdad, dlbuf, norm_a, norm_l);
  w2_kernel<<<(B4*160*320 + 255)/256, 256, 0, stream>>>(wc_w, colsum, W2h);

  // ---- fused epilogue + composed conv ----
  final_mfma<<<dim3(32,3,4), 256, 0, stream>>>(W2h, pT, kvp, q8f, proj1,
                                               norm_a, norm_l, ag, lg, out);
  conv_mfma<<<dim3(32,3,4), 256, 0, stream>>>(Wd3b, xTh, out);
}

// Round 8
// 340.289 us; speedup vs baseline: 2.6183x; 1.0425x over previous
//
#include <hip/hip_runtime.h>
#include <stdint.h>

#define B4 4
#define NPIX 4096

typedef short sh8 __attribute__((ext_vector_type(8)));
typedef float f4 __attribute__((ext_vector_type(4)));

__device__ __forceinline__ float delu_f(float v){
  return v > 0.f ? __fmaf_rn(10.f, v, 1.f) : __expf(10.f*v);
}
__device__ __forceinline__ unsigned short f2bf(float f){
  unsigned u = __float_as_uint(f);
  u += 0x7fffu + ((u>>16)&1u);
  return (unsigned short)(u>>16);
}
__device__ __forceinline__ float bf2f(unsigned short h){
  return __uint_as_float(((unsigned)h)<<16);
}

// ---------------- generic 64x64x16 f32 tile GEMM (weight-compose only) ----------------
__global__ __launch_bounds__(256) void gemm_f32(
    const float* __restrict__ W, const float* __restrict__ bias,
    const float* __restrict__ X, long xStride, int ldX,
    float* __restrict__ Out, long outStride, int ldOut,
    int M, int K)
{
  __shared__ float Wt[16][64];
  __shared__ float Xt[16][64];
  const int b  = blockIdx.z;
  const int m0 = blockIdx.y * 64;
  const int n0 = blockIdx.x * 64;
  const int tid = threadIdx.x;
  const int tc = tid & 15, tr = tid >> 4;
  const int wm = tid >> 2, wk = (tid & 3) << 2;
  const int xk = tid >> 4, xn = (tid & 15) << 2;
  const float* Xb = X + (long)b * xStride;
  float acc[4][4] = {};

  for (int k0 = 0; k0 < K; k0 += 16) {
    float4 wv4;
    if (m0 + wm < M) wv4 = *reinterpret_cast<const float4*>(W + (long)(m0+wm)*K + k0 + wk);
    else wv4 = make_float4(0.f,0.f,0.f,0.f);
    Wt[wk+0][wm] = wv4.x; Wt[wk+1][wm] = wv4.y; Wt[wk+2][wm] = wv4.z; Wt[wk+3][wm] = wv4.w;
    *reinterpret_cast<float4*>(&Xt[xk][xn]) =
        *reinterpret_cast<const float4*>(Xb + (long)(k0+xk)*ldX + n0 + xn);
    __syncthreads();
    #pragma unroll
    for (int kk = 0; kk < 16; ++kk) {
      float4 a4 = *reinterpret_cast<const float4*>(&Wt[kk][tr<<2]);
      float4 b4 = *reinterpret_cast<const float4*>(&Xt[kk][tc<<2]);
      float av[4] = {a4.x,a4.y,a4.z,a4.w};
      float bv[4] = {b4.x,b4.y,b4.z,b4.w};
      #pragma unroll
      for (int i=0;i<4;i++)
        #pragma unroll
        for (int j=0;j<4;j++) acc[i][j] = __fmaf_rn(av[i], bv[j], acc[i][j]);
    }
    __syncthreads();
  }

  #pragma unroll
  for (int i=0;i<4;i++){
    int m = m0 + (tr<<2) + i;
    if (m < M) {
      float bv = bias ? bias[m] : 0.f;
      float r[4];
      #pragma unroll
      for (int j=0;j<4;j++) r[j] = acc[i][j] + bv;
      *reinterpret_cast<float4*>(Out + (long)b*outStride + (long)m*ldOut + n0 + (tc<<2)) =
          make_float4(r[0],r[1],r[2],r[3]);
    }
  }
}

// ---------------- bf16 MFMA GEMM: C[m][n] = sum_k W[m][k] * xT[n][k] ----------------
// EP: 0 = store acc+bias
// EP: 3 = merged lq/lk/lv (M=960): seg0 -> delu colsum to qsum; seg1 -> delu store kl;
//         seg2 -> store vl. Out = projL base, outStride = 640*NPIX, bias = bias3[960].
template<int EP, int SPLIT>
__global__ __launch_bounds__(256) void gemm_mfma(
    const unsigned short* __restrict__ Whi, const unsigned short* __restrict__ Wlo,
    const float* __restrict__ bias,
    const unsigned short* __restrict__ Xhi, const unsigned short* __restrict__ Xlo,
    float* __restrict__ Out, long outStride, float* __restrict__ qsum)
{
  __shared__ unsigned short Ah[64][40];
  __shared__ unsigned short Bh[128][40];
  __shared__ unsigned short Al[SPLIT?64:8][40];
  __shared__ unsigned short Bl[SPLIT?128:8][40];
  const int b  = blockIdx.z;
  const int m0 = blockIdx.y * 64;
  const int n0 = blockIdx.x * 128;
  const int tid = threadIdx.x;
  const int sRow = tid >> 2, sK = (tid & 3) << 3;
  const int lane = tid & 63, w = tid >> 6;
  const int wr = w >> 1, wc = w & 1;
  const int fr = lane & 15, fko = (lane >> 4) << 3;

  f4 z4 = {0.f,0.f,0.f,0.f};
  f4 acc[2][4];
  #pragma unroll
  for (int mf=0; mf<2; mf++)
    #pragma unroll
    for (int nf=0; nf<4; nf++) acc[mf][nf] = z4;

  for (int k0 = 0; k0 < 320; k0 += 32) {
    *reinterpret_cast<sh8*>(&Ah[sRow][sK]) =
        *reinterpret_cast<const sh8*>(Whi + (long)(m0+sRow)*320 + k0 + sK);
    if (SPLIT)
      *reinterpret_cast<sh8*>(&Al[sRow][sK]) =
          *reinterpret_cast<const sh8*>(Wlo + (long)(m0+sRow)*320 + k0 + sK);
    #pragma unroll
    for (int r=0; r<2; r++){
      int row = r*64 + sRow;
      long src = ((long)b*NPIX + n0 + row)*320 + k0 + sK;
      *reinterpret_cast<sh8*>(&Bh[row][sK]) = *reinterpret_cast<const sh8*>(Xhi + src);
      if (SPLIT)
        *reinterpret_cast<sh8*>(&Bl[row][sK]) = *reinterpret_cast<const sh8*>(Xlo + src);
    }
    __syncthreads();
    sh8 aH[2], bH[4];
    #pragma unroll
    for (int mf=0; mf<2; mf++)
      aH[mf] = *reinterpret_cast<const sh8*>(&Ah[wr*32 + mf*16 + fr][fko]);
    #pragma unroll
    for (int nf=0; nf<4; nf++)
      bH[nf] = *reinterpret_cast<const sh8*>(&Bh[wc*64 + nf*16 + fr][fko]);
    #pragma unroll
    for (int mf=0; mf<2; mf++)
      #pragma unroll
      for (int nf=0; nf<4; nf++)
        acc[mf][nf] = __builtin_amdgcn_mfma_f32_16x16x32_bf16(aH[mf], bH[nf], acc[mf][nf], 0,0,0);
    if (SPLIT){
      sh8 aL[2], bL[4];
      #pragma unroll
      for (int mf=0; mf<2; mf++)
        aL[mf] = *reinterpret_cast<const sh8*>(&Al[wr*32 + mf*16 + fr][fko]);
      #pragma unroll
      for (int nf=0; nf<4; nf++)
        bL[nf] = *reinterpret_cast<const sh8*>(&Bl[wc*64 + nf*16 + fr][fko]);
      #pragma unroll
      for (int mf=0; mf<2; mf++)
        #pragma unroll
        for (int nf=0; nf<4; nf++){
          acc[mf][nf] = __builtin_amdgcn_mfma_f32_16x16x32_bf16(aL[mf], bH[nf], acc[mf][nf], 0,0,0);
          acc[mf][nf] = __builtin_amdgcn_mfma_f32_16x16x32_bf16(aH[mf], bL[nf], acc[mf][nf], 0,0,0);
        }
    }
    __syncthreads();
  }

  const int orow0 = m0 + wr*32;
  const int ocol  = n0 + wc*64;
  if (EP == 3){
    const int seg = m0 / 320;
    if (seg == 0){
      #pragma unroll
      for (int nf=0; nf<4; nf++){
        float s = 0.f;
        #pragma unroll
        for (int mf=0; mf<2; mf++)
          #pragma unroll
          for (int r=0; r<4; r++)
            s += delu_f(acc[mf][nf][r] + bias[orow0 + mf*16 + ((lane>>4)<<2) + r]);
        s += __shfl_xor(s, 16, 64);
        s += __shfl_xor(s, 32, 64);
        if (lane < 16) atomicAdd(&qsum[(long)b*NPIX + ocol + nf*16 + fr], s);
      }
    } else {
      const int mseg0 = m0 - seg*320 + wr*32;
      long base = (long)b*outStride + (seg == 2 ? 320L*NPIX : 0);
      #pragma unroll
      for (int mf=0; mf<2; mf++)
        #pragma unroll
        for (int r=0; r<4; r++){
          int rowI = mseg0 + mf*16 + ((lane>>4)<<2) + r;
          float bv = bias[seg*320 + rowI];
          #pragma unroll
          for (int nf=0; nf<4; nf++){
            float v = acc[mf][nf][r] + bv;
            if (seg == 1) v = delu_f(v);
            Out[base + (long)rowI*NPIX + ocol + nf*16 + fr] = v;
          }
        }
    }
  } else {
    #pragma unroll
    for (int mf=0; mf<2; mf++)
      #pragma unroll
      for (int r=0; r<4; r++){
        int row = orow0 + mf*16 + ((lane>>4)<<2) + r;
        float bv = bias ? bias[row] : 0.f;
        #pragma unroll
        for (int nf=0; nf<4; nf++){
          float v = acc[mf][nf][r] + bv;
          Out[(long)b*outStride + (long)row*NPIX + ocol + nf*16 + fr] = v;
        }
      }
  }
}

// ---------------- x-build MFMA: role-flipped (A = pixels, B = weight rows), 3-pass split ----------------
__global__ __launch_bounds__(256) void xbuild_mfma(
    const unsigned short* __restrict__ inThi, const unsigned short* __restrict__ inTlo,
    int cOff, int K,
    const unsigned short* __restrict__ Wh, const unsigned short* __restrict__ Wl,
    const float* __restrict__ bias, int outC, int tOff,
    unsigned short* __restrict__ xTh, unsigned short* __restrict__ xTl)
{
  __shared__ unsigned short Ah[64][40];
  __shared__ unsigned short Bh[128][40];
  __shared__ unsigned short Al[64][40];
  __shared__ unsigned short Bl[128][40];
  const int b  = blockIdx.z;
  const int m0 = blockIdx.y * 64;
  const int n0 = blockIdx.x * 128;
  const int tid = threadIdx.x;
  const int sRow = tid >> 2, sK = (tid & 3) << 3;
  const int lane = tid & 63, w = tid >> 6;
  const int wr = w >> 1, wc = w & 1;
  const int fr = lane & 15, fko = (lane >> 4) << 3;

  f4 z4 = {0.f,0.f,0.f,0.f};
  f4 acc[2][4];
  #pragma unroll
  for (int mf=0; mf<2; mf++)
    #pragma unroll
    for (int nf=0; nf<4; nf++) acc[mf][nf] = z4;

  for (int k0 = 0; k0 < K; k0 += 32) {
    long asrc = ((long)b*NPIX + m0 + sRow)*320 + cOff + k0 + sK;
    *reinterpret_cast<sh8*>(&Ah[sRow][sK]) = *reinterpret_cast<const sh8*>(inThi + asrc);
    *reinterpret_cast<sh8*>(&Al[sRow][sK]) = *reinterpret_cast<const sh8*>(inTlo + asrc);
    #pragma unroll
    for (int r=0; r<2; r++){
      int row = r*64 + sRow;
      sh8 vh = {0,0,0,0,0,0,0,0}, vl = {0,0,0,0,0,0,0,0};
      if (n0 + row < outC){
        vh = *reinterpret_cast<const sh8*>(Wh + (long)(n0+row)*K + k0 + sK);
        vl = *reinterpret_cast<const sh8*>(Wl + (long)(n0+row)*K + k0 + sK);
      }
      *reinterpret_cast<sh8*>(&Bh[row][sK]) = vh;
      *reinterpret_cast<sh8*>(&Bl[row][sK]) = vl;
    }
    __syncthreads();
    sh8 aH[2], aL[2], bH[4], bL[4];
    #pragma unroll
    for (int mf=0; mf<2; mf++){
      aH[mf] = *reinterpret_cast<const sh8*>(&Ah[wr*32 + mf*16 + fr][fko]);
      aL[mf] = *reinterpret_cast<const sh8*>(&Al[wr*32 + mf*16 + fr][fko]);
    }
    #pragma unroll
    for (int nf=0; nf<4; nf++){
      bH[nf] = *reinterpret_cast<const sh8*>(&Bh[wc*64 + nf*16 + fr][fko]);
      bL[nf] = *reinterpret_cast<const sh8*>(&Bl[wc*64 + nf*16 + fr][fko]);
    }
    #pragma unroll
    for (int mf=0; mf<2; mf++)
      #pragma unroll
      for (int nf=0; nf<4; nf++){
        acc[mf][nf] = __builtin_amdgcn_mfma_f32_16x16x32_bf16(aH[mf], bH[nf], acc[mf][nf], 0,0,0);
        acc[mf][nf] = __builtin_amdgcn_mfma_f32_16x16x32_bf16(aH[mf], bL[nf], acc[mf][nf], 0,0,0);
        acc[mf][nf] = __builtin_amdgcn_mfma_f32_16x16x32_bf16(aL[mf], bH[nf], acc[mf][nf], 0,0,0);
      }
    __syncthreads();
  }

  const int opix0 = m0 + wr*32;
  const int ocol  = n0 + wc*64;
  #pragma unroll
  for (int mf=0; mf<2; mf++)
    #pragma unroll
    for (int r=0; r<4; r++){
      int pix = opix0 + mf*16 + ((lane>>4)<<2) + r;
      #pragma unroll
      for (int nf=0; nf<4; nf++){
        int col = ocol + nf*16 + fr;
        if (col < outC){
          float v = acc[mf][nf][r] + bias[col];
          unsigned short h = f2bf(v);
          long o = ((long)b*NPIX + pix)*320 + tOff + col;
          xTh[o] = h;
          xTl[o] = f2bf(v - bf2f(h));
        }
      }
    }
}

// ---------------- kvp via MFMA, K-split: kvp[b][m][o] = sum_n k8[m][n]*vp[o][n] ----------------
__global__ __launch_bounds__(256) void kvp_mfma(
    const float* __restrict__ proj1, const float* __restrict__ q8f,
    float* __restrict__ kvp)
{
  __shared__ unsigned short Ah[64][40];
  __shared__ unsigned short Bh[128][40];
  __shared__ unsigned short Al[64][40];
  __shared__ unsigned short Bl[128][40];
  const int b = blockIdx.z;
  const int o0 = blockIdx.x * 128;
  const int kbase = blockIdx.y * 128;
  const int tid = threadIdx.x;
  const int sRow = tid >> 2, sK = (tid & 3) << 3;
  const int lane = tid & 63, w = tid >> 6;
  const int wr = w >> 1, wc = w & 1;
  const int fr = lane & 15, fko = (lane >> 4) << 3;
  const float* k8 = q8f + ((long)b*128 + 40)*NPIX;
  const float* vp = proj1 + (long)b*(320L*NPIX);

  f4 z4 = {0.f,0.f,0.f,0.f};
  f4 acc[2][4];
  #pragma unroll
  for (int mf=0; mf<2; mf++)
    #pragma unroll
    for (int nf=0; nf<4; nf++) acc[mf][nf] = z4;

  for (int k0 = 0; k0 < 128; k0 += 32) {
    {
      float vv[8] = {0,0,0,0,0,0,0,0};
      if (sRow < 40){
        float4 a4 = *reinterpret_cast<const float4*>(k8 + (long)sRow*NPIX + kbase + k0 + sK);
        float4 b4 = *reinterpret_cast<const float4*>(k8 + (long)sRow*NPIX + kbase + k0 + sK + 4);
        vv[0]=a4.x; vv[1]=a4.y; vv[2]=a4.z; vv[3]=a4.w;
        vv[4]=b4.x; vv[5]=b4.y; vv[6]=b4.z; vv[7]=b4.w;
      }
      #pragma unroll
      for (int i=0;i<8;i++){
        unsigned short h = f2bf(vv[i]);
        Ah[sRow][sK+i] = h;
        Al[sRow][sK+i] = f2bf(vv[i] - bf2f(h));
      }
    }
    #pragma unroll
    for (int r=0;r<2;r++){
      int row = r*64 + sRow;
      int o = o0 + row;
      float vv[8] = {0,0,0,0,0,0,0,0};
      if (o < 160){
        float4 v4a = *reinterpret_cast<const float4*>(vp + (long)o*NPIX + kbase + k0 + sK);
        float4 v4b = *reinterpret_cast<const float4*>(vp + (long)o*NPIX + kbase + k0 + sK + 4);
        vv[0]=v4a.x; vv[1]=v4a.y; vv[2]=v4a.z; vv[3]=v4a.w;
        vv[4]=v4b.x; vv[5]=v4b.y; vv[6]=v4b.z; vv[7]=v4b.w;
      }
      #pragma unroll
      for (int i=0;i<8;i++){
        unsigned short h = f2bf(vv[i]);
        Bh[row][sK+i] = h;
        Bl[row][sK+i] = f2bf(vv[i] - bf2f(h));
      }
    }
    __syncthreads();
    sh8 aH[2], aL[2], bH[4], bL[4];
    #pragma unroll
    for (int mf=0; mf<2; mf++){
      aH[mf] = *reinterpret_cast<const sh8*>(&Ah[wr*32 + mf*16 + fr][fko]);
      aL[mf] = *reinterpret_cast<const sh8*>(&Al[wr*32 + mf*16 + fr][fko]);
    }
    #pragma unroll
    for (int nf=0; nf<4; nf++){
      bH[nf] = *reinterpret_cast<const sh8*>(&Bh[wc*64 + nf*16 + fr][fko]);
      bL[nf] = *reinterpret_cast<const sh8*>(&Bl[wc*64 + nf*16 + fr][fko]);
    }
    #pragma unroll
    for (int mf=0; mf<2; mf++)
      #pragma unroll
      for (int nf=0; nf<4; nf++){
        acc[mf][nf] = __builtin_amdgcn_mfma_f32_16x16x32_bf16(aH[mf], bH[nf], acc[mf][nf], 0,0,0);
        acc[mf][nf] = __builtin_amdgcn_mfma_f32_16x16x32_bf16(aH[mf], bL[nf], acc[mf][nf], 0,0,0);
        acc[mf][nf] = __builtin_amdgcn_mfma_f32_16x16x32_bf16(aL[mf], bH[nf], acc[mf][nf], 0,0,0);
      }
    __syncthreads();
  }

  const int orow0 = wr*32;
  const int ocol  = o0 + wc*64;
  #pragma unroll
  for (int mf=0; mf<2; mf++)
    #pragma unroll
    for (int r=0; r<4; r++){
      int row = orow0 + mf*16 + ((lane>>4)<<2) + r;
      if (row < 40){
        #pragma unroll
        for (int nf=0; nf<4; nf++){
          int col = ocol + nf*16 + fr;
          if (col < 160)
            atomicAdd(&kvp[((long)b*40 + row)*160 + col], acc[mf][nf][r]);
        }
      }
    }
}

// ---------------- final MFMA: out = outacc + cL*norm_l*(W2@pT) + cA*norm_a*(kvpT@q8) ----------------
__global__ __launch_bounds__(256) void final_mfma(
    const unsigned short* __restrict__ W2h,
    const unsigned short* __restrict__ pT,
    const float* __restrict__ kvp,
    const float* __restrict__ q8f,
    const float* __restrict__ proj1,
    const float* __restrict__ norm_a, const float* __restrict__ norm_l,
    const float* __restrict__ ag, const float* __restrict__ lg,
    float* __restrict__ Out)
{
  __shared__ unsigned short Ah[64][40];
  __shared__ unsigned short Bh[128][40];
  __shared__ unsigned short Al[64][40];
  __shared__ unsigned short Bl[128][40];
  const int b  = blockIdx.z;
  const int m0 = blockIdx.y * 64;
  const int n0 = blockIdx.x * 128;
  const int tid = threadIdx.x;
  const int sRow = tid >> 2, sK = (tid & 3) << 3;
  const int lane = tid & 63, w = tid >> 6;
  const int wr = w >> 1, wc = w & 1;
  const int fr = lane & 15, fko = (lane >> 4) << 3;

  f4 z4 = {0.f,0.f,0.f,0.f};
  f4 acc1[2][4], acc2[2][4];
  #pragma unroll
  for (int mf=0; mf<2; mf++)
    #pragma unroll
    for (int nf=0; nf<4; nf++){ acc1[mf][nf] = z4; acc2[mf][nf] = z4; }

  for (int k0 = 0; k0 < 320; k0 += 32) {
    sh8 av = {0,0,0,0,0,0,0,0};
    if (m0 + sRow < 160)
      av = *reinterpret_cast<const sh8*>(W2h + ((long)b*160 + m0 + sRow)*320 + k0 + sK);
    *reinterpret_cast<sh8*>(&Ah[sRow][sK]) = av;
    #pragma unroll
    for (int r=0; r<2; r++){
      int row = r*64 + sRow;
      *reinterpret_cast<sh8*>(&Bh[row][sK]) =
          *reinterpret_cast<const sh8*>(pT + ((long)b*NPIX + n0 + row)*320 + k0 + sK);
    }
    __syncthreads();
    sh8 aH[2], bH[4];
    #pragma unroll
    for (int mf=0; mf<2; mf++)
      aH[mf] = *reinterpret_cast<const sh8*>(&Ah[wr*32 + mf*16 + fr][fko]);
    #pragma unroll
    for (int nf=0; nf<4; nf++)
      bH[nf] = *reinterpret_cast<const sh8*>(&Bh[wc*64 + nf*16 + fr][fko]);
    #pragma unroll
    for (int mf=0; mf<2; mf++)
      #pragma unroll
      for (int nf=0; nf<4; nf++)
        acc1[mf][nf] = __builtin_amdgcn_mfma_f32_16x16x32_bf16(aH[mf], bH[nf], acc1[mf][nf], 0,0,0);
    __syncthreads();
  }

  for (int k0 = 0; k0 < 64; k0 += 32) {
    {
      int m = m0 + sRow;
      #pragma unroll
      for (int i=0;i<8;i++){
        int kk = k0 + sK + i;
        float v = (kk < 40 && m < 160) ? kvp[((long)b*40 + kk)*160 + m] : 0.f;
        unsigned short h = f2bf(v);
        Ah[sRow][sK+i] = h;
        Al[sRow][sK+i] = f2bf(v - bf2f(h));
      }
    }
    #pragma unroll
    for (int r=0; r<2; r++){
      int row = r*64 + sRow;
      int pix = n0 + row;
      #pragma unroll
      for (int i=0;i<8;i++){
        int kk = k0 + sK + i;
        float v = (kk < 40) ? q8f[((long)b*128 + kk)*NPIX + pix] : 0.f;
        unsigned short h = f2bf(v);
        Bh[row][sK+i] = h;
        Bl[row][sK+i] = f2bf(v - bf2f(h));
      }
    }
    __syncthreads();
    sh8 aH[2], aL[2], bH[4], bL[4];
    #pragma unroll
    for (int mf=0; mf<2; mf++){
      aH[mf] = *reinterpret_cast<const sh8*>(&Ah[wr*32 + mf*16 + fr][fko]);
      aL[mf] = *reinterpret_cast<const sh8*>(&Al[wr*32 + mf*16 + fr][fko]);
    }
    #pragma unroll
    for (int nf=0; nf<4; nf++){
      bH[nf] = *reinterpret_cast<const sh8*>(&Bh[wc*64 + nf*16 + fr][fko]);
      bL[nf] = *reinterpret_cast<const sh8*>(&Bl[wc*64 + nf*16 + fr][fko]);
    }
    #pragma unroll
    for (int mf=0; mf<2; mf++)
      #pragma unroll
      for (int nf=0; nf<4; nf++){
        acc2[mf][nf] = __builtin_amdgcn_mfma_f32_16x16x32_bf16(aH[mf], bH[nf], acc2[mf][nf], 0,0,0);
        acc2[mf][nf] = __builtin_amdgcn_mfma_f32_16x16x32_bf16(aH[mf], bL[nf], acc2[mf][nf], 0,0,0);
        acc2[mf][nf] = __builtin_amdgcn_mfma_f32_16x16x32_bf16(aL[mf], bH[nf], acc2[mf][nf], 0,0,0);
      }
    __syncthreads();
  }

  const float cA = 0.7f*ag[0], cL = 0.3f*lg[0];
  const int orow0 = m0 + wr*32;
  const int ocol  = n0 + wc*64;
  #pragma unroll
  for (int mf=0; mf<2; mf++)
    #pragma unroll
    for (int r=0; r<4; r++){
      int row = orow0 + mf*16 + ((lane>>4)<<2) + r;
      if (row < 160){
        const float* oa = proj1 + (long)b*(320L*NPIX) + (long)(160+row)*NPIX;
        #pragma unroll
        for (int nf=0; nf<4; nf++){
          int col = ocol + nf*16 + fr;
          Out[((long)b*160 + row)*NPIX + col] =
              oa[col] + cL*norm_l[(long)b*NPIX+col]*acc1[mf][nf][r]
                      + cA*norm_a[(long)b*NPIX+col]*acc2[mf][nf][r];
        }
      }
    }
}

// ---------------- composed 3x3 conv via MFMA, halo-staged + swizzled + reg-prefetch ----
// A: [64][292] shorts (stride 584B, 18-bank step -> conflict-free).
// B: 16B-granular [g=4][265 units] where unit = (lr*66+lw), pad 264->265 per g block.
__global__ __launch_bounds__(256) void conv_mfma(
    const unsigned short* __restrict__ Wd3,   // [192][2880] bf16 (rows 160.. zero)
    const unsigned short* __restrict__ Xhi,   // [B][4096][320] bf16
    float* __restrict__ Out)                  // [B][160][4096] +=
{
  __shared__ unsigned short Ah[64][292];
  __shared__ unsigned short Bs[4*265*8];
  const int b  = blockIdx.z;
  const int m0 = blockIdx.y * 64;
  const int n0 = blockIdx.x * 128;
  const int h0 = n0 >> 6;
  const int tid = threadIdx.x;
  const int lane = tid & 63, w = tid >> 6;
  const int wr = w >> 1, wc = w & 1;
  const int fr = lane & 15, fg = lane >> 4;
  const int fko = fg << 3;

  f4 z4 = {0.f,0.f,0.f,0.f};
  f4 acc[2][4];
  #pragma unroll
  for (int mf=0; mf<2; mf++)
    #pragma unroll
    for (int nf=0; nf<4; nf++) acc[mf][nf] = z4;

  const int sr = tid >> 6;          // halo row 0..3
  const int sw = tid & 63;          // image col 0..63
  const int hp = h0 - 1 + sr;
  const bool rowok = (hp >= 0) && (hp < 64);
  const sh8 zero8 = {0,0,0,0,0,0,0,0};
  // zero the horizontal halo columns once (lw = 0 and 65, all g, all rows)
  if (tid < 32){
    int r = tid >> 3;               // 0..3
    int ws = (tid & 4) ? 65 : 0;
    int g = tid & 3;
    *reinterpret_cast<sh8*>(&Bs[((size_t)g*265 + r*66 + ws)*8]) = zero8;
  }

  const int arow = tid >> 2;
  const int acol = (tid & 3) << 3;

  sh8 aReg[9], bReg[4];
  {
    const unsigned short* wsrc = Wd3 + (long)(m0+arow)*2880 + acol;
    #pragma unroll
    for (int t=0;t<9;t++) aReg[t] = *reinterpret_cast<const sh8*>(wsrc + t*320);
    const unsigned short* bsrc = Xhi + ((long)b*NPIX + hp*64 + sw)*320;
    #pragma unroll
    for (int g=0; g<4; g++){
      sh8 v = zero8;
      if (rowok) v = *reinterpret_cast<const sh8*>(bsrc + g*8);
      bReg[g] = v;
    }
  }

  for (int c0 = 0; c0 < 320; c0 += 32){
    // write staged regs to LDS
    #pragma unroll
    for (int t=0;t<9;t++)
      *reinterpret_cast<sh8*>(&Ah[arow][t*32 + acol]) = aReg[t];
    #pragma unroll
    for (int g=0; g<4; g++)
      *reinterpret_cast<sh8*>(&Bs[((size_t)g*265 + sr*66 + sw + 1)*8]) = bReg[g];
    // prefetch next chunk (latency hides under MFMA phase)
    if (c0 + 32 < 320){
      const unsigned short* wsrc = Wd3 + (long)(m0+arow)*2880 + c0 + 32 + acol;
      #pragma unroll
      for (int t=0;t<9;t++) aReg[t] = *reinterpret_cast<const sh8*>(wsrc + t*320);
      const unsigned short* bsrc = Xhi + ((long)b*NPIX + hp*64 + sw)*320 + c0 + 32;
      #pragma unroll
      for (int g=0; g<4; g++){
        sh8 v = zero8;
        if (rowok) v = *reinterpret_cast<const sh8*>(bsrc + g*8);
        bReg[g] = v;
      }
    }
    __syncthreads();
    #pragma unroll
    for (int t=0; t<9; t++){
      const int dh = t/3 - 1, dw = t%3 - 1;
      sh8 aH[2], bH[4];
      #pragma unroll
      for (int mf=0; mf<2; mf++)
        aH[mf] = *reinterpret_cast<const sh8*>(&Ah[wr*32 + mf*16 + fr][t*32 + fko]);
      #pragma unroll
      for (int nf=0; nf<4; nf++){
        int np = wc*64 + nf*16 + fr;
        int lr = (np >> 6) + dh + 1;
        int lw = (np & 63) + dw + 1;
        bH[nf] = *reinterpret_cast<const sh8*>(&Bs[((size_t)fg*265 + lr*66 + lw)*8]);
      }
      #pragma unroll
      for (int mf=0; mf<2; mf++)
        #pragma unroll
        for (int nf=0; nf<4; nf++)
          acc[mf][nf] = __builtin_amdgcn_mfma_f32_16x16x32_bf16(aH[mf], bH[nf], acc[mf][nf], 0,0,0);
    }
    __syncthreads();
  }

  const int orow0 = m0 + wr*32;
  const int ocol  = n0 + wc*64;
  #pragma unroll
  for (int mf=0; mf<2; mf++)
    #pragma unroll
    for (int r=0; r<4; r++){
      int row = orow0 + mf*16 + ((lane>>4)<<2) + r;
      if (row < 160){
        #pragma unroll
        for (int nf=0; nf<4; nf++){
          long o = ((long)b*160 + row)*NPIX + ocol + nf*16 + fr;
          Out[o] += acc[mf][nf][r];
        }
      }
    }
}

// ---------------- weight composition kernels ----------------
__global__ void compose1_kernel(const float* __restrict__ av_w, const float* __restrict__ ad1_w,
    const float* __restrict__ ld1_w, const float* __restrict__ wc_w,
    const float* __restrict__ ag, const float* __restrict__ lg, float* __restrict__ Wbig1)
{
  int idx = blockIdx.x*256 + threadIdx.x;
  if (idx >= 320*320) return;
  int r = idx / 320, c = idx % 320;
  float cD = 1.4f*ag[0], cL = 0.3f*lg[0];
  if (r < 160) {
    float s = 0.f;
    for (int j=0;j<320;j++) s += wc_w[r*320+j]*av_w[j*320+c];
    Wbig1[idx] = s;
  } else {
    int o = r - 160;
    float s1 = 0.f, s2 = 0.f;
    for (int j=0;j<320;j++){
      float w = wc_w[o*320+j];
      s1 += w*ad1_w[j*320+c];
      s2 += w*ld1_w[j*320+c];
    }
    Wbig1[idx] = 2.f*wc_w[o*320+c] + cD*s1 + cL*s2;
  }
}

__global__ void bias1_kernel(const float* __restrict__ av_b, const float* __restrict__ ad1_b,
    const float* __restrict__ ad3_b, const float* __restrict__ ld1_b, const float* __restrict__ ld3_b,
    const float* __restrict__ wc_w, const float* __restrict__ wc_b,
    const float* __restrict__ ag, const float* __restrict__ lg, float* __restrict__ bias1)
{
  int r = blockIdx.x*64 + threadIdx.x;
  if (r >= 320) return;
  float cD = 1.4f*ag[0], cL = 0.3f*lg[0];
  if (r < 160){
    float s = 0.f;
    for (int j=0;j<320;j++) s += wc_w[r*320+j]*av_b[j];
    bias1[r] = s;
  } else {
    int o = r - 160;
    float s = wc_b[o];
    for (int j=0;j<320;j++){
      float w = wc_w[o*320+j];
      s += cD*w*(ad1_b[j]+ad3_b[j]) + cL*w*(ld1_b[j]+ld3_b[j]);
    }
    bias1[r] = s;
  }
}

__global__ void composeqk_kernel(const float* __restrict__ aq_w, const float* __restrict__ aq_b,
    const float* __restrict__ ak_w, const float* __restrict__ ak_b,
    const float* __restrict__ w_swin, const float* __restrict__ b_swin,
    const float* __restrict__ w_res, const float* __restrict__ b_res,
    double* __restrict__ Wsw, double* __restrict__ Wres, double* __restrict__ bqk)
{
  int idx = blockIdx.x*256 + threadIdx.x;
  if (idx < 80*192){
    int m = idx/192, j = idx%192;
    const float* aw = (m < 40) ? aq_w + m*320 : ak_w + (m-40)*320;
    double s = 0.0;
    for (int i=0;i<192;i++) s += (double)aw[i]*(double)w_swin[i*192+j];
    Wsw[idx] = s;
  }
  int idx2 = idx - 80*192;
  if (idx2 >= 0 && idx2 < 80*128){
    int m = idx2/128, j = idx2%128;
    const float* aw = (m < 40) ? aq_w + m*320 + 192 : ak_w + (m-40)*320 + 192;
    double s = 0.0;
    for (int i=0;i<128;i++) s += (double)aw[i]*(double)w_res[i*128+j];
    Wres[idx2] = s;
  }
  int idx3 = idx - 80*192 - 80*128;
  if (idx3 >= 0 && idx3 < 80){
    int m = idx3;
    const float* aw = (m < 40) ? aq_w + m*320 : ak_w + (m-40)*320;
    double s = (double)((m < 40) ? aq_b[m] : ak_b[m-40]);
    for (int i=0;i<192;i++) s += (double)aw[i]*(double)b_swin[i];
    for (int i=0;i<128;i++) s += (double)aw[192+i]*(double)b_res[i];
    bqk[m] = s;
  }
}

__global__ void t1_kernel(const float* __restrict__ ad3_w, const float* __restrict__ ld3_w,
    const float* __restrict__ ag, const float* __restrict__ lg, float* __restrict__ Wmix)
{
  long idx = (long)blockIdx.x*256 + threadIdx.x;
  if (idx >= 2880L*320) return;
  int k = (int)(idx / 320), c = (int)(idx % 320);
  int t = k / 320, j = k % 320;
  float cD = 1.4f*ag[0], cL = 0.3f*lg[0];
  long src = (long)(j*320 + c)*9 + t;
  Wmix[idx] = cD*ad3_w[src] + cL*ld3_w[src];
}

// padded composed qk weight [128][320] bf16 hi/lo + fp32 bias[128]
__global__ void cvtqk_kernel(const double* __restrict__ Wsw, const double* __restrict__ Wres,
    const double* __restrict__ bqk,
    unsigned short* __restrict__ Wqkh, unsigned short* __restrict__ Wqkl,
    float* __restrict__ biasqk)
{
  int idx = blockIdx.x*256 + threadIdx.x;
  if (idx < 128*320){
    int row = idx / 320, col = idx % 320;
    double v = 0.0;
    if (row < 80) v = (col < 192) ? Wsw[row*192+col] : Wres[row*128+(col-192)];
    float f = (float)v;
    unsigned short h = f2bf(f);
    Wqkh[idx] = h;
    Wqkl[idx] = f2bf(f - bf2f(h));
  }
  if (idx < 128) biasqk[idx] = (idx < 80) ? (float)bqk[idx] : 0.f;
}

// ---------------- conversions ----------------
__global__ void cvt_bf16_kernel(const float* __restrict__ src, unsigned short* __restrict__ dst, int n){
  int i = blockIdx.x*256 + threadIdx.x;
  if (i < n) dst[i] = f2bf(src[i]);
}
__global__ void cvt_split_kernel(const float* __restrict__ src,
    unsigned short* __restrict__ hi, unsigned short* __restrict__ lo, int n){
  int i = blockIdx.x*256 + threadIdx.x;
  if (i < n){
    float v = src[i];
    unsigned short h = f2bf(v);
    hi[i] = h;
    lo[i] = f2bf(v - bf2f(h));
  }
}
__global__ void cvt_pad_kernel(const float* __restrict__ src, unsigned short* __restrict__ dst){
  int i = blockIdx.x*256 + threadIdx.x;
  if (i >= 192*2880) return;
  int row = i / 2880;
  dst[i] = (row < 160) ? f2bf(src[i]) : (unsigned short)0;
}
__global__ void bias3_kernel(const float* __restrict__ a, const float* __restrict__ b_,
    const float* __restrict__ c, float* __restrict__ o){
  int i = blockIdx.x*256 + threadIdx.x;
  if (i < 320) o[i] = a[i];
  else if (i < 640) o[i] = b_[i-320];
  else if (i < 960) o[i] = c[i-640];
}

// inT: transpose raw inputs to [B][4096][320] bf16 hi/lo + fused fp64 da partial (wda . in)
__global__ __launch_bounds__(256) void inT_kernel(
    const float* __restrict__ swin, const float* __restrict__ resnet,
    const double* __restrict__ wdad, double* __restrict__ dabuf,
    unsigned short* __restrict__ inThi, unsigned short* __restrict__ inTlo)
{
  __shared__ float t[64][65];
  __shared__ double redD[4][64];
  const int b = blockIdx.z, ct = blockIdx.y, n0 = blockIdx.x*64;
  const float* src; int C, cs0;
  if (ct < 3){ src = swin;   C = 192; cs0 = ct*64; }
  else       { src = resnet; C = 128; cs0 = (ct-3)*64; }
  const int dst0 = ct*64;
  const int tid = threadIdx.x;
  #pragma unroll
  for (int it=0; it<16; ++it){
    int idx = it*256 + tid;
    int c = idx >> 6, n = idx & 63;
    t[c][n] = src[((long)b*C + cs0 + c)*NPIX + n0 + n];
  }
  __syncthreads();
  {
    int cg = tid >> 6, n = tid & 63;
    double s = 0.0;
    #pragma unroll
    for (int j=0;j<16;j++){
      int c = cg*16 + j;
      s += wdad[b*320 + dst0 + c] * (double)t[c][n];
    }
    redD[cg][n] = s;
  }
  __syncthreads();
  if (tid < 64){
    double s = redD[0][tid]+redD[1][tid]+redD[2][tid]+redD[3][tid];
    atomicAdd(&dabuf[(long)b*NPIX + n0 + tid], s);
  }
  #pragma unroll
  for (int it=0; it<16; ++it){
    int idx = it*256 + tid;
    int n = idx >> 6, c = idx & 63;
    float v = t[c][n];
    unsigned short h = f2bf(v);
    long o = ((long)b*NPIX + n0 + n)*320 + dst0 + c;
    inThi[o] = h;
    inTlo[o] = f2bf(v - bf2f(h));
  }
}

// pT[n][c] = bf16(kl[c][n]*vl[c][n]) + fused fp32 dl partial (cs . kl)
__global__ __launch_bounds__(256) void pT_kernel(
    const float* __restrict__ projL, const float* __restrict__ colsum,
    unsigned short* __restrict__ pT, float* __restrict__ dlbuf)
{
  __shared__ float t[64][65];
  __shared__ float css[64];
  __shared__ float redF[4][64];
  const int b = blockIdx.z, c0 = blockIdx.y*64, n0 = blockIdx.x*64;
  const float* kl = projL + (long)b*(640L*NPIX);
  const float* vl = kl + 320L*NPIX;
  const int tid = threadIdx.x;
  if (tid < 64) css[tid] = colsum[b*320 + c0 + tid];
  __syncthreads();
  float sdl = 0.f;
  #pragma unroll
  for (int it=0; it<16; ++it){
    int idx = it*256 + tid;
    int c = idx >> 6, n = idx & 63;
    long s = (long)(c0+c)*NPIX + n0 + n;
    float klv = kl[s];
    t[c][n] = klv*vl[s];
    sdl = __fmaf_rn(css[c], klv, sdl);
  }
  redF[tid>>6][tid&63] = sdl;
  __syncthreads();
  if (tid < 64)
    atomicAdd(&dlbuf[(long)b*NPIX + n0 + tid],
              redF[0][tid]+redF[1][tid]+redF[2][tid]+redF[3][tid]);
  #pragma unroll
  for (int it=0; it<16; ++it){
    int idx = it*256 + tid;
    int n = idx >> 6, c = idx & 63;
    pT[((long)b*NPIX + n0 + n)*320 + c0 + c] = f2bf(t[c][n]);
  }
}

// norm finisher
__global__ void normfin_kernel(const double* __restrict__ dabuf, const double* __restrict__ cdad,
    const float* __restrict__ dlbuf, float* __restrict__ norm_a, float* __restrict__ norm_l)
{
  int i = blockIdx.x*256 + threadIdx.x;
  if (i >= B4*NPIX) return;
  int b = i >> 12;
  norm_a[i] = (float)(1.0/(dabuf[i] + cdad[b]));
  norm_l[i] = 1.f/(dlbuf[i] + 1e-10f);
}

// W2h[b][o][c] = bf16(wc[o][c]*colsum[b][c])
__global__ void w2_kernel(const float* __restrict__ wc_w, const float* __restrict__ colsum,
    unsigned short* __restrict__ W2h)
{
  int idx = blockIdx.x*256 + threadIdx.x;
  if (idx >= B4*160*320) return;
  int b = idx / (160*320);
  int rem = idx - b*160*320;
  int c = rem % 320;
  W2h[idx] = f2bf(wc_w[rem]*colsum[b*320+c]);
}

// ---------------- fp64 rank-1 denominator path ----------------
__global__ __launch_bounds__(256) void chsum_kernel(
    const float* __restrict__ swin, const float* __restrict__ resnet,
    double* __restrict__ chsumd)
{
  int b = blockIdx.y, c = blockIdx.x;
  const float* row = (c < 192) ? swin + ((long)b*192 + c)*NPIX
                               : resnet + ((long)b*128 + (c-192))*NPIX;
  double s = 0.0;
  for (int n = threadIdx.x; n < NPIX; n += 256) s += (double)row[n];
  __shared__ double sd[256];
  sd[threadIdx.x] = s; __syncthreads();
  for (int o=128; o; o>>=1){ if (threadIdx.x < o) sd[threadIdx.x] += sd[threadIdx.x+o]; __syncthreads(); }
  if (threadIdx.x == 0) chsumd[b*320+c] = sd[0];
}

__global__ __launch_bounds__(320) void skda_kernel(
    const double* __restrict__ Wsw, const double* __restrict__ Wres,
    const double* __restrict__ bqk, const double* __restrict__ chsumd,
    double* __restrict__ wdad, double* __restrict__ cdad)
{
  int b = blockIdx.x;
  __shared__ double sk[40];
  int tid = threadIdx.x;
  if (tid < 40){
    int m = 40 + tid;
    double s = 4096.0 * bqk[m];
    for (int j=0;j<192;j++) s += Wsw[m*192+j]*chsumd[b*320+j];
    for (int j=0;j<128;j++) s += Wres[m*128+j]*chsumd[b*320+192+j];
    sk[tid] = s + 1e-10;
  }
  __syncthreads();
  {
    int c = tid;
    double s = 0.0;
    if (c < 192){ for (int m=0;m<40;m++) s += sk[m]*Wsw[m*192+c]; }
    else        { for (int m=0;m<40;m++) s += sk[m]*Wres[m*128+(c-192)]; }
    wdad[b*320+c] = s;
  }
  if (tid == 0){
    double s = 0.0;
    for (int m=0;m<40;m++) s += sk[m]*bqk[m];
    cdad[b] = s;
  }
}

// ---------------- reductions ----------------
__global__ void colsum_kernel(const float* __restrict__ projL, const float* __restrict__ qsum,
    float* __restrict__ colsum)
{
  int b = blockIdx.y, c = blockIdx.x;
  const float* kl = projL + (long)b*640*NPIX + (long)c*NPIX;
  const float* qs = qsum + (long)b*NPIX;
  double s = 0.0;
  for (int n=threadIdx.x; n<NPIX; n+=256) s += (double)kl[n]*(double)qs[n];
  __shared__ double sd[256];
  sd[threadIdx.x] = s; __syncthreads();
  for (int o=128; o; o>>=1){ if (threadIdx.x < o) sd[threadIdx.x] += sd[threadIdx.x+o]; __syncthreads(); }
  if (threadIdx.x == 0) colsum[b*320+c] = (float)sd[0];
}

extern "C" void kernel_launch(void* const* d_in, const int* in_sizes, int n_in,
                              void* d_out, int out_size, void* d_ws, size_t ws_size,
                              hipStream_t stream)
{
  const float* swin   = (const float*)d_in[0];
  const float* resnet = (const float*)d_in[1];
  const float* w_swin = (const float*)d_in[2];
  const float* b_swin = (const float*)d_in[3];
  const float* w_res  = (const float*)d_in[4];
  const float* b_res  = (const float*)d_in[5];
  const float* aq_w = (const float*)d_in[6];
  const float* aq_b = (const float*)d_in[7];
  const float* ak_w = (const float*)d_in[8];
  const float* ak_b = (const float*)d_in[9];
  const float* av_w = (const float*)d_in[10];
  const float* av_b = (const float*)d_in[11];
  const float* ad1_w = (const float*)d_in[12];
  const float* ad1_b = (const float*)d_in[13];
  const float* ad3_w = (const float*)d_in[14];
  const float* ad3_b = (const float*)d_in[15];
  const float* ag    = (const float*)d_in[16];
  const float* lq_w = (const float*)d_in[17];
  const float* lq_b = (const float*)d_in[18];
  const float* lk_w = (const float*)d_in[19];
  const float* lk_b = (const float*)d_in[20];
  const float* lv_w = (const float*)d_in[21];
  const float* lv_b = (const float*)d_in[22];
  const float* ld1_w = (const float*)d_in[23];
  const float* ld1_b = (const float*)d_in[24];
  const float* ld3_w = (const float*)d_in[25];
  const float* ld3_b = (const float*)d_in[26];
  const float* lg    = (const float*)d_in[27];
  const float* wc_w = (const float*)d_in[28];
  const float* wc_b = (const float*)d_in[29];
  float* out = (float*)d_out;

  // ---- workspace carve ----
  char* p = (char*)d_ws;
  double* Wsw   = (double*)p; p += (size_t)80*192*8;
  double* Wres  = (double*)p; p += (size_t)80*128*8;
  double* bqk   = (double*)p; p += (size_t)80*8;
  double* chsumd= (double*)p; p += (size_t)B4*320*8;
  double* wdad  = (double*)p; p += (size_t)B4*320*8;
  double* cdad  = (double*)p; p += (size_t)B4*8;
  double* dabuf = (double*)p; p += (size_t)B4*NPIX*8;
  float* dlbuf  = (float*)p;  p += (size_t)B4*NPIX*4;
  float* q8f    = (float*)p;  p += (size_t)B4*128*NPIX*4;
  float* proj1  = (float*)p;  p += (size_t)B4*320*NPIX*4;  // rows 0..159 vp, 160..319 outacc
  float* projL  = (float*)p;  p += (size_t)B4*640*NPIX*4;  // rows 0..319 kl, 320..639 vl
  float* qsum   = (float*)p;  p += (size_t)B4*NPIX*4;
  float* norm_a = (float*)p;  p += (size_t)B4*NPIX*4;
  float* norm_l = (float*)p;  p += (size_t)B4*NPIX*4;
  float* colsum = (float*)p;  p += (size_t)B4*320*4;
  float* kvp    = (float*)p;  p += (size_t)B4*40*160*4;
  float* Wbig1  = (float*)p;  p += (size_t)320*320*4;
  float* bias1  = (float*)p;  p += (size_t)320*4;
  float* Wmix   = (float*)p;  p += (size_t)2880*320*4;
  float* Wd3eff = (float*)p;  p += (size_t)160*2880*4;
  float* biasqk = (float*)p;  p += (size_t)128*4;
  float* bias3  = (float*)p;  p += (size_t)960*4;
  p = (char*)(((uintptr_t)p + 255) & ~(uintptr_t)255);
  unsigned short* xTh  = (unsigned short*)p; p += (size_t)B4*NPIX*320*2;
  unsigned short* xTl  = (unsigned short*)p; p += (size_t)B4*NPIX*320*2;
  unsigned short* Wb1h = (unsigned short*)p; p += (size_t)320*320*2;
  unsigned short* Wb1l = (unsigned short*)p; p += (size_t)320*320*2;
  unsigned short* lqh  = (unsigned short*)p; p += (size_t)320*320*2;   // lqh/lkh/lvh contiguous = [960][320]
  unsigned short* lkh  = (unsigned short*)p; p += (size_t)320*320*2;
  unsigned short* lvh  = (unsigned short*)p; p += (size_t)320*320*2;
  unsigned short* Wd3b = (unsigned short*)p; p += (size_t)192*2880*2;
  unsigned short* wswh = (unsigned short*)p; p += (size_t)192*192*2;
  unsigned short* wswl = (unsigned short*)p; p += (size_t)192*192*2;
  unsigned short* wrsh = (unsigned short*)p; p += (size_t)128*128*2;
  unsigned short* wrsl = (unsigned short*)p; p += (size_t)128*128*2;
  unsigned short* Wqkh = (unsigned short*)p; p += (size_t)128*320*2;
  unsigned short* Wqkl = (unsigned short*)p; p += (size_t)128*320*2;
  if ((size_t)(p - (char*)d_ws) > ws_size) return;

  // aliases over dead regions (stream-ordered safety):
  unsigned short* inThi = (unsigned short*)projL;          // dead once lkv writes projL
  unsigned short* inTlo = inThi + (size_t)B4*NPIX*320;
  unsigned short* pT = xTl;                                // dead once proj1 split GEMM done
  unsigned short* W2h = (unsigned short*)Wmix;             // dead once Wd3eff composed

  hipMemsetAsync(qsum, 0, (size_t)B4*NPIX*4, stream);
  hipMemsetAsync(kvp,  0, (size_t)B4*40*160*4, stream);
  hipMemsetAsync(dabuf, 0, (size_t)B4*NPIX*8, stream);
  hipMemsetAsync(dlbuf, 0, (size_t)B4*NPIX*4, stream);

  // ---- weight composition ----
  composeqk_kernel<<<(80*192 + 80*128 + 80 + 255)/256, 256, 0, stream>>>(
      aq_w, aq_b, ak_w, ak_b, w_swin, b_swin, w_res, b_res, Wsw, Wres, bqk);
  compose1_kernel<<<(320*320 + 255)/256, 256, 0, stream>>>(av_w, ad1_w, ld1_w, wc_w, ag, lg, Wbig1);
  bias1_kernel<<<5, 64, 0, stream>>>(av_b, ad1_b, ad3_b, ld1_b, ld3_b, wc_w, wc_b, ag, lg, bias1);
  t1_kernel<<<(2880*320 + 255)/256, 256, 0, stream>>>(ad3_w, ld3_w, ag, lg, Wmix);
  gemm_f32<<<dim3(5,3,9), 256, 0, stream>>>(wc_w, nullptr, Wmix, 320L*320, 320,
      Wd3eff, 320, 2880, 160, 320);

  // ---- weight bf16 conversions ----
  cvt_split_kernel<<<(320*320 + 255)/256, 256, 0, stream>>>(Wbig1, Wb1h, Wb1l, 320*320);
  cvt_bf16_kernel<<<(320*320 + 255)/256, 256, 0, stream>>>(lq_w, lqh, 320*320);
  cvt_bf16_kernel<<<(320*320 + 255)/256, 256, 0, stream>>>(lk_w, lkh, 320*320);
  cvt_bf16_kernel<<<(320*320 + 255)/256, 256, 0, stream>>>(lv_w, lvh, 320*320);
  cvt_pad_kernel<<<(192*2880 + 255)/256, 256, 0, stream>>>(Wd3eff, Wd3b);
  cvt_split_kernel<<<(192*192 + 255)/256, 256, 0, stream>>>(w_swin, wswh, wswl, 192*192);
  cvt_split_kernel<<<(128*128 + 255)/256, 256, 0, stream>>>(w_res, wrsh, wrsl, 128*128);
  cvtqk_kernel<<<(128*320 + 255)/256, 256, 0, stream>>>(Wsw, Wres, bqk, Wqkh, Wqkl, biasqk);
  bias3_kernel<<<4, 256, 0, stream>>>(lq_b, lk_b, lv_b, bias3);

  // ---- fp64 rank-1 denominator composition (must precede inT) ----
  chsum_kernel<<<dim3(320,4), 256, 0, stream>>>(swin, resnet, chsumd);
  skda_kernel<<<4, 320, 0, stream>>>(Wsw, Wres, bqk, chsumd, wdad, cdad);

  // ---- input transpose (+fused da partial) + x-build + q8/k8 via MFMA ----
  inT_kernel<<<dim3(64,5,4), 256, 0, stream>>>(swin, resnet, wdad, dabuf, inThi, inTlo);
  xbuild_mfma<<<dim3(2,64,4), 256, 0, stream>>>(inThi, inTlo, 0, 192,
      wswh, wswl, b_swin, 192, 0, xTh, xTl);
  xbuild_mfma<<<dim3(1,64,4), 256, 0, stream>>>(inThi, inTlo, 192, 128,
      wrsh, wrsl, b_res, 128, 192, xTh, xTl);
  gemm_mfma<0,1><<<dim3(32,2,4), 256, 0, stream>>>(Wqkh, Wqkl, biasqk, inThi, inTlo,
      q8f, 128L*NPIX, nullptr);   // before lkv overwrites inT

  // ---- merged lq/lk/lv projection (stacked [960][320]) ----
  gemm_mfma<3,0><<<dim3(32,15,4), 256, 0, stream>>>(lqh, nullptr, bias3, xTh, nullptr,
      projL, 640L*NPIX, qsum);
  // ---- proj1 split GEMM (last: frees xTl for pT alias) ----
  gemm_mfma<0,1><<<dim3(32,5,4), 256, 0, stream>>>(Wb1h, Wb1l, bias1, xTh, xTl,
      proj1, 320L*NPIX, nullptr);

  // ---- reductions ----
  kvp_mfma<<<dim3(2,32,4), 256, 0, stream>>>(proj1, q8f, kvp);
  colsum_kernel<<<dim3(320,4), 256, 0, stream>>>(projL, qsum, colsum);

  // ---- prep for final (pT fuses dl partial) ----
  pT_kernel<<<dim3(64,5,4), 256, 0, stream>>>(projL, colsum, pT, dlbuf);
  normfin_kernel<<<(B4*NPIX + 255)/256, 256, 0, stream>>>(dabuf, cdad, dlbuf, norm_a, norm_l);
  w2_kernel<<<(B4*160*320 + 255)/256, 256, 0, stream>>>(wc_w, colsum, W2h);

  // ---- fused epilogue + composed conv ----
  final_mfma<<<dim3(32,3,4), 256, 0, stream>>>(W2h, pT, kvp, q8f, proj1,
                                               norm_a, norm_l, ag, lg, out);
  conv_mfma<<<dim3(32,3,4), 256, 0, stream>>>(Wd3b, xTh, out);
}